// Round 1
// baseline (784.023 us; speedup 1.0000x reference)
//
#include <hip/hip_runtime.h>
#include <hip/hip_bf16.h>
#include <math.h>

typedef __bf16 bf16_t;
typedef __bf16 bf16x8 __attribute__((ext_vector_type(8)));
typedef __bf16 bf16x4 __attribute__((ext_vector_type(4)));
typedef float  f32x4  __attribute__((ext_vector_type(4)));

#define T_STEPS 32
#define BATCH   64
#define DIN     512
#define HID     512
#define VOCAB   32000
#define FFEAT   768
#define ROWS    2048   /* T*B */
#define G3      1536   /* 3*H */
#define NBLK_A  32

#define EPI_F32  0
#define EPI_BF16 1
#define EPI_TANH 2
#define EPI_EXP  3

// ---------------------------------------------------------------------------
// Generic bf16 GEMM: C[M][N] = A[M][K] @ B[N][K]^T + bias, templated epilogue.
// Block = 256 thr = 4 waves, block tile 128x128, wave tile 64x64 (4x4 frags of
// 16x16x32 MFMA). Fragments loaded directly from global (L1/L2).
// MFMA 16x16x32 layouts: A: row=lane&15, k=(lane>>4)*8+j ; B: col=lane&15,
// same k map; C/D: col=lane&15, row=(lane>>4)*4+reg  [guide §3, m89-verified].
// ---------------------------------------------------------------------------
template<int EPI>
__global__ __launch_bounds__(256) void gemm_bt(
    const bf16_t* __restrict__ A, const bf16_t* __restrict__ B,
    const float* __restrict__ bias, void* __restrict__ out,
    float* __restrict__ partial, int M, int N, int K, int NB)
{
  __shared__ float psum[128][2];
  const int lane = threadIdx.x & 63;
  const int wv   = threadIdx.x >> 6;
  const int wm = wv >> 1, wn = wv & 1;
  const int bn = blockIdx.x, bm = blockIdx.y;
  const int m0 = bm * 128 + wm * 64;
  const int n0 = bn * 128 + wn * 64;
  const int la = lane & 15, lg = lane >> 4;

  f32x4 acc[4][4] = {};
  const bf16_t* Ap = A + (size_t)(m0 + la) * K + lg * 8;
  const bf16_t* Bp = B + (size_t)(n0 + la) * K + lg * 8;

#pragma unroll 2
  for (int k0 = 0; k0 < K; k0 += 32) {
    bf16x8 a[4], b[4];
#pragma unroll
    for (int i = 0; i < 4; ++i) a[i] = *(const bf16x8*)(Ap + (size_t)i * 16 * K + k0);
#pragma unroll
    for (int j = 0; j < 4; ++j) b[j] = *(const bf16x8*)(Bp + (size_t)j * 16 * K + k0);
#pragma unroll
    for (int i = 0; i < 4; ++i)
#pragma unroll
      for (int j = 0; j < 4; ++j)
        acc[i][j] = __builtin_amdgcn_mfma_f32_16x16x32_bf16(a[i], b[j], acc[i][j], 0, 0, 0);
  }

#pragma unroll
  for (int i = 0; i < 4; ++i) {
#pragma unroll
    for (int r = 0; r < 4; ++r) {
      const int row = m0 + i * 16 + lg * 4 + r;
      float vsum = 0.f;
#pragma unroll
      for (int j = 0; j < 4; ++j) {
        const int col = n0 + j * 16 + la;
        float v = acc[i][j][r] + bias[col];
        if constexpr (EPI == EPI_F32) {
          ((float*)out)[(size_t)row * N + col] = v;
        } else if constexpr (EPI == EPI_BF16) {
          ((bf16_t*)out)[(size_t)row * N + col] = (bf16_t)v;
        } else if constexpr (EPI == EPI_TANH) {
          ((bf16_t*)out)[(size_t)row * N + col] = (bf16_t)tanhf(v);
        } else {
          float e = expf(v);
          ((float*)out)[(size_t)row * N + col] = e;
          vsum += e;
        }
      }
      if constexpr (EPI == EPI_EXP) {
        vsum += __shfl_xor(vsum, 1);
        vsum += __shfl_xor(vsum, 2);
        vsum += __shfl_xor(vsum, 4);
        vsum += __shfl_xor(vsum, 8);
        if (la == 0) psum[wm * 64 + i * 16 + lg * 4 + r][wn] = vsum;
      }
    }
  }
  if constexpr (EPI == EPI_EXP) {
    __syncthreads();
    if (threadIdx.x < 128) {
      const int rb = bm * 128 + threadIdx.x;
      partial[(size_t)rb * NB + bn] = psum[threadIdx.x][0] + psum[threadIdx.x][1];
    }
  }
  (void)partial; (void)NB;
}

// ---------------------------------------------------------------------------
// Phase A: sequential GRU recurrence. 32 blocks; block g owns h1 cols
// [16g,16g+16). Permuted W_hh slice (48 rows x 512) staged in LDS. Cross-step
// sync = cumulative-counter spin barrier (all 32 blocks co-resident).
// ---------------------------------------------------------------------------
__global__ __launch_bounds__(256) void phaseA_k(
    const bf16_t* __restrict__ Wg, const float* __restrict__ bhh,
    const float* __restrict__ gi, const float* __restrict__ ct,
    bf16_t* __restrict__ hbuf, bf16_t* __restrict__ Xall,
    int* __restrict__ bar)
{
  __shared__ bf16_t Wl[48 * 520];
  __shared__ float bl[48];
  const int tid = threadIdx.x, blk = blockIdx.x;

  for (int i = tid; i < 48 * 64; i += 256) {
    const int rw = i >> 6, ch = (i & 63) << 3;
    *(bf16x8*)(Wl + rw * 520 + ch) = *(const bf16x8*)(Wg + (size_t)(blk * 48 + rw) * 512 + ch);
  }
  if (tid < 48) bl[tid] = bhh[blk * 48 + tid];
  __syncthreads();

  const int lane = tid & 63, wv = tid >> 6;
  const int la = lane & 15, lg = lane >> 4;
  const int jcol = blk * 16 + la;

  for (int t = 0; t < T_STEPS; ++t) {
    const bf16_t* hcur = hbuf + (size_t)(t & 1) * BATCH * HID;
    bf16_t* hnxt = hbuf + (size_t)((t + 1) & 1) * BATCH * HID;
    f32x4 acc0 = {}, acc1 = {}, acc2 = {};
    const bf16_t* Ap = hcur + (size_t)(wv * 16 + la) * HID + lg * 8;
#pragma unroll 4
    for (int k0 = 0; k0 < HID; k0 += 32) {
      bf16x8 a  = *(const bf16x8*)(Ap + k0);
      bf16x8 b0 = *(const bf16x8*)(Wl + (0 * 16 + la) * 520 + k0 + lg * 8);
      bf16x8 b1 = *(const bf16x8*)(Wl + (1 * 16 + la) * 520 + k0 + lg * 8);
      bf16x8 b2 = *(const bf16x8*)(Wl + (2 * 16 + la) * 520 + k0 + lg * 8);
      acc0 = __builtin_amdgcn_mfma_f32_16x16x32_bf16(a, b0, acc0, 0, 0, 0);
      acc1 = __builtin_amdgcn_mfma_f32_16x16x32_bf16(a, b1, acc1, 0, 0, 0);
      acc2 = __builtin_amdgcn_mfma_f32_16x16x32_bf16(a, b2, acc2, 0, 0, 0);
    }
    const float* girow = gi + (size_t)t * BATCH * G3 + (size_t)blk * 48;
#pragma unroll
    for (int r = 0; r < 4; ++r) {
      const int row = wv * 16 + lg * 4 + r;
      const float ghr = acc0[r] + bl[la];
      const float ghz = acc1[r] + bl[16 + la];
      const float ghn = acc2[r] + bl[32 + la];
      const float* gp = girow + (size_t)row * G3;
      const float rr = 1.f / (1.f + expf(-(gp[la] + ghr)));
      const float zz = 1.f / (1.f + expf(-(gp[16 + la] + ghz)));
      const float nn = tanhf(gp[32 + la] + rr * ghn);
      const float hold = (float)hcur[(size_t)row * HID + jcol];
      const float h1 = (1.f - zz) * nn + zz * hold;
      hnxt[(size_t)row * HID + jcol] = (bf16_t)h1;
      Xall[((size_t)t * BATCH + row) * HID + jcol] = (bf16_t)(h1 * ct[row * HID + jcol]);
    }
    __syncthreads();
    if (tid == 0) {
      __threadfence();  // publish hnxt/Xall
      int a = __hip_atomic_fetch_add(bar, 1, __ATOMIC_ACQ_REL, __HIP_MEMORY_SCOPE_AGENT);
      if (a == NBLK_A * (t + 1) - 1) {
        __hip_atomic_fetch_add(bar + 1, 1, __ATOMIC_RELEASE, __HIP_MEMORY_SCOPE_AGENT);
      } else {
        while (__hip_atomic_load(bar + 1, __ATOMIC_RELAXED, __HIP_MEMORY_SCOPE_AGENT) < t + 1) {
          __builtin_amdgcn_s_sleep(2);
        }
      }
      __threadfence();  // acquire: invalidate L1 before reading others' h1
    }
    __syncthreads();
  }
}

// ---------------------------------------------------------------------------
// Per-(t,b) 8-head self-attention on a single vector (heads act as sequence).
// One wave per row; q,k,v staged in LDS as f32.
// ---------------------------------------------------------------------------
__global__ __launch_bounds__(256) void attn_k(const bf16_t* __restrict__ QKV,
                                              bf16_t* __restrict__ attO)
{
  __shared__ float sq[4][512], sk[4][512], sv[4][512], sw[4][64];
  const int tid = threadIdx.x;
  const int wv = tid >> 6, lane = tid & 63;
  const int row = blockIdx.x * 4 + wv;
  const bf16_t* base = QKV + (size_t)row * G3;
  bf16x8 vq = *(const bf16x8*)(base + lane * 8);
  bf16x8 vk = *(const bf16x8*)(base + 512 + lane * 8);
  bf16x8 vv = *(const bf16x8*)(base + 1024 + lane * 8);
#pragma unroll
  for (int e = 0; e < 8; ++e) {
    sq[wv][lane * 8 + e] = (float)vq[e];
    sk[wv][lane * 8 + e] = (float)vk[e];
    sv[wv][lane * 8 + e] = (float)vv[e];
  }
  __syncthreads();
  const int h = lane >> 3, g = lane & 7;
  float s = 0.f;
#pragma unroll 16
  for (int d = 0; d < 64; ++d) s += sq[wv][h * 64 + d] * sk[wv][g * 64 + d];
  s *= (1.f / 64.f);  // reference divides by head_dim (not sqrt)
  float m = s;
  m = fmaxf(m, __shfl_xor(m, 1));
  m = fmaxf(m, __shfl_xor(m, 2));
  m = fmaxf(m, __shfl_xor(m, 4));
  const float e = expf(s - m);
  float sum = e;
  sum += __shfl_xor(sum, 1);
  sum += __shfl_xor(sum, 2);
  sum += __shfl_xor(sum, 4);
  sw[wv][lane] = e / sum;
  __syncthreads();
#pragma unroll
  for (int rep = 0; rep < 8; ++rep) {
    const int idx = rep * 64 + lane;
    const int hh = idx >> 6, d = idx & 63;
    float o = 0.f;
#pragma unroll
    for (int gg = 0; gg < 8; ++gg) o += sw[wv][hh * 8 + gg] * sv[wv][gg * 64 + d];
    attO[(size_t)row * HID + idx] = (bf16_t)o;
  }
}

// --------------------------- small prep kernels ----------------------------
__global__ __launch_bounds__(256) void cast_k(const float* __restrict__ src,
                                              bf16_t* __restrict__ dst, int n4)
{
  const int i = blockIdx.x * 256 + threadIdx.x;
  if (i >= n4) return;
  float4 v = ((const float4*)src)[i];
  bf16x4 o = {(bf16_t)v.x, (bf16_t)v.y, (bf16_t)v.z, (bf16_t)v.w};
  *(bf16x4*)(dst + (size_t)i * 4) = o;
}

// gate-row permutation: block g owns h1 cols [16g,16g+16); its 48 rows are
// [r cols]++[z cols]++[n cols]. src row = sec*512 + g*16 + jj.
__global__ __launch_bounds__(256) void perm_cast_k(const float* __restrict__ src,
                                                   bf16_t* __restrict__ dst)
{
  const int i = blockIdx.x * 256 + threadIdx.x;  // 1536*128
  const int pg = i >> 7, kq = (i & 127) << 2;
  const int g = pg / 48, rem = pg - g * 48, sec = rem >> 4, jj = rem & 15;
  const int srow = sec * 512 + g * 16 + jj;
  float4 v = *(const float4*)(src + (size_t)srow * DIN + kq);
  bf16x4 o = {(bf16_t)v.x, (bf16_t)v.y, (bf16_t)v.z, (bf16_t)v.w};
  *(bf16x4*)(dst + (size_t)pg * DIN + kq) = o;
}

__global__ void perm_bias_k(const float* __restrict__ bih, const float* __restrict__ bhh,
                            float* __restrict__ bihp, float* __restrict__ bhhp)
{
  const int pg = blockIdx.x * 256 + threadIdx.x;
  if (pg >= G3) return;
  const int g = pg / 48, rem = pg - g * 48, sec = rem >> 4, jj = rem & 15;
  const int srow = sec * 512 + g * 16 + jj;
  bihp[pg] = bih[srow];
  bhhp[pg] = bhh[srow];
}

__global__ void bcat_k(const float* __restrict__ a, const float* __restrict__ b,
                       const float* __restrict__ c, float* __restrict__ d)
{
  const int i = blockIdx.x * 256 + threadIdx.x;
  if (i >= G3) return;
  d[i] = i < 512 ? a[i] : (i < 1024 ? b[i - 512] : c[i - 1024]);
}

__global__ __launch_bounds__(256) void yemb_k(const int* __restrict__ y,
                                              const float* __restrict__ embW,
                                              bf16_t* __restrict__ out)
{
  const int idx = blockIdx.x * 256 + threadIdx.x;  // 2048*64
  const int rb = idx >> 6, c = (idx & 63) << 3;
  const int tok = y[rb];
  const float4* s = (const float4*)(embW + (size_t)tok * DIN + c);
  float4 v0 = s[0], v1 = s[1];
  bf16x8 o = {(bf16_t)v0.x, (bf16_t)v0.y, (bf16_t)v0.z, (bf16_t)v0.w,
              (bf16_t)v1.x, (bf16_t)v1.y, (bf16_t)v1.z, (bf16_t)v1.w};
  *(bf16x8*)(out + (size_t)rb * DIN + c) = o;
}

__global__ __launch_bounds__(256) void ct_k(const float* __restrict__ ctx,
                                            const float* __restrict__ Watt,
                                            const float* __restrict__ batt,
                                            float* __restrict__ ct)
{
  const int idx = blockIdx.x * 256 + threadIdx.x;  // 64*512
  const int b = idx >> 9, j = idx & 511;
  const float4* c4 = (const float4*)(ctx + (size_t)b * FFEAT);
  const float4* w4 = (const float4*)(Watt + (size_t)j * FFEAT);
  float s = batt[j];
  for (int q = 0; q < FFEAT / 4; ++q) {
    float4 cc = c4[q], ww = w4[q];
    s += cc.x * ww.x + cc.y * ww.y + cc.z * ww.z + cc.w * ww.w;
  }
  ct[idx] = tanhf(s);
}

__global__ __launch_bounds__(256) void reduce_rows(const float* __restrict__ partial,
                                                   float* __restrict__ rowsum, int NB)
{
  const int wv = threadIdx.x >> 6, lane = threadIdx.x & 63;
  const int row = blockIdx.x * 4 + wv;
  float s = 0.f;
  for (int c = lane; c < NB; c += 64) s += partial[(size_t)row * NB + c];
  for (int m = 1; m < 64; m <<= 1) s += __shfl_xor(s, m);
  if (lane == 0) rowsum[row] = s;
}

__global__ __launch_bounds__(256) void normalize_k(float* __restrict__ out,
                                                   const float* __restrict__ rowsum)
{
  const size_t idx = (size_t)blockIdx.x * 256 + threadIdx.x;  // float4 units
  const int row = (int)(idx / (VOCAB / 4));
  float4 v = ((float4*)out)[idx];
  const float inv = 1.0f / rowsum[row];
  v.x *= inv; v.y *= inv; v.z *= inv; v.w *= inv;
  ((float4*)out)[idx] = v;
}

// ---------------------------------------------------------------------------
extern "C" void kernel_launch(void* const* d_in, const int* in_sizes, int n_in,
                              void* d_out, int out_size, void* d_ws, size_t ws_size,
                              hipStream_t stream)
{
  const int*   y     = (const int*)  d_in[0];
  const float* ctx   = (const float*)d_in[1];
  const float* embW  = (const float*)d_in[2];
  const float* W_ih  = (const float*)d_in[3];
  const float* b_ih  = (const float*)d_in[4];
  const float* W_hh  = (const float*)d_in[5];
  const float* b_hh  = (const float*)d_in[6];
  const float* W_att = (const float*)d_in[7];
  const float* b_att = (const float*)d_in[8];
  const float* Wq    = (const float*)d_in[9];
  const float* bq    = (const float*)d_in[10];
  const float* Wk    = (const float*)d_in[11];
  const float* bk    = (const float*)d_in[12];
  const float* Wv    = (const float*)d_in[13];
  const float* bv    = (const float*)d_in[14];
  const float* Wfc   = (const float*)d_in[15];
  const float* bfc   = (const float*)d_in[16];
  const float* Wh2o  = (const float*)d_in[17];
  const float* bh2o  = (const float*)d_in[18];
  const float* W_out = (const float*)d_in[19];
  const float* b_out = (const float*)d_in[20];

  char* p = (char*)d_ws;
  auto alloc = [&](size_t bytes) {
    char* r = p;
    p += (bytes + 255) & ~(size_t)255;
    return r;
  };
  bf16_t* WoutB   = (bf16_t*)alloc((size_t)VOCAB * DIN * 2);
  bf16_t* WgIh    = (bf16_t*)alloc((size_t)G3 * DIN * 2);
  bf16_t* WgHh    = (bf16_t*)alloc((size_t)G3 * DIN * 2);
  bf16_t* Wqkv    = (bf16_t*)alloc((size_t)G3 * DIN * 2);
  bf16_t* WfcB    = (bf16_t*)alloc((size_t)HID * HID * 2);
  bf16_t* Wh2oB   = (bf16_t*)alloc((size_t)HID * HID * 2);
  float*  bIhP    = (float*)alloc(G3 * 4);
  float*  bHhP    = (float*)alloc(G3 * 4);
  float*  bQkv    = (float*)alloc(G3 * 4);
  bf16_t* Yemb    = (bf16_t*)alloc((size_t)ROWS * DIN * 2);
  float*  giP     = (float*)alloc((size_t)ROWS * G3 * 4);
  float*  ctB     = (float*)alloc((size_t)BATCH * HID * 4);
  bf16_t* hbuf    = (bf16_t*)alloc((size_t)2 * BATCH * HID * 2);
  bf16_t* Xall    = (bf16_t*)alloc((size_t)ROWS * DIN * 2);
  bf16_t* QKV     = (bf16_t*)alloc((size_t)ROWS * G3 * 2);
  bf16_t* attO    = (bf16_t*)alloc((size_t)ROWS * HID * 2);
  bf16_t* h2B     = (bf16_t*)alloc((size_t)ROWS * HID * 2);
  bf16_t* logit   = (bf16_t*)alloc((size_t)ROWS * DIN * 2);
  float*  partial = (float*)alloc((size_t)ROWS * 250 * 4);
  float*  rowsum  = (float*)alloc((size_t)ROWS * 4);
  int*    bar     = (int*)alloc(256);

  hipMemsetAsync(hbuf, 0, (size_t)2 * BATCH * HID * 2, stream);  // h0 = 0 (+ replay reset)
  hipMemsetAsync(bar, 0, 8, stream);                             // barrier counters

  // weight prep
  cast_k<<<(VOCAB * DIN / 4 + 255) / 256, 256, 0, stream>>>(W_out, WoutB, VOCAB * DIN / 4);
  cast_k<<<256, 256, 0, stream>>>(Wq, Wqkv, HID * HID / 4);
  cast_k<<<256, 256, 0, stream>>>(Wk, Wqkv + (size_t)HID * DIN, HID * HID / 4);
  cast_k<<<256, 256, 0, stream>>>(Wv, Wqkv + (size_t)2 * HID * DIN, HID * HID / 4);
  cast_k<<<256, 256, 0, stream>>>(Wfc, WfcB, HID * HID / 4);
  cast_k<<<256, 256, 0, stream>>>(Wh2o, Wh2oB, HID * HID / 4);
  perm_cast_k<<<768, 256, 0, stream>>>(W_ih, WgIh);
  perm_cast_k<<<768, 256, 0, stream>>>(W_hh, WgHh);
  perm_bias_k<<<6, 256, 0, stream>>>(b_ih, b_hh, bIhP, bHhP);
  bcat_k<<<6, 256, 0, stream>>>(bq, bk, bv, bQkv);
  yemb_k<<<512, 256, 0, stream>>>(y, embW, Yemb);
  ct_k<<<128, 256, 0, stream>>>(ctx, W_att, b_att, ctB);

  // gi for all steps: [2048,512] @ [1536,512]^T  -> fp32 (bias = b_ih)
  gemm_bt<EPI_F32><<<dim3(12, 16), 256, 0, stream>>>(
      Yemb, WgIh, bIhP, giP, nullptr, ROWS, G3, DIN, 12);

  // sequential GRU recurrence -> Xall = h1 * ct (bf16)
  phaseA_k<<<NBLK_A, 256, 0, stream>>>(WgHh, bHhP, giP, ctB, hbuf, Xall, bar);

  // QKV = X @ [Wq;Wk;Wv]^T + b
  gemm_bt<EPI_BF16><<<dim3(12, 16), 256, 0, stream>>>(
      Xall, Wqkv, bQkv, QKV, nullptr, ROWS, G3, DIN, 12);

  attn_k<<<512, 256, 0, stream>>>(QKV, attO);

  // h2 = att @ Wfc^T + bfc
  gemm_bt<EPI_BF16><<<dim3(4, 16), 256, 0, stream>>>(
      attO, WfcB, bfc, h2B, nullptr, ROWS, HID, HID, 4);

  // logit = tanh(h2 @ Wh2o^T + b)
  gemm_bt<EPI_TANH><<<dim3(4, 16), 256, 0, stream>>>(
      h2B, Wh2oB, bh2o, logit, nullptr, ROWS, DIN, HID, 4);

  // e = exp(logit @ W_out^T + b) -> d_out, per-(row, col-block) partial sums
  gemm_bt<EPI_EXP><<<dim3(250, 16), 256, 0, stream>>>(
      logit, WoutB, b_out, d_out, partial, ROWS, VOCAB, DIN, 250);

  reduce_rows<<<512, 256, 0, stream>>>(partial, rowsum, 250);
  normalize_k<<<ROWS * VOCAB / 4 / 256, 256, 0, stream>>>((float*)d_out, rowsum);
}

// Round 2
// 720.156 us; speedup vs baseline: 1.0887x; 1.0887x over previous
//
#include <hip/hip_runtime.h>
#include <hip/hip_bf16.h>
#include <math.h>

typedef __bf16 bf16_t;
typedef __bf16 bf16x8 __attribute__((ext_vector_type(8)));
typedef __bf16 bf16x4 __attribute__((ext_vector_type(4)));
typedef float  f32x4  __attribute__((ext_vector_type(4)));

#define T_STEPS 32
#define BATCH   64
#define DIN     512
#define HID     512
#define VOCAB   32000
#define FFEAT   768
#define ROWS    2048   /* T*B */
#define G3      1536   /* 3*H */
#define NBLK_A  32

#define EPI_F32  0
#define EPI_BF16 1
#define EPI_TANH 2
#define EPI_EXP  3

// ---------------------------------------------------------------------------
// Generic bf16 GEMM: C[M][N] = A[M][K] @ B[N][K]^T + bias, templated epilogue.
// Block = 256 thr = 4 waves, block tile 128x128, wave tile 64x64 (4x4 frags of
// 16x16x32 MFMA). Fragments loaded directly from global (L1/L2).
// EPI_EXP uses a 1D grid + bn-major XCD-chunk swizzle so each XCD's L2 keeps
// one B-panel (128KB) hot across all 16 bm tiles (16x less L3 B traffic).
// ---------------------------------------------------------------------------
template<int EPI>
__global__ __launch_bounds__(256) void gemm_bt(
    const bf16_t* __restrict__ A, const bf16_t* __restrict__ B,
    const float* __restrict__ bias, void* __restrict__ out,
    float* __restrict__ partial, int M, int N, int K, int NB)
{
  __shared__ float psum[128][2];
  const int lane = threadIdx.x & 63;
  const int wv   = threadIdx.x >> 6;
  const int wm = wv >> 1, wn = wv & 1;
  int bn, bm;
  if constexpr (EPI == EPI_EXP) {
    // 1D grid of NB*16 blocks; order wgs bn-major (wg = bn*16+bm), chunk to XCDs
    const int lin = blockIdx.x;
    const int nwg = NB * 16;
    const int cpx = nwg >> 3;           // nwg % 8 == 0 (4000/8=500)
    const int wg  = (lin & 7) * cpx + (lin >> 3);
    bn = wg >> 4; bm = wg & 15;
  } else {
    bn = blockIdx.x; bm = blockIdx.y;
  }
  const int m0 = bm * 128 + wm * 64;
  const int n0 = bn * 128 + wn * 64;
  const int la = lane & 15, lg = lane >> 4;

  f32x4 acc[4][4] = {};
  const bf16_t* Ap = A + (size_t)(m0 + la) * K + lg * 8;
  const bf16_t* Bp = B + (size_t)(n0 + la) * K + lg * 8;

#pragma unroll 2
  for (int k0 = 0; k0 < K; k0 += 32) {
    bf16x8 a[4], b[4];
#pragma unroll
    for (int i = 0; i < 4; ++i) a[i] = *(const bf16x8*)(Ap + (size_t)i * 16 * K + k0);
#pragma unroll
    for (int j = 0; j < 4; ++j) b[j] = *(const bf16x8*)(Bp + (size_t)j * 16 * K + k0);
#pragma unroll
    for (int i = 0; i < 4; ++i)
#pragma unroll
      for (int j = 0; j < 4; ++j)
        acc[i][j] = __builtin_amdgcn_mfma_f32_16x16x32_bf16(a[i], b[j], acc[i][j], 0, 0, 0);
  }

#pragma unroll
  for (int i = 0; i < 4; ++i) {
#pragma unroll
    for (int r = 0; r < 4; ++r) {
      const int row = m0 + i * 16 + lg * 4 + r;
      float vsum = 0.f;
#pragma unroll
      for (int j = 0; j < 4; ++j) {
        const int col = n0 + j * 16 + la;
        float v = acc[i][j][r] + bias[col];
        if constexpr (EPI == EPI_F32) {
          ((float*)out)[(size_t)row * N + col] = v;
        } else if constexpr (EPI == EPI_BF16) {
          ((bf16_t*)out)[(size_t)row * N + col] = (bf16_t)v;
        } else if constexpr (EPI == EPI_TANH) {
          ((bf16_t*)out)[(size_t)row * N + col] = (bf16_t)tanhf(v);
        } else {
          float e = expf(v);
          ((float*)out)[(size_t)row * N + col] = e;
          vsum += e;
        }
      }
      if constexpr (EPI == EPI_EXP) {
        vsum += __shfl_xor(vsum, 1);
        vsum += __shfl_xor(vsum, 2);
        vsum += __shfl_xor(vsum, 4);
        vsum += __shfl_xor(vsum, 8);
        if (la == 0) psum[wm * 64 + i * 16 + lg * 4 + r][wn] = vsum;
      }
    }
  }
  if constexpr (EPI == EPI_EXP) {
    __syncthreads();
    if (threadIdx.x < 128) {
      const int rb = bm * 128 + threadIdx.x;
      partial[(size_t)rb * NB + bn] = psum[threadIdx.x][0] + psum[threadIdx.x][1];
    }
  }
  (void)partial; (void)NB;
}

// ---------------------------------------------------------------------------
// Phase A: sequential GRU recurrence. 32 blocks; block g owns h1 cols
// [16g,16g+16). All cross-block h traffic via relaxed AGENT-scope atomics
// (sc0/sc1 -> coherent at L3, NO cache-wide fences). Per-WAVE distributed
// flags: wave w only consumes rows [16w,16w+16) which are produced by wave w
// of every block -> each wave polls its own 32 flags in parallel lanes.
// h stored as packed bf16 pairs (u32); previous own h kept in registers.
// ---------------------------------------------------------------------------
__global__ __launch_bounds__(256) void phaseA_k(
    const bf16_t* __restrict__ Wg, const float* __restrict__ bhh,
    const float* __restrict__ gi, const float* __restrict__ ct,
    unsigned int* __restrict__ hbuf /* u32[2][64][256] bf16-pairs */,
    bf16_t* __restrict__ Xall, int* __restrict__ flags /* [4][32] */)
{
  __shared__ bf16_t Wl[48 * 520];
  __shared__ float bl[48];
  const int tid = threadIdx.x, blk = blockIdx.x;

  for (int i = tid; i < 48 * 64; i += 256) {
    const int rw = i >> 6, ch = (i & 63) << 3;
    *(bf16x8*)(Wl + rw * 520 + ch) = *(const bf16x8*)(Wg + (size_t)(blk * 48 + rw) * 512 + ch);
  }
  if (tid < 48) bl[tid] = bhh[blk * 48 + tid];
  __syncthreads();

  const int lane = tid & 63, wv = tid >> 6;
  const int la = lane & 15, lg = lane >> 4;
  const int jcol = blk * 16 + la;
  const int rowA = wv * 16 + la;          // A-fragment row this lane loads

  const float blr = bl[la], blz = bl[16 + la], bln = bl[32 + la];
  float hprev[4], ctv[4];
#pragma unroll
  for (int r = 0; r < 4; ++r) {
    hprev[r] = 0.f;
    ctv[r] = ct[(size_t)(wv * 16 + lg * 4 + r) * HID + jcol];
  }

  for (int t = 0; t < T_STEPS; ++t) {
    // ---- gi prefetch (independent of h; hides HBM latency under the poll)
    const float* girow = gi + (size_t)t * BATCH * G3 + (size_t)blk * 48;
    float gv[12];
#pragma unroll
    for (int r = 0; r < 4; ++r) {
      const float* gp = girow + (size_t)(wv * 16 + lg * 4 + r) * G3;
      gv[r * 3 + 0] = gp[la];
      gv[r * 3 + 1] = gp[16 + la];
      gv[r * 3 + 2] = gp[32 + la];
    }
    // ---- wait: wave w needs flag[w][blk] >= t from every block
    if (t > 0) {
      if (lane < 32) {
        while (__hip_atomic_load(&flags[wv * 32 + lane], __ATOMIC_RELAXED,
                                 __HIP_MEMORY_SCOPE_AGENT) < t)
          __builtin_amdgcn_s_sleep(1);
      }
      asm volatile("" ::: "memory");
    }
    // ---- load A fragments (16 rows of h, full K) via coherent u64 loads
    const unsigned long long* hb =
        (const unsigned long long*)(hbuf + (size_t)(t & 1) * 64 * 256);
    bf16x8 af[16];
#pragma unroll
    for (int q = 0; q < 16; ++q) {
      union { unsigned long long u[2]; bf16x8 v; } c;
      const size_t bidx = (size_t)rowA * 128 + q * 8 + lg * 2;
      c.u[0] = __hip_atomic_load(hb + bidx,     __ATOMIC_RELAXED, __HIP_MEMORY_SCOPE_AGENT);
      c.u[1] = __hip_atomic_load(hb + bidx + 1, __ATOMIC_RELAXED, __HIP_MEMORY_SCOPE_AGENT);
      af[q] = c.v;
    }
    // ---- MFMA: gh = h @ Whh_slice^T (48 cols = r,z,n x 16)
    f32x4 acc0 = {}, acc1 = {}, acc2 = {};
#pragma unroll
    for (int q = 0; q < 16; ++q) {
      const bf16_t* wp = Wl + q * 32 + lg * 8;
      bf16x8 b0 = *(const bf16x8*)(wp + (0 * 16 + la) * 520);
      bf16x8 b1 = *(const bf16x8*)(wp + (1 * 16 + la) * 520);
      bf16x8 b2 = *(const bf16x8*)(wp + (2 * 16 + la) * 520);
      acc0 = __builtin_amdgcn_mfma_f32_16x16x32_bf16(af[q], b0, acc0, 0, 0, 0);
      acc1 = __builtin_amdgcn_mfma_f32_16x16x32_bf16(af[q], b1, acc1, 0, 0, 0);
      acc2 = __builtin_amdgcn_mfma_f32_16x16x32_bf16(af[q], b2, acc2, 0, 0, 0);
    }
    // ---- epilogue: gates, h1, Xall, packed coherent h store
    unsigned int* hn = hbuf + (size_t)((t + 1) & 1) * 64 * 256;
#pragma unroll
    for (int r = 0; r < 4; ++r) {
      const int row = wv * 16 + lg * 4 + r;
      const float ghr = acc0[r] + blr;
      const float ghz = acc1[r] + blz;
      const float ghn = acc2[r] + bln;
      const float rr = 1.f / (1.f + expf(-(gv[r * 3 + 0] + ghr)));
      const float zz = 1.f / (1.f + expf(-(gv[r * 3 + 1] + ghz)));
      const float nn = tanhf(gv[r * 3 + 2] + rr * ghn);
      const float h1 = (1.f - zz) * nn + zz * hprev[r];
      hprev[r] = h1;
      Xall[((size_t)t * BATCH + row) * HID + jcol] = (bf16_t)(h1 * ctv[r]);
      const unsigned int mine =
          (unsigned int)__builtin_bit_cast(unsigned short, (bf16_t)h1);
      const unsigned int other = (unsigned int)__shfl_xor((int)mine, 1);
      if ((la & 1) == 0) {
        __hip_atomic_store(hn + (size_t)row * 256 + blk * 8 + (la >> 1),
                           mine | (other << 16), __ATOMIC_RELAXED,
                           __HIP_MEMORY_SCOPE_AGENT);
      }
    }
    // release: h stores (sc0sc1) are at the coherence point once vmcnt==0
    asm volatile("s_waitcnt vmcnt(0)" ::: "memory");
    if (lane == 0) {
      __hip_atomic_store(&flags[wv * 32 + blk], t + 1, __ATOMIC_RELAXED,
                         __HIP_MEMORY_SCOPE_AGENT);
    }
  }
}

// ---------------------------------------------------------------------------
// Per-(t,b) 8-head self-attention on a single vector (heads act as sequence).
// ---------------------------------------------------------------------------
__global__ __launch_bounds__(256) void attn_k(const bf16_t* __restrict__ QKV,
                                              bf16_t* __restrict__ attO)
{
  __shared__ float sq[4][512], sk[4][512], sv[4][512], sw[4][64];
  const int tid = threadIdx.x;
  const int wv = tid >> 6, lane = tid & 63;
  const int row = blockIdx.x * 4 + wv;
  const bf16_t* base = QKV + (size_t)row * G3;
  bf16x8 vq = *(const bf16x8*)(base + lane * 8);
  bf16x8 vk = *(const bf16x8*)(base + 512 + lane * 8);
  bf16x8 vv = *(const bf16x8*)(base + 1024 + lane * 8);
#pragma unroll
  for (int e = 0; e < 8; ++e) {
    sq[wv][lane * 8 + e] = (float)vq[e];
    sk[wv][lane * 8 + e] = (float)vk[e];
    sv[wv][lane * 8 + e] = (float)vv[e];
  }
  __syncthreads();
  const int h = lane >> 3, g = lane & 7;
  float s = 0.f;
#pragma unroll 16
  for (int d = 0; d < 64; ++d) s += sq[wv][h * 64 + d] * sk[wv][g * 64 + d];
  s *= (1.f / 64.f);  // reference divides by head_dim (not sqrt)
  float m = s;
  m = fmaxf(m, __shfl_xor(m, 1));
  m = fmaxf(m, __shfl_xor(m, 2));
  m = fmaxf(m, __shfl_xor(m, 4));
  const float e = expf(s - m);
  float sum = e;
  sum += __shfl_xor(sum, 1);
  sum += __shfl_xor(sum, 2);
  sum += __shfl_xor(sum, 4);
  sw[wv][lane] = e / sum;
  __syncthreads();
#pragma unroll
  for (int rep = 0; rep < 8; ++rep) {
    const int idx = rep * 64 + lane;
    const int hh = idx >> 6, d = idx & 63;
    float o = 0.f;
#pragma unroll
    for (int gg = 0; gg < 8; ++gg) o += sw[wv][hh * 8 + gg] * sv[wv][gg * 64 + d];
    attO[(size_t)row * HID + idx] = (bf16_t)o;
  }
}

// --------------------------- small prep kernels ----------------------------
__global__ __launch_bounds__(256) void cast_k(const float* __restrict__ src,
                                              bf16_t* __restrict__ dst, int n4)
{
  const int i = blockIdx.x * 256 + threadIdx.x;
  if (i >= n4) return;
  float4 v = ((const float4*)src)[i];
  bf16x4 o = {(bf16_t)v.x, (bf16_t)v.y, (bf16_t)v.z, (bf16_t)v.w};
  *(bf16x4*)(dst + (size_t)i * 4) = o;
}

__global__ __launch_bounds__(256) void perm_cast_k(const float* __restrict__ src,
                                                   bf16_t* __restrict__ dst)
{
  const int i = blockIdx.x * 256 + threadIdx.x;  // 1536*128
  const int pg = i >> 7, kq = (i & 127) << 2;
  const int g = pg / 48, rem = pg - g * 48, sec = rem >> 4, jj = rem & 15;
  const int srow = sec * 512 + g * 16 + jj;
  float4 v = *(const float4*)(src + (size_t)srow * DIN + kq);
  bf16x4 o = {(bf16_t)v.x, (bf16_t)v.y, (bf16_t)v.z, (bf16_t)v.w};
  *(bf16x4*)(dst + (size_t)pg * DIN + kq) = o;
}

__global__ void perm_bias_k(const float* __restrict__ bih, const float* __restrict__ bhh,
                            float* __restrict__ bihp, float* __restrict__ bhhp)
{
  const int pg = blockIdx.x * 256 + threadIdx.x;
  if (pg >= G3) return;
  const int g = pg / 48, rem = pg - g * 48, sec = rem >> 4, jj = rem & 15;
  const int srow = sec * 512 + g * 16 + jj;
  bihp[pg] = bih[srow];
  bhhp[pg] = bhh[srow];
}

__global__ void bcat_k(const float* __restrict__ a, const float* __restrict__ b,
                       const float* __restrict__ c, float* __restrict__ d)
{
  const int i = blockIdx.x * 256 + threadIdx.x;
  if (i >= G3) return;
  d[i] = i < 512 ? a[i] : (i < 1024 ? b[i - 512] : c[i - 1024]);
}

__global__ __launch_bounds__(256) void yemb_k(const int* __restrict__ y,
                                              const float* __restrict__ embW,
                                              bf16_t* __restrict__ out)
{
  const int idx = blockIdx.x * 256 + threadIdx.x;  // 2048*64
  const int rb = idx >> 6, c = (idx & 63) << 3;
  const int tok = y[rb];
  const float4* s = (const float4*)(embW + (size_t)tok * DIN + c);
  float4 v0 = s[0], v1 = s[1];
  bf16x8 o = {(bf16_t)v0.x, (bf16_t)v0.y, (bf16_t)v0.z, (bf16_t)v0.w,
              (bf16_t)v1.x, (bf16_t)v1.y, (bf16_t)v1.z, (bf16_t)v1.w};
  *(bf16x8*)(out + (size_t)rb * DIN + c) = o;
}

__global__ __launch_bounds__(256) void ct_k(const float* __restrict__ ctx,
                                            const float* __restrict__ Watt,
                                            const float* __restrict__ batt,
                                            float* __restrict__ ct)
{
  const int idx = blockIdx.x * 256 + threadIdx.x;  // 64*512
  const int b = idx >> 9, j = idx & 511;
  const float4* c4 = (const float4*)(ctx + (size_t)b * FFEAT);
  const float4* w4 = (const float4*)(Watt + (size_t)j * FFEAT);
  float s = batt[j];
  for (int q = 0; q < FFEAT / 4; ++q) {
    float4 cc = c4[q], ww = w4[q];
    s += cc.x * ww.x + cc.y * ww.y + cc.z * ww.z + cc.w * ww.w;
  }
  ct[idx] = tanhf(s);
}

__global__ __launch_bounds__(256) void reduce_rows(const float* __restrict__ partial,
                                                   float* __restrict__ rowsum, int NB)
{
  const int wv = threadIdx.x >> 6, lane = threadIdx.x & 63;
  const int row = blockIdx.x * 4 + wv;
  float s = 0.f;
  for (int c = lane; c < NB; c += 64) s += partial[(size_t)row * NB + c];
  for (int m = 1; m < 64; m <<= 1) s += __shfl_xor(s, m);
  if (lane == 0) rowsum[row] = s;
}

__global__ __launch_bounds__(256) void normalize_k(float* __restrict__ out,
                                                   const float* __restrict__ rowsum)
{
  const size_t idx = (size_t)blockIdx.x * 256 + threadIdx.x;  // float4 units
  const int row = (int)(idx / (VOCAB / 4));
  float4 v = ((float4*)out)[idx];
  const float inv = 1.0f / rowsum[row];
  v.x *= inv; v.y *= inv; v.z *= inv; v.w *= inv;
  ((float4*)out)[idx] = v;
}

// ---------------------------------------------------------------------------
extern "C" void kernel_launch(void* const* d_in, const int* in_sizes, int n_in,
                              void* d_out, int out_size, void* d_ws, size_t ws_size,
                              hipStream_t stream)
{
  const int*   y     = (const int*)  d_in[0];
  const float* ctx   = (const float*)d_in[1];
  const float* embW  = (const float*)d_in[2];
  const float* W_ih  = (const float*)d_in[3];
  const float* b_ih  = (const float*)d_in[4];
  const float* W_hh  = (const float*)d_in[5];
  const float* b_hh  = (const float*)d_in[6];
  const float* W_att = (const float*)d_in[7];
  const float* b_att = (const float*)d_in[8];
  const float* Wq    = (const float*)d_in[9];
  const float* bq    = (const float*)d_in[10];
  const float* Wk    = (const float*)d_in[11];
  const float* bk    = (const float*)d_in[12];
  const float* Wv    = (const float*)d_in[13];
  const float* bv    = (const float*)d_in[14];
  const float* Wfc   = (const float*)d_in[15];
  const float* bfc   = (const float*)d_in[16];
  const float* Wh2o  = (const float*)d_in[17];
  const float* bh2o  = (const float*)d_in[18];
  const float* W_out = (const float*)d_in[19];
  const float* b_out = (const float*)d_in[20];

  char* p = (char*)d_ws;
  auto alloc = [&](size_t bytes) {
    char* r = p;
    p += (bytes + 255) & ~(size_t)255;
    return r;
  };
  bf16_t* WoutB   = (bf16_t*)alloc((size_t)VOCAB * DIN * 2);
  bf16_t* WgIh    = (bf16_t*)alloc((size_t)G3 * DIN * 2);
  bf16_t* WgHh    = (bf16_t*)alloc((size_t)G3 * DIN * 2);
  bf16_t* Wqkv    = (bf16_t*)alloc((size_t)G3 * DIN * 2);
  bf16_t* WfcB    = (bf16_t*)alloc((size_t)HID * HID * 2);
  bf16_t* Wh2oB   = (bf16_t*)alloc((size_t)HID * HID * 2);
  float*  bIhP    = (float*)alloc(G3 * 4);
  float*  bHhP    = (float*)alloc(G3 * 4);
  float*  bQkv    = (float*)alloc(G3 * 4);
  bf16_t* Yemb    = (bf16_t*)alloc((size_t)ROWS * DIN * 2);
  float*  giP     = (float*)alloc((size_t)ROWS * G3 * 4);
  float*  ctB     = (float*)alloc((size_t)BATCH * HID * 4);
  unsigned int* hbuf = (unsigned int*)alloc((size_t)2 * BATCH * (HID / 2) * 4);
  bf16_t* Xall    = (bf16_t*)alloc((size_t)ROWS * DIN * 2);
  bf16_t* QKV     = (bf16_t*)alloc((size_t)ROWS * G3 * 2);
  bf16_t* attO    = (bf16_t*)alloc((size_t)ROWS * HID * 2);
  bf16_t* h2B     = (bf16_t*)alloc((size_t)ROWS * HID * 2);
  bf16_t* logit   = (bf16_t*)alloc((size_t)ROWS * DIN * 2);
  float*  partial = (float*)alloc((size_t)ROWS * 250 * 4);
  float*  rowsum  = (float*)alloc((size_t)ROWS * 4);
  int*    flags   = (int*)alloc(512);

  hipMemsetAsync(hbuf, 0, (size_t)2 * BATCH * (HID / 2) * 4, stream);  // h0 = 0
  hipMemsetAsync(flags, 0, 512, stream);

  // weight prep
  cast_k<<<(VOCAB * DIN / 4 + 255) / 256, 256, 0, stream>>>(W_out, WoutB, VOCAB * DIN / 4);
  cast_k<<<256, 256, 0, stream>>>(Wq, Wqkv, HID * HID / 4);
  cast_k<<<256, 256, 0, stream>>>(Wk, Wqkv + (size_t)HID * DIN, HID * HID / 4);
  cast_k<<<256, 256, 0, stream>>>(Wv, Wqkv + (size_t)2 * HID * DIN, HID * HID / 4);
  cast_k<<<256, 256, 0, stream>>>(Wfc, WfcB, HID * HID / 4);
  cast_k<<<256, 256, 0, stream>>>(Wh2o, Wh2oB, HID * HID / 4);
  perm_cast_k<<<768, 256, 0, stream>>>(W_ih, WgIh);
  perm_cast_k<<<768, 256, 0, stream>>>(W_hh, WgHh);
  perm_bias_k<<<6, 256, 0, stream>>>(b_ih, b_hh, bIhP, bHhP);
  bcat_k<<<6, 256, 0, stream>>>(bq, bk, bv, bQkv);
  yemb_k<<<512, 256, 0, stream>>>(y, embW, Yemb);
  ct_k<<<128, 256, 0, stream>>>(ctx, W_att, b_att, ctB);

  // gi for all steps: [2048,512] @ [1536,512]^T  -> fp32 (bias = b_ih)
  gemm_bt<EPI_F32><<<dim3(12, 16), 256, 0, stream>>>(
      Yemb, WgIh, bIhP, giP, nullptr, ROWS, G3, DIN, 12);

  // sequential GRU recurrence -> Xall = h1 * ct (bf16)
  phaseA_k<<<NBLK_A, 256, 0, stream>>>(WgHh, bHhP, giP, ctB, hbuf, Xall, flags);

  // QKV = X @ [Wq;Wk;Wv]^T + b
  gemm_bt<EPI_BF16><<<dim3(12, 16), 256, 0, stream>>>(
      Xall, Wqkv, bQkv, QKV, nullptr, ROWS, G3, DIN, 12);

  attn_k<<<512, 256, 0, stream>>>(QKV, attO);

  // h2 = att @ Wfc^T + bfc
  gemm_bt<EPI_BF16><<<dim3(4, 16), 256, 0, stream>>>(
      attO, WfcB, bfc, h2B, nullptr, ROWS, HID, HID, 4);

  // logit = tanh(h2 @ Wh2o^T + b)
  gemm_bt<EPI_TANH><<<dim3(4, 16), 256, 0, stream>>>(
      h2B, Wh2oB, bh2o, logit, nullptr, ROWS, DIN, HID, 4);

  // e = exp(logit @ W_out^T + b) -> d_out, per-(row, col-block) partial sums
  gemm_bt<EPI_EXP><<<dim3(250 * 16), 256, 0, stream>>>(
      logit, WoutB, b_out, d_out, partial, ROWS, VOCAB, DIN, 250);

  reduce_rows<<<512, 256, 0, stream>>>(partial, rowsum, 250);
  normalize_k<<<ROWS * VOCAB / 4 / 256, 256, 0, stream>>>((float*)d_out, rowsum);
}

// Round 3
// 600.635 us; speedup vs baseline: 1.3053x; 1.1990x over previous
//
#include <hip/hip_runtime.h>
#include <hip/hip_bf16.h>
#include <math.h>

typedef __bf16 bf16_t;
typedef __bf16 bf16x8 __attribute__((ext_vector_type(8)));
typedef __bf16 bf16x4 __attribute__((ext_vector_type(4)));
typedef float  f32x4  __attribute__((ext_vector_type(4)));

#define T_STEPS 32
#define BATCH   64
#define DIN     512
#define HID     512
#define VOCAB   32000
#define FFEAT   768
#define ROWS    2048   /* T*B */
#define G3      1536   /* 3*H */
#define NBLK_A  32

#define EPI_F32  0
#define EPI_BF16 1
#define EPI_TANH 2
#define EPI_SUM  3   /* exp + partial row sums only, no store */
#define EPI_PROB 4   /* exp * 1/rowsum -> f32 store (final probs) */

// async global->LDS, 16B per lane (guide §5: width=16 is the proven fast path)
#define GLOAD16(gp, lp) __builtin_amdgcn_global_load_lds( \
    (const __attribute__((address_space(1))) void*)(gp),  \
    (__attribute__((address_space(3))) void*)(lp), 16, 0, 0)

// ---------------------------------------------------------------------------
// LDS-staged bf16 GEMM (m97 structure): C[M][N] = A[M][K] @ B[N][K]^T + bias.
// 256 thr = 4 waves, block tile 128x128, wave tile 64x64 (4x4 frags of
// 16x16x32 MFMA), BK=32 double-buffered in LDS via global_load_lds dwordx4.
// [128][32] bf16 rows = 64B stride -> wave b128 reads tile all 32 banks
// (volume floor, no conflicts) -> no swizzle needed.
// EPI_SUM/EPI_PROB use a 1D grid + bn-major XCD-chunk swizzle so each XCD's
// L2 keeps one B-panel (128KB) hot across all 16 bm tiles.
// ---------------------------------------------------------------------------
template<int EPI>
__global__ __launch_bounds__(256) void gemm_lds(
    const bf16_t* __restrict__ A, const bf16_t* __restrict__ B,
    const float* __restrict__ bias, void* __restrict__ out,
    float* __restrict__ partial, const float* __restrict__ rowsum,
    int M, int N, int K, int NB)
{
  __shared__ bf16_t As[2][128 * 32];
  __shared__ bf16_t Bs[2][128 * 32];
  __shared__ float psum[128][2];

  const int lane = threadIdx.x & 63;
  const int wv   = threadIdx.x >> 6;
  const int wm = wv >> 1, wn = wv & 1;
  int bn, bm;
  if constexpr (EPI == EPI_SUM || EPI == EPI_PROB) {
    const int lin = blockIdx.x;
    const int nwg = NB * 16;
    const int cpx = nwg >> 3;           // nwg % 8 == 0 (4000/8=500)
    const int wg  = (lin & 7) * cpx + (lin >> 3);
    bn = wg >> 4; bm = wg & 15;
  } else {
    bn = blockIdx.x; bm = blockIdx.y;
  }
  const int la = lane & 15, lg = lane >> 4;
  const int tid = threadIdx.x;

  // stage one 128x32 A-tile + B-tile into buffer `buf` (4 x 16B per thread)
  auto stage = [&](int buf, int k0) {
#pragma unroll
    for (int q = 0; q < 2; ++q) {
      const int idx = q * 256 + tid;
      const int row = idx >> 2, c = idx & 3;
      GLOAD16(A + (size_t)(bm * 128 + row) * K + k0 + c * 8, &As[buf][idx * 8]);
      GLOAD16(B + (size_t)(bn * 128 + row) * K + k0 + c * 8, &Bs[buf][idx * 8]);
    }
  };

  f32x4 acc[4][4] = {};
  const int NT = K >> 5;
  stage(0, 0);
  for (int kt = 0; kt < NT; ++kt) {
    __syncthreads();                    // drains vmcnt -> buf[kt&1] ready
    if (kt + 1 < NT) stage((kt + 1) & 1, (kt + 1) * 32);
    const bf16_t* Ab = As[kt & 1];
    const bf16_t* Bb = Bs[kt & 1];
    bf16x8 a[4], b[4];
#pragma unroll
    for (int i = 0; i < 4; ++i)
      a[i] = *(const bf16x8*)(Ab + (wm * 64 + i * 16 + la) * 32 + lg * 8);
#pragma unroll
    for (int j = 0; j < 4; ++j)
      b[j] = *(const bf16x8*)(Bb + (wn * 64 + j * 16 + la) * 32 + lg * 8);
#pragma unroll
    for (int i = 0; i < 4; ++i)
#pragma unroll
      for (int j = 0; j < 4; ++j)
        acc[i][j] = __builtin_amdgcn_mfma_f32_16x16x32_bf16(a[i], b[j], acc[i][j], 0, 0, 0);
  }

  const int m0 = bm * 128 + wm * 64;
  const int n0 = bn * 128 + wn * 64;
#pragma unroll
  for (int i = 0; i < 4; ++i) {
#pragma unroll
    for (int r = 0; r < 4; ++r) {
      const int row = m0 + i * 16 + lg * 4 + r;
      float vsum = 0.f;
      float inv;
      if constexpr (EPI == EPI_PROB) inv = 1.0f / rowsum[row];
#pragma unroll
      for (int j = 0; j < 4; ++j) {
        const int col = n0 + j * 16 + la;
        float v = acc[i][j][r] + bias[col];
        if constexpr (EPI == EPI_F32) {
          ((float*)out)[(size_t)row * N + col] = v;
        } else if constexpr (EPI == EPI_BF16) {
          ((bf16_t*)out)[(size_t)row * N + col] = (bf16_t)v;
        } else if constexpr (EPI == EPI_TANH) {
          ((bf16_t*)out)[(size_t)row * N + col] = (bf16_t)tanhf(v);
        } else if constexpr (EPI == EPI_SUM) {
          vsum += expf(v);
        } else {  // EPI_PROB
          ((float*)out)[(size_t)row * N + col] = expf(v) * inv;
        }
      }
      if constexpr (EPI == EPI_SUM) {
        vsum += __shfl_xor(vsum, 1);
        vsum += __shfl_xor(vsum, 2);
        vsum += __shfl_xor(vsum, 4);
        vsum += __shfl_xor(vsum, 8);
        if (la == 0) psum[wm * 64 + i * 16 + lg * 4 + r][wn] = vsum;
      }
    }
  }
  if constexpr (EPI == EPI_SUM) {
    __syncthreads();
    if (tid < 128) {
      const int rb = bm * 128 + tid;
      partial[(size_t)rb * NB + bn] = psum[tid][0] + psum[tid][1];
    }
  }
  (void)partial; (void)rowsum; (void)NB;
}

// ---------------------------------------------------------------------------
// Phase A: sequential GRU recurrence. 32 blocks; block g owns h1 cols
// [16g,16g+16). Cross-block h via relaxed AGENT-scope atomics (coherent at
// L2/L3 point, no cache-wide fences); per-wave distributed flags.
// ---------------------------------------------------------------------------
__global__ __launch_bounds__(256) void phaseA_k(
    const bf16_t* __restrict__ Wg, const float* __restrict__ bhh,
    const float* __restrict__ gi, const float* __restrict__ ct,
    unsigned int* __restrict__ hbuf /* u32[2][64][256] bf16-pairs */,
    bf16_t* __restrict__ Xall, int* __restrict__ flags /* [4][32] */)
{
  __shared__ bf16_t Wl[48 * 520];
  __shared__ float bl[48];
  const int tid = threadIdx.x, blk = blockIdx.x;

  for (int i = tid; i < 48 * 64; i += 256) {
    const int rw = i >> 6, ch = (i & 63) << 3;
    *(bf16x8*)(Wl + rw * 520 + ch) = *(const bf16x8*)(Wg + (size_t)(blk * 48 + rw) * 512 + ch);
  }
  if (tid < 48) bl[tid] = bhh[blk * 48 + tid];
  __syncthreads();

  const int lane = tid & 63, wv = tid >> 6;
  const int la = lane & 15, lg = lane >> 4;
  const int jcol = blk * 16 + la;
  const int rowA = wv * 16 + la;

  const float blr = bl[la], blz = bl[16 + la], bln = bl[32 + la];
  float hprev[4], ctv[4];
#pragma unroll
  for (int r = 0; r < 4; ++r) {
    hprev[r] = 0.f;
    ctv[r] = ct[(size_t)(wv * 16 + lg * 4 + r) * HID + jcol];
  }

  for (int t = 0; t < T_STEPS; ++t) {
    const float* girow = gi + (size_t)t * BATCH * G3 + (size_t)blk * 48;
    float gv[12];
#pragma unroll
    for (int r = 0; r < 4; ++r) {
      const float* gp = girow + (size_t)(wv * 16 + lg * 4 + r) * G3;
      gv[r * 3 + 0] = gp[la];
      gv[r * 3 + 1] = gp[16 + la];
      gv[r * 3 + 2] = gp[32 + la];
    }
    if (t > 0) {
      if (lane < 32) {
        while (__hip_atomic_load(&flags[wv * 32 + lane], __ATOMIC_RELAXED,
                                 __HIP_MEMORY_SCOPE_AGENT) < t)
          __builtin_amdgcn_s_sleep(1);
      }
      asm volatile("" ::: "memory");
    }
    const unsigned long long* hb =
        (const unsigned long long*)(hbuf + (size_t)(t & 1) * 64 * 256);
    bf16x8 af[16];
#pragma unroll
    for (int q = 0; q < 16; ++q) {
      union { unsigned long long u[2]; bf16x8 v; } c;
      const size_t bidx = (size_t)rowA * 128 + q * 8 + lg * 2;
      c.u[0] = __hip_atomic_load(hb + bidx,     __ATOMIC_RELAXED, __HIP_MEMORY_SCOPE_AGENT);
      c.u[1] = __hip_atomic_load(hb + bidx + 1, __ATOMIC_RELAXED, __HIP_MEMORY_SCOPE_AGENT);
      af[q] = c.v;
    }
    f32x4 acc0 = {}, acc1 = {}, acc2 = {};
#pragma unroll
    for (int q = 0; q < 16; ++q) {
      const bf16_t* wp = Wl + q * 32 + lg * 8;
      bf16x8 b0 = *(const bf16x8*)(wp + (0 * 16 + la) * 520);
      bf16x8 b1 = *(const bf16x8*)(wp + (1 * 16 + la) * 520);
      bf16x8 b2 = *(const bf16x8*)(wp + (2 * 16 + la) * 520);
      acc0 = __builtin_amdgcn_mfma_f32_16x16x32_bf16(af[q], b0, acc0, 0, 0, 0);
      acc1 = __builtin_amdgcn_mfma_f32_16x16x32_bf16(af[q], b1, acc1, 0, 0, 0);
      acc2 = __builtin_amdgcn_mfma_f32_16x16x32_bf16(af[q], b2, acc2, 0, 0, 0);
    }
    unsigned int* hn = hbuf + (size_t)((t + 1) & 1) * 64 * 256;
#pragma unroll
    for (int r = 0; r < 4; ++r) {
      const int row = wv * 16 + lg * 4 + r;
      const float ghr = acc0[r] + blr;
      const float ghz = acc1[r] + blz;
      const float ghn = acc2[r] + bln;
      const float rr = 1.f / (1.f + expf(-(gv[r * 3 + 0] + ghr)));
      const float zz = 1.f / (1.f + expf(-(gv[r * 3 + 1] + ghz)));
      const float nn = tanhf(gv[r * 3 + 2] + rr * ghn);
      const float h1 = (1.f - zz) * nn + zz * hprev[r];
      hprev[r] = h1;
      Xall[((size_t)t * BATCH + row) * HID + jcol] = (bf16_t)(h1 * ctv[r]);
      const unsigned int mine =
          (unsigned int)__builtin_bit_cast(unsigned short, (bf16_t)h1);
      const unsigned int other = (unsigned int)__shfl_xor((int)mine, 1);
      if ((la & 1) == 0) {
        __hip_atomic_store(hn + (size_t)row * 256 + blk * 8 + (la >> 1),
                           mine | (other << 16), __ATOMIC_RELAXED,
                           __HIP_MEMORY_SCOPE_AGENT);
      }
    }
    asm volatile("s_waitcnt vmcnt(0)" ::: "memory");
    if (lane == 0) {
      __hip_atomic_store(&flags[wv * 32 + blk], t + 1, __ATOMIC_RELAXED,
                         __HIP_MEMORY_SCOPE_AGENT);
    }
  }
}

// ---------------------------------------------------------------------------
// Per-(t,b) 8-head self-attention on a single vector.
// ---------------------------------------------------------------------------
__global__ __launch_bounds__(256) void attn_k(const bf16_t* __restrict__ QKV,
                                              bf16_t* __restrict__ attO)
{
  __shared__ float sq[4][512], sk[4][512], sv[4][512], sw[4][64];
  const int tid = threadIdx.x;
  const int wv = tid >> 6, lane = tid & 63;
  const int row = blockIdx.x * 4 + wv;
  const bf16_t* base = QKV + (size_t)row * G3;
  bf16x8 vq = *(const bf16x8*)(base + lane * 8);
  bf16x8 vk = *(const bf16x8*)(base + 512 + lane * 8);
  bf16x8 vv = *(const bf16x8*)(base + 1024 + lane * 8);
#pragma unroll
  for (int e = 0; e < 8; ++e) {
    sq[wv][lane * 8 + e] = (float)vq[e];
    sk[wv][lane * 8 + e] = (float)vk[e];
    sv[wv][lane * 8 + e] = (float)vv[e];
  }
  __syncthreads();
  const int h = lane >> 3, g = lane & 7;
  float s = 0.f;
#pragma unroll 16
  for (int d = 0; d < 64; ++d) s += sq[wv][h * 64 + d] * sk[wv][g * 64 + d];
  s *= (1.f / 64.f);  // reference divides by head_dim (not sqrt)
  float m = s;
  m = fmaxf(m, __shfl_xor(m, 1));
  m = fmaxf(m, __shfl_xor(m, 2));
  m = fmaxf(m, __shfl_xor(m, 4));
  const float e = expf(s - m);
  float sum = e;
  sum += __shfl_xor(sum, 1);
  sum += __shfl_xor(sum, 2);
  sum += __shfl_xor(sum, 4);
  sw[wv][lane] = e / sum;
  __syncthreads();
#pragma unroll
  for (int rep = 0; rep < 8; ++rep) {
    const int idx = rep * 64 + lane;
    const int hh = idx >> 6, d = idx & 63;
    float o = 0.f;
#pragma unroll
    for (int gg = 0; gg < 8; ++gg) o += sw[wv][hh * 8 + gg] * sv[wv][gg * 64 + d];
    attO[(size_t)row * HID + idx] = (bf16_t)o;
  }
}

// --------------------------- small prep kernels ----------------------------
__global__ __launch_bounds__(256) void cast_k(const float* __restrict__ src,
                                              bf16_t* __restrict__ dst, int n4)
{
  const int i = blockIdx.x * 256 + threadIdx.x;
  if (i >= n4) return;
  float4 v = ((const float4*)src)[i];
  bf16x4 o = {(bf16_t)v.x, (bf16_t)v.y, (bf16_t)v.z, (bf16_t)v.w};
  *(bf16x4*)(dst + (size_t)i * 4) = o;
}

__global__ __launch_bounds__(256) void perm_cast_k(const float* __restrict__ src,
                                                   bf16_t* __restrict__ dst)
{
  const int i = blockIdx.x * 256 + threadIdx.x;  // 1536*128
  const int pg = i >> 7, kq = (i & 127) << 2;
  const int g = pg / 48, rem = pg - g * 48, sec = rem >> 4, jj = rem & 15;
  const int srow = sec * 512 + g * 16 + jj;
  float4 v = *(const float4*)(src + (size_t)srow * DIN + kq);
  bf16x4 o = {(bf16_t)v.x, (bf16_t)v.y, (bf16_t)v.z, (bf16_t)v.w};
  *(bf16x4*)(dst + (size_t)pg * DIN + kq) = o;
}

__global__ void perm_bias_k(const float* __restrict__ bih, const float* __restrict__ bhh,
                            float* __restrict__ bihp, float* __restrict__ bhhp)
{
  const int pg = blockIdx.x * 256 + threadIdx.x;
  if (pg >= G3) return;
  const int g = pg / 48, rem = pg - g * 48, sec = rem >> 4, jj = rem & 15;
  const int srow = sec * 512 + g * 16 + jj;
  bihp[pg] = bih[srow];
  bhhp[pg] = bhh[srow];
}

__global__ void bcat_k(const float* __restrict__ a, const float* __restrict__ b,
                       const float* __restrict__ c, float* __restrict__ d)
{
  const int i = blockIdx.x * 256 + threadIdx.x;
  if (i >= G3) return;
  d[i] = i < 512 ? a[i] : (i < 1024 ? b[i - 512] : c[i - 1024]);
}

__global__ __launch_bounds__(256) void yemb_k(const int* __restrict__ y,
                                              const float* __restrict__ embW,
                                              bf16_t* __restrict__ out)
{
  const int idx = blockIdx.x * 256 + threadIdx.x;  // 2048*64
  const int rb = idx >> 6, c = (idx & 63) << 3;
  const int tok = y[rb];
  const float4* s = (const float4*)(embW + (size_t)tok * DIN + c);
  float4 v0 = s[0], v1 = s[1];
  bf16x8 o = {(bf16_t)v0.x, (bf16_t)v0.y, (bf16_t)v0.z, (bf16_t)v0.w,
              (bf16_t)v1.x, (bf16_t)v1.y, (bf16_t)v1.z, (bf16_t)v1.w};
  *(bf16x8*)(out + (size_t)rb * DIN + c) = o;
}

__global__ __launch_bounds__(256) void ct_k(const float* __restrict__ ctx,
                                            const float* __restrict__ Watt,
                                            const float* __restrict__ batt,
                                            float* __restrict__ ct)
{
  const int idx = blockIdx.x * 256 + threadIdx.x;  // 64*512
  const int b = idx >> 9, j = idx & 511;
  const float4* c4 = (const float4*)(ctx + (size_t)b * FFEAT);
  const float4* w4 = (const float4*)(Watt + (size_t)j * FFEAT);
  float s = batt[j];
  for (int q = 0; q < FFEAT / 4; ++q) {
    float4 cc = c4[q], ww = w4[q];
    s += cc.x * ww.x + cc.y * ww.y + cc.z * ww.z + cc.w * ww.w;
  }
  ct[idx] = tanhf(s);
}

__global__ __launch_bounds__(256) void reduce_rows(const float* __restrict__ partial,
                                                   float* __restrict__ rowsum, int NB)
{
  const int wv = threadIdx.x >> 6, lane = threadIdx.x & 63;
  const int row = blockIdx.x * 4 + wv;
  float s = 0.f;
  for (int c = lane; c < NB; c += 64) s += partial[(size_t)row * NB + c];
  for (int m = 1; m < 64; m <<= 1) s += __shfl_xor(s, m);
  if (lane == 0) rowsum[row] = s;
}

// ---------------------------------------------------------------------------
extern "C" void kernel_launch(void* const* d_in, const int* in_sizes, int n_in,
                              void* d_out, int out_size, void* d_ws, size_t ws_size,
                              hipStream_t stream)
{
  const int*   y     = (const int*)  d_in[0];
  const float* ctx   = (const float*)d_in[1];
  const float* embW  = (const float*)d_in[2];
  const float* W_ih  = (const float*)d_in[3];
  const float* b_ih  = (const float*)d_in[4];
  const float* W_hh  = (const float*)d_in[5];
  const float* b_hh  = (const float*)d_in[6];
  const float* W_att = (const float*)d_in[7];
  const float* b_att = (const float*)d_in[8];
  const float* Wq    = (const float*)d_in[9];
  const float* bq    = (const float*)d_in[10];
  const float* Wk    = (const float*)d_in[11];
  const float* bk    = (const float*)d_in[12];
  const float* Wv    = (const float*)d_in[13];
  const float* bv    = (const float*)d_in[14];
  const float* Wfc   = (const float*)d_in[15];
  const float* bfc   = (const float*)d_in[16];
  const float* Wh2o  = (const float*)d_in[17];
  const float* bh2o  = (const float*)d_in[18];
  const float* W_out = (const float*)d_in[19];
  const float* b_out = (const float*)d_in[20];

  char* p = (char*)d_ws;
  auto alloc = [&](size_t bytes) {
    char* r = p;
    p += (bytes + 255) & ~(size_t)255;
    return r;
  };
  bf16_t* WoutB   = (bf16_t*)alloc((size_t)VOCAB * DIN * 2);
  bf16_t* WgIh    = (bf16_t*)alloc((size_t)G3 * DIN * 2);
  bf16_t* WgHh    = (bf16_t*)alloc((size_t)G3 * DIN * 2);
  bf16_t* Wqkv    = (bf16_t*)alloc((size_t)G3 * DIN * 2);
  bf16_t* WfcB    = (bf16_t*)alloc((size_t)HID * HID * 2);
  bf16_t* Wh2oB   = (bf16_t*)alloc((size_t)HID * HID * 2);
  float*  bIhP    = (float*)alloc(G3 * 4);
  float*  bHhP    = (float*)alloc(G3 * 4);
  float*  bQkv    = (float*)alloc(G3 * 4);
  bf16_t* Yemb    = (bf16_t*)alloc((size_t)ROWS * DIN * 2);
  float*  giP     = (float*)alloc((size_t)ROWS * G3 * 4);
  float*  ctB     = (float*)alloc((size_t)BATCH * HID * 4);
  unsigned int* hbuf = (unsigned int*)alloc((size_t)2 * BATCH * (HID / 2) * 4);
  bf16_t* Xall    = (bf16_t*)alloc((size_t)ROWS * DIN * 2);
  bf16_t* QKV     = (bf16_t*)alloc((size_t)ROWS * G3 * 2);
  bf16_t* attO    = (bf16_t*)alloc((size_t)ROWS * HID * 2);
  bf16_t* h2B     = (bf16_t*)alloc((size_t)ROWS * HID * 2);
  bf16_t* logit   = (bf16_t*)alloc((size_t)ROWS * DIN * 2);
  float*  partial = (float*)alloc((size_t)ROWS * 250 * 4);
  float*  rowsum  = (float*)alloc((size_t)ROWS * 4);
  int*    flags   = (int*)alloc(512);

  hipMemsetAsync(hbuf, 0, (size_t)2 * BATCH * (HID / 2) * 4, stream);  // h0 = 0
  hipMemsetAsync(flags, 0, 512, stream);

  // weight prep
  cast_k<<<(VOCAB * DIN / 4 + 255) / 256, 256, 0, stream>>>(W_out, WoutB, VOCAB * DIN / 4);
  cast_k<<<256, 256, 0, stream>>>(Wq, Wqkv, HID * HID / 4);
  cast_k<<<256, 256, 0, stream>>>(Wk, Wqkv + (size_t)HID * DIN, HID * HID / 4);
  cast_k<<<256, 256, 0, stream>>>(Wv, Wqkv + (size_t)2 * HID * DIN, HID * HID / 4);
  cast_k<<<256, 256, 0, stream>>>(Wfc, WfcB, HID * HID / 4);
  cast_k<<<256, 256, 0, stream>>>(Wh2o, Wh2oB, HID * HID / 4);
  perm_cast_k<<<768, 256, 0, stream>>>(W_ih, WgIh);
  perm_cast_k<<<768, 256, 0, stream>>>(W_hh, WgHh);
  perm_bias_k<<<6, 256, 0, stream>>>(b_ih, b_hh, bIhP, bHhP);
  bcat_k<<<6, 256, 0, stream>>>(bq, bk, bv, bQkv);
  yemb_k<<<512, 256, 0, stream>>>(y, embW, Yemb);
  ct_k<<<128, 256, 0, stream>>>(ctx, W_att, b_att, ctB);

  // gi for all steps: [2048,512] @ [1536,512]^T -> fp32 (bias = b_ih)
  gemm_lds<EPI_F32><<<dim3(12, 16), 256, 0, stream>>>(
      Yemb, WgIh, bIhP, giP, nullptr, nullptr, ROWS, G3, DIN, 12);

  // sequential GRU recurrence -> Xall = h1 * ct (bf16)
  phaseA_k<<<NBLK_A, 256, 0, stream>>>(WgHh, bHhP, giP, ctB, hbuf, Xall, flags);

  // QKV = X @ [Wq;Wk;Wv]^T + b
  gemm_lds<EPI_BF16><<<dim3(12, 16), 256, 0, stream>>>(
      Xall, Wqkv, bQkv, QKV, nullptr, nullptr, ROWS, G3, DIN, 12);

  attn_k<<<512, 256, 0, stream>>>(QKV, attO);

  // h2 = att @ Wfc^T + bfc
  gemm_lds<EPI_BF16><<<dim3(4, 16), 256, 0, stream>>>(
      attO, WfcB, bfc, h2B, nullptr, nullptr, ROWS, HID, HID, 4);

  // logit = tanh(h2 @ Wh2o^T + b)
  gemm_lds<EPI_TANH><<<dim3(4, 16), 256, 0, stream>>>(
      h2B, Wh2oB, bh2o, logit, nullptr, nullptr, ROWS, DIN, HID, 4);

  // pass 1: rowsums of exp(logit @ W_out^T + b) -- no 262MB store
  gemm_lds<EPI_SUM><<<dim3(250 * 16), 256, 0, stream>>>(
      logit, WoutB, b_out, nullptr, partial, nullptr, ROWS, VOCAB, DIN, 250);
  reduce_rows<<<512, 256, 0, stream>>>(partial, rowsum, 250);
  // pass 2: recompute, write normalized f32 probs directly
  gemm_lds<EPI_PROB><<<dim3(250 * 16), 256, 0, stream>>>(
      logit, WoutB, b_out, d_out, nullptr, rowsum, ROWS, VOCAB, DIN, 250);
}

// Round 4
// 520.038 us; speedup vs baseline: 1.5076x; 1.1550x over previous
//
#include <hip/hip_runtime.h>
#include <hip/hip_bf16.h>
#include <math.h>

typedef __bf16 bf16_t;
typedef __bf16 bf16x8 __attribute__((ext_vector_type(8)));
typedef __bf16 bf16x4 __attribute__((ext_vector_type(4)));
typedef float  f32x4  __attribute__((ext_vector_type(4)));

#define T_STEPS 32
#define BATCH   64
#define DIN     512
#define HID     512
#define VOCAB   32000
#define FFEAT   768
#define ROWS    2048   /* T*B */
#define G3      1536   /* 3*H */
#define NBLK_A  32

#define EPI_F32  0
#define EPI_BF16 1
#define EPI_TANH 2
#define EPI_SUM  3   /* exp + partial row sums only, no store */
#define EPI_PROB 4   /* exp * 1/rowsum -> f32 store (final probs) */

// async global->LDS, 16B per lane (guide §5: width=16 is the proven fast path)
#define GLOAD16(gp, lp) __builtin_amdgcn_global_load_lds( \
    (const __attribute__((address_space(1))) void*)(gp),  \
    (__attribute__((address_space(3))) void*)(lp), 16, 0, 0)

// ---------------------------------------------------------------------------
// LDS-staged bf16 GEMM (m97 structure): C[M][N] = A[M][K] @ B[N][K]^T + bias.
// 256 thr = 4 waves, block tile 128x128, wave tile 64x64 (4x4 frags of
// 16x16x32 MFMA), BK=32 double-buffered in LDS via global_load_lds dwordx4.
// [128][32] bf16 rows = 64B stride -> wave b128 reads tile all 32 banks.
// EPI_SUM/EPI_PROB: 1D grid + bn-major XCD-chunk swizzle (B-panel stays in
// one XCD's L2 across all 16 bm tiles).
// ---------------------------------------------------------------------------
template<int EPI>
__global__ __launch_bounds__(256) void gemm_lds(
    const bf16_t* __restrict__ A, const bf16_t* __restrict__ B,
    const float* __restrict__ bias, void* __restrict__ out,
    float* __restrict__ partial, const float* __restrict__ rowsum,
    int M, int N, int K, int NB)
{
  __shared__ bf16_t As[2][128 * 32];
  __shared__ bf16_t Bs[2][128 * 32];
  __shared__ float psum[128][2];

  const int lane = threadIdx.x & 63;
  const int wv   = threadIdx.x >> 6;
  const int wm = wv >> 1, wn = wv & 1;
  int bn, bm;
  if constexpr (EPI == EPI_SUM || EPI == EPI_PROB) {
    const int lin = blockIdx.x;
    const int nwg = NB * 16;
    const int cpx = nwg >> 3;           // nwg % 8 == 0 (4000/8=500)
    const int wg  = (lin & 7) * cpx + (lin >> 3);
    bn = wg >> 4; bm = wg & 15;
  } else {
    bn = blockIdx.x; bm = blockIdx.y;
  }
  const int la = lane & 15, lg = lane >> 4;
  const int tid = threadIdx.x;

  auto stage = [&](int buf, int k0) {
#pragma unroll
    for (int q = 0; q < 2; ++q) {
      const int idx = q * 256 + tid;
      const int row = idx >> 2, c = idx & 3;
      GLOAD16(A + (size_t)(bm * 128 + row) * K + k0 + c * 8, &As[buf][idx * 8]);
      GLOAD16(B + (size_t)(bn * 128 + row) * K + k0 + c * 8, &Bs[buf][idx * 8]);
    }
  };

  f32x4 acc[4][4] = {};
  const int NT = K >> 5;
  stage(0, 0);
  for (int kt = 0; kt < NT; ++kt) {
    __syncthreads();                    // drains vmcnt -> buf[kt&1] ready
    if (kt + 1 < NT) stage((kt + 1) & 1, (kt + 1) * 32);
    const bf16_t* Ab = As[kt & 1];
    const bf16_t* Bb = Bs[kt & 1];
    bf16x8 a[4], b[4];
#pragma unroll
    for (int i = 0; i < 4; ++i)
      a[i] = *(const bf16x8*)(Ab + (wm * 64 + i * 16 + la) * 32 + lg * 8);
#pragma unroll
    for (int j = 0; j < 4; ++j)
      b[j] = *(const bf16x8*)(Bb + (wn * 64 + j * 16 + la) * 32 + lg * 8);
#pragma unroll
    for (int i = 0; i < 4; ++i)
#pragma unroll
      for (int j = 0; j < 4; ++j)
        acc[i][j] = __builtin_amdgcn_mfma_f32_16x16x32_bf16(a[i], b[j], acc[i][j], 0, 0, 0);
  }

  const int m0 = bm * 128 + wm * 64;
  const int n0 = bn * 128 + wn * 64;
#pragma unroll
  for (int i = 0; i < 4; ++i) {
#pragma unroll
    for (int r = 0; r < 4; ++r) {
      const int row = m0 + i * 16 + lg * 4 + r;
      float vsum = 0.f;
      float inv;
      if constexpr (EPI == EPI_PROB) inv = 1.0f / rowsum[row];
#pragma unroll
      for (int j = 0; j < 4; ++j) {
        const int col = n0 + j * 16 + la;
        float v = acc[i][j][r] + bias[col];
        if constexpr (EPI == EPI_F32) {
          ((float*)out)[(size_t)row * N + col] = v;
        } else if constexpr (EPI == EPI_BF16) {
          ((bf16_t*)out)[(size_t)row * N + col] = (bf16_t)v;
        } else if constexpr (EPI == EPI_TANH) {
          ((bf16_t*)out)[(size_t)row * N + col] = (bf16_t)tanhf(v);
        } else if constexpr (EPI == EPI_SUM) {
          vsum += expf(v);
        } else {  // EPI_PROB
          ((float*)out)[(size_t)row * N + col] = expf(v) * inv;
        }
      }
      if constexpr (EPI == EPI_SUM) {
        vsum += __shfl_xor(vsum, 1);
        vsum += __shfl_xor(vsum, 2);
        vsum += __shfl_xor(vsum, 4);
        vsum += __shfl_xor(vsum, 8);
        if (la == 0) psum[wm * 64 + i * 16 + lg * 4 + r][wn] = vsum;
      }
    }
  }
  if constexpr (EPI == EPI_SUM) {
    __syncthreads();
    if (tid < 128) {
      const int rb = bm * 128 + tid;
      partial[(size_t)rb * NB + bn] = psum[tid][0] + psum[tid][1];
    }
  }
  (void)partial; (void)rowsum; (void)NB;
}

// ---------------------------------------------------------------------------
// Phase A: sequential GRU recurrence. 32 blocks; block g owns h1 cols
// [16g,16g+16). Contention-free cross-block exchange:
//  - h layout [parity][blk][row][8 u32]: each block's 2KB region is
//    line-exclusive (no cross-block WAW serialization at the fabric).
//  - flags one 64B line per (blk,wave): flags[(blk*4+wv)*16].
//  - flag raised after h stores drain (vmcnt0); Xall stores issued AFTER the
//    flag so their latency overlaps the next step's poll.
// ---------------------------------------------------------------------------
__global__ __launch_bounds__(256) void phaseA_k(
    const bf16_t* __restrict__ Wg, const float* __restrict__ bhh,
    const float* __restrict__ gi, const float* __restrict__ ct,
    unsigned int* __restrict__ hbuf /* u32[2][32][64][8] */,
    bf16_t* __restrict__ Xall, int* __restrict__ flags /* [(blk*4+wv)*16] */)
{
  __shared__ bf16_t Wl[48 * 520];
  __shared__ float bl[48];
  const int tid = threadIdx.x, blk = blockIdx.x;

  for (int i = tid; i < 48 * 64; i += 256) {
    const int rw = i >> 6, ch = (i & 63) << 3;
    *(bf16x8*)(Wl + rw * 520 + ch) = *(const bf16x8*)(Wg + (size_t)(blk * 48 + rw) * 512 + ch);
  }
  if (tid < 48) bl[tid] = bhh[blk * 48 + tid];
  __syncthreads();

  const int lane = tid & 63, wv = tid >> 6;
  const int la = lane & 15, lg = lane >> 4;
  const int jcol = blk * 16 + la;
  const int rowA = wv * 16 + la;          // A-fragment row this lane loads

  const float blr = bl[la], blz = bl[16 + la], bln = bl[32 + la];
  float hprev[4], ctv[4];
#pragma unroll
  for (int r = 0; r < 4; ++r) {
    hprev[r] = 0.f;
    ctv[r] = ct[(size_t)(wv * 16 + lg * 4 + r) * HID + jcol];
  }

  for (int t = 0; t < T_STEPS; ++t) {
    // ---- gi prefetch (overlaps the poll)
    const float* girow = gi + (size_t)t * BATCH * G3 + (size_t)blk * 48;
    float gv[12];
#pragma unroll
    for (int r = 0; r < 4; ++r) {
      const float* gp = girow + (size_t)(wv * 16 + lg * 4 + r) * G3;
      gv[r * 3 + 0] = gp[la];
      gv[r * 3 + 1] = gp[16 + la];
      gv[r * 3 + 2] = gp[32 + la];
    }
    // ---- wait: wave w needs flag[blk=lane][w] >= t (each flag own line)
    if (t > 0) {
      if (lane < 32) {
        while (__hip_atomic_load(&flags[(lane * 4 + wv) * 16], __ATOMIC_RELAXED,
                                 __HIP_MEMORY_SCOPE_AGENT) < t)
          __builtin_amdgcn_s_sleep(1);
      }
      asm volatile("" ::: "memory");
    }
    // ---- load A fragments: af[q] = 8 bf16 at (rowA, cols 32q+8lg..+8)
    // layout u64: blk'*256 + rowA*4 + (lg&1)*2, blk' = 2q + (lg>>1)
    const unsigned long long* hb =
        (const unsigned long long*)(hbuf + (size_t)(t & 1) * 16384);
    bf16x8 af[16];
#pragma unroll
    for (int q = 0; q < 16; ++q) {
      union { unsigned long long u[2]; bf16x8 v; } c;
      const size_t bidx = (size_t)(2 * q + (lg >> 1)) * 256 + rowA * 4 + (lg & 1) * 2;
      c.u[0] = __hip_atomic_load(hb + bidx,     __ATOMIC_RELAXED, __HIP_MEMORY_SCOPE_AGENT);
      c.u[1] = __hip_atomic_load(hb + bidx + 1, __ATOMIC_RELAXED, __HIP_MEMORY_SCOPE_AGENT);
      af[q] = c.v;
    }
    // ---- MFMA: gh = h @ Whh_slice^T (48 cols = r,z,n x 16)
    f32x4 acc0 = {}, acc1 = {}, acc2 = {};
#pragma unroll
    for (int q = 0; q < 16; ++q) {
      const bf16_t* wp = Wl + q * 32 + lg * 8;
      bf16x8 b0 = *(const bf16x8*)(wp + (0 * 16 + la) * 520);
      bf16x8 b1 = *(const bf16x8*)(wp + (1 * 16 + la) * 520);
      bf16x8 b2 = *(const bf16x8*)(wp + (2 * 16 + la) * 520);
      acc0 = __builtin_amdgcn_mfma_f32_16x16x32_bf16(af[q], b0, acc0, 0, 0, 0);
      acc1 = __builtin_amdgcn_mfma_f32_16x16x32_bf16(af[q], b1, acc1, 0, 0, 0);
      acc2 = __builtin_amdgcn_mfma_f32_16x16x32_bf16(af[q], b2, acc2, 0, 0, 0);
    }
    // ---- gates + h1 (registers first)
    float h1v[4];
#pragma unroll
    for (int r = 0; r < 4; ++r) {
      const float ghr = acc0[r] + blr;
      const float ghz = acc1[r] + blz;
      const float ghn = acc2[r] + bln;
      const float rr = 1.f / (1.f + expf(-(gv[r * 3 + 0] + ghr)));
      const float zz = 1.f / (1.f + expf(-(gv[r * 3 + 1] + ghz)));
      const float nn = tanhf(gv[r * 3 + 2] + rr * ghn);
      h1v[r] = (1.f - zz) * nn + zz * hprev[r];
      hprev[r] = h1v[r];
    }
    // ---- h stores (block-exclusive lines), then flag, then Xall
    unsigned int* hn = hbuf + (size_t)((t + 1) & 1) * 16384 + blk * 512;
#pragma unroll
    for (int r = 0; r < 4; ++r) {
      const int row = wv * 16 + lg * 4 + r;
      const unsigned int mine =
          (unsigned int)__builtin_bit_cast(unsigned short, (bf16_t)h1v[r]);
      const unsigned int other = (unsigned int)__shfl_xor((int)mine, 1);
      if ((la & 1) == 0) {
        __hip_atomic_store(hn + row * 8 + (la >> 1), mine | (other << 16),
                           __ATOMIC_RELAXED, __HIP_MEMORY_SCOPE_AGENT);
      }
    }
    asm volatile("s_waitcnt vmcnt(0)" ::: "memory");
    if (lane == 0) {
      __hip_atomic_store(&flags[(blk * 4 + wv) * 16], t + 1, __ATOMIC_RELAXED,
                         __HIP_MEMORY_SCOPE_AGENT);
    }
#pragma unroll
    for (int r = 0; r < 4; ++r) {
      const int row = wv * 16 + lg * 4 + r;
      Xall[((size_t)t * BATCH + row) * HID + jcol] = (bf16_t)(h1v[r] * ctv[r]);
    }
  }
}

// ---------------------------------------------------------------------------
// Per-(t,b) 8-head self-attention on a single vector.
// ---------------------------------------------------------------------------
__global__ __launch_bounds__(256) void attn_k(const bf16_t* __restrict__ QKV,
                                              bf16_t* __restrict__ attO)
{
  __shared__ float sq[4][512], sk[4][512], sv[4][512], sw[4][64];
  const int tid = threadIdx.x;
  const int wv = tid >> 6, lane = tid & 63;
  const int row = blockIdx.x * 4 + wv;
  const bf16_t* base = QKV + (size_t)row * G3;
  bf16x8 vq = *(const bf16x8*)(base + lane * 8);
  bf16x8 vk = *(const bf16x8*)(base + 512 + lane * 8);
  bf16x8 vv = *(const bf16x8*)(base + 1024 + lane * 8);
#pragma unroll
  for (int e = 0; e < 8; ++e) {
    sq[wv][lane * 8 + e] = (float)vq[e];
    sk[wv][lane * 8 + e] = (float)vk[e];
    sv[wv][lane * 8 + e] = (float)vv[e];
  }
  __syncthreads();
  const int h = lane >> 3, g = lane & 7;
  float s = 0.f;
#pragma unroll 16
  for (int d = 0; d < 64; ++d) s += sq[wv][h * 64 + d] * sk[wv][g * 64 + d];
  s *= (1.f / 64.f);  // reference divides by head_dim (not sqrt)
  float m = s;
  m = fmaxf(m, __shfl_xor(m, 1));
  m = fmaxf(m, __shfl_xor(m, 2));
  m = fmaxf(m, __shfl_xor(m, 4));
  const float e = expf(s - m);
  float sum = e;
  sum += __shfl_xor(sum, 1);
  sum += __shfl_xor(sum, 2);
  sum += __shfl_xor(sum, 4);
  sw[wv][lane] = e / sum;
  __syncthreads();
#pragma unroll
  for (int rep = 0; rep < 8; ++rep) {
    const int idx = rep * 64 + lane;
    const int hh = idx >> 6, d = idx & 63;
    float o = 0.f;
#pragma unroll
    for (int gg = 0; gg < 8; ++gg) o += sw[wv][hh * 8 + gg] * sv[wv][gg * 64 + d];
    attO[(size_t)row * HID + idx] = (bf16_t)o;
  }
}

// --------------------------- small prep kernels ----------------------------
__global__ __launch_bounds__(256) void cast_k(const float* __restrict__ src,
                                              bf16_t* __restrict__ dst, int n4)
{
  const int i = blockIdx.x * 256 + threadIdx.x;
  if (i >= n4) return;
  float4 v = ((const float4*)src)[i];
  bf16x4 o = {(bf16_t)v.x, (bf16_t)v.y, (bf16_t)v.z, (bf16_t)v.w};
  *(bf16x4*)(dst + (size_t)i * 4) = o;
}

__global__ __launch_bounds__(256) void perm_cast_k(const float* __restrict__ src,
                                                   bf16_t* __restrict__ dst)
{
  const int i = blockIdx.x * 256 + threadIdx.x;  // 1536*128
  const int pg = i >> 7, kq = (i & 127) << 2;
  const int g = pg / 48, rem = pg - g * 48, sec = rem >> 4, jj = rem & 15;
  const int srow = sec * 512 + g * 16 + jj;
  float4 v = *(const float4*)(src + (size_t)srow * DIN + kq);
  bf16x4 o = {(bf16_t)v.x, (bf16_t)v.y, (bf16_t)v.z, (bf16_t)v.w};
  *(bf16x4*)(dst + (size_t)pg * DIN + kq) = o;
}

__global__ void perm_bias_k(const float* __restrict__ bih, const float* __restrict__ bhh,
                            float* __restrict__ bihp, float* __restrict__ bhhp)
{
  const int pg = blockIdx.x * 256 + threadIdx.x;
  if (pg >= G3) return;
  const int g = pg / 48, rem = pg - g * 48, sec = rem >> 4, jj = rem & 15;
  const int srow = sec * 512 + g * 16 + jj;
  bihp[pg] = bih[srow];
  bhhp[pg] = bhh[srow];
}

__global__ void bcat_k(const float* __restrict__ a, const float* __restrict__ b,
                       const float* __restrict__ c, float* __restrict__ d)
{
  const int i = blockIdx.x * 256 + threadIdx.x;
  if (i >= G3) return;
  d[i] = i < 512 ? a[i] : (i < 1024 ? b[i - 512] : c[i - 1024]);
}

__global__ __launch_bounds__(256) void yemb_k(const int* __restrict__ y,
                                              const float* __restrict__ embW,
                                              bf16_t* __restrict__ out)
{
  const int idx = blockIdx.x * 256 + threadIdx.x;  // 2048*64
  const int rb = idx >> 6, c = (idx & 63) << 3;
  const int tok = y[rb];
  const float4* s = (const float4*)(embW + (size_t)tok * DIN + c);
  float4 v0 = s[0], v1 = s[1];
  bf16x8 o = {(bf16_t)v0.x, (bf16_t)v0.y, (bf16_t)v0.z, (bf16_t)v0.w,
              (bf16_t)v1.x, (bf16_t)v1.y, (bf16_t)v1.z, (bf16_t)v1.w};
  *(bf16x8*)(out + (size_t)rb * DIN + c) = o;
}

__global__ __launch_bounds__(256) void ct_k(const float* __restrict__ ctx,
                                            const float* __restrict__ Watt,
                                            const float* __restrict__ batt,
                                            float* __restrict__ ct)
{
  const int idx = blockIdx.x * 256 + threadIdx.x;  // 64*512
  const int b = idx >> 9, j = idx & 511;
  const float4* c4 = (const float4*)(ctx + (size_t)b * FFEAT);
  const float4* w4 = (const float4*)(Watt + (size_t)j * FFEAT);
  float s = batt[j];
  for (int q = 0; q < FFEAT / 4; ++q) {
    float4 cc = c4[q], ww = w4[q];
    s += cc.x * ww.x + cc.y * ww.y + cc.z * ww.z + cc.w * ww.w;
  }
  ct[idx] = tanhf(s);
}

__global__ __launch_bounds__(256) void reduce_rows(const float* __restrict__ partial,
                                                   float* __restrict__ rowsum, int NB)
{
  const int wv = threadIdx.x >> 6, lane = threadIdx.x & 63;
  const int row = blockIdx.x * 4 + wv;
  float s = 0.f;
  for (int c = lane; c < NB; c += 64) s += partial[(size_t)row * NB + c];
  for (int m = 1; m < 64; m <<= 1) s += __shfl_xor(s, m);
  if (lane == 0) rowsum[row] = s;
}

// ---------------------------------------------------------------------------
extern "C" void kernel_launch(void* const* d_in, const int* in_sizes, int n_in,
                              void* d_out, int out_size, void* d_ws, size_t ws_size,
                              hipStream_t stream)
{
  const int*   y     = (const int*)  d_in[0];
  const float* ctx   = (const float*)d_in[1];
  const float* embW  = (const float*)d_in[2];
  const float* W_ih  = (const float*)d_in[3];
  const float* b_ih  = (const float*)d_in[4];
  const float* W_hh  = (const float*)d_in[5];
  const float* b_hh  = (const float*)d_in[6];
  const float* W_att = (const float*)d_in[7];
  const float* b_att = (const float*)d_in[8];
  const float* Wq    = (const float*)d_in[9];
  const float* bq    = (const float*)d_in[10];
  const float* Wk    = (const float*)d_in[11];
  const float* bk    = (const float*)d_in[12];
  const float* Wv    = (const float*)d_in[13];
  const float* bv    = (const float*)d_in[14];
  const float* Wfc   = (const float*)d_in[15];
  const float* bfc   = (const float*)d_in[16];
  const float* Wh2o  = (const float*)d_in[17];
  const float* bh2o  = (const float*)d_in[18];
  const float* W_out = (const float*)d_in[19];
  const float* b_out = (const float*)d_in[20];

  char* p = (char*)d_ws;
  auto alloc = [&](size_t bytes) {
    char* r = p;
    p += (bytes + 255) & ~(size_t)255;
    return r;
  };
  bf16_t* WoutB   = (bf16_t*)alloc((size_t)VOCAB * DIN * 2);
  bf16_t* WgIh    = (bf16_t*)alloc((size_t)G3 * DIN * 2);
  bf16_t* WgHh    = (bf16_t*)alloc((size_t)G3 * DIN * 2);
  bf16_t* Wqkv    = (bf16_t*)alloc((size_t)G3 * DIN * 2);
  bf16_t* WfcB    = (bf16_t*)alloc((size_t)HID * HID * 2);
  bf16_t* Wh2oB   = (bf16_t*)alloc((size_t)HID * HID * 2);
  float*  bIhP    = (float*)alloc(G3 * 4);
  float*  bHhP    = (float*)alloc(G3 * 4);
  float*  bQkv    = (float*)alloc(G3 * 4);
  bf16_t* Yemb    = (bf16_t*)alloc((size_t)ROWS * DIN * 2);
  float*  giP     = (float*)alloc((size_t)ROWS * G3 * 4);
  float*  ctB     = (float*)alloc((size_t)BATCH * HID * 4);
  unsigned int* hbuf = (unsigned int*)alloc((size_t)2 * 16384 * 4);
  bf16_t* Xall    = (bf16_t*)alloc((size_t)ROWS * DIN * 2);
  bf16_t* QKV     = (bf16_t*)alloc((size_t)ROWS * G3 * 2);
  bf16_t* attO    = (bf16_t*)alloc((size_t)ROWS * HID * 2);
  bf16_t* h2B     = (bf16_t*)alloc((size_t)ROWS * HID * 2);
  bf16_t* logit   = (bf16_t*)alloc((size_t)ROWS * DIN * 2);
  float*  partial = (float*)alloc((size_t)ROWS * 250 * 4);
  float*  rowsum  = (float*)alloc((size_t)ROWS * 4);
  int*    flags   = (int*)alloc(32 * 4 * 64);

  hipMemsetAsync(hbuf, 0, (size_t)2 * 16384 * 4, stream);  // h0 = 0
  hipMemsetAsync(flags, 0, 32 * 4 * 64, stream);

  // weight prep
  cast_k<<<(VOCAB * DIN / 4 + 255) / 256, 256, 0, stream>>>(W_out, WoutB, VOCAB * DIN / 4);
  cast_k<<<256, 256, 0, stream>>>(Wq, Wqkv, HID * HID / 4);
  cast_k<<<256, 256, 0, stream>>>(Wk, Wqkv + (size_t)HID * DIN, HID * HID / 4);
  cast_k<<<256, 256, 0, stream>>>(Wv, Wqkv + (size_t)2 * HID * DIN, HID * HID / 4);
  cast_k<<<256, 256, 0, stream>>>(Wfc, WfcB, HID * HID / 4);
  cast_k<<<256, 256, 0, stream>>>(Wh2o, Wh2oB, HID * HID / 4);
  perm_cast_k<<<768, 256, 0, stream>>>(W_ih, WgIh);
  perm_cast_k<<<768, 256, 0, stream>>>(W_hh, WgHh);
  perm_bias_k<<<6, 256, 0, stream>>>(b_ih, b_hh, bIhP, bHhP);
  bcat_k<<<6, 256, 0, stream>>>(bq, bk, bv, bQkv);
  yemb_k<<<512, 256, 0, stream>>>(y, embW, Yemb);
  ct_k<<<128, 256, 0, stream>>>(ctx, W_att, b_att, ctB);

  // gi for all steps: [2048,512] @ [1536,512]^T -> fp32 (bias = b_ih)
  gemm_lds<EPI_F32><<<dim3(12, 16), 256, 0, stream>>>(
      Yemb, WgIh, bIhP, giP, nullptr, nullptr, ROWS, G3, DIN, 12);

  // sequential GRU recurrence -> Xall = h1 * ct (bf16)
  phaseA_k<<<NBLK_A, 256, 0, stream>>>(WgHh, bHhP, giP, ctB, hbuf, Xall, flags);

  // QKV = X @ [Wq;Wk;Wv]^T + b
  gemm_lds<EPI_BF16><<<dim3(12, 16), 256, 0, stream>>>(
      Xall, Wqkv, bQkv, QKV, nullptr, nullptr, ROWS, G3, DIN, 12);

  attn_k<<<512, 256, 0, stream>>>(QKV, attO);

  // h2 = att @ Wfc^T + bfc
  gemm_lds<EPI_BF16><<<dim3(4, 16), 256, 0, stream>>>(
      attO, WfcB, bfc, h2B, nullptr, nullptr, ROWS, HID, HID, 4);

  // logit = tanh(h2 @ Wh2o^T + b)
  gemm_lds<EPI_TANH><<<dim3(4, 16), 256, 0, stream>>>(
      h2B, Wh2oB, bh2o, logit, nullptr, nullptr, ROWS, DIN, HID, 4);

  // pass 1: rowsums of exp(logit @ W_out^T + b) -- no 262MB store
  gemm_lds<EPI_SUM><<<dim3(250 * 16), 256, 0, stream>>>(
      logit, WoutB, b_out, nullptr, partial, nullptr, ROWS, VOCAB, DIN, 250);
  reduce_rows<<<512, 256, 0, stream>>>(partial, rowsum, 250);
  // pass 2: recompute, write normalized f32 probs directly
  gemm_lds<EPI_PROB><<<dim3(250 * 16), 256, 0, stream>>>(
      logit, WoutB, b_out, d_out, nullptr, rowsum, ROWS, VOCAB, DIN, 250);
}

// Round 5
// 513.620 us; speedup vs baseline: 1.5265x; 1.0125x over previous
//
#include <hip/hip_runtime.h>
#include <hip/hip_bf16.h>
#include <math.h>

typedef __bf16 bf16_t;
typedef __bf16 bf16x8 __attribute__((ext_vector_type(8)));
typedef __bf16 bf16x4 __attribute__((ext_vector_type(4)));
typedef float  f32x4  __attribute__((ext_vector_type(4)));

#define T_STEPS 32
#define BATCH   64
#define DIN     512
#define HID     512
#define VOCAB   32000
#define FFEAT   768
#define ROWS    2048   /* T*B */
#define G3      1536   /* 3*H */
#define NBLK_A  32

#define EPI_F32  0
#define EPI_BF16 1
#define EPI_TANH 2
#define EPI_SUM  3   /* exp + partial row sums only, no store */
#define EPI_PROB 4   /* exp * 1/rowsum -> f32 store (final probs) */

// async global->LDS, 16B per lane (guide §5: width=16 is the proven fast path)
#define GLOAD16(gp, lp) __builtin_amdgcn_global_load_lds( \
    (const __attribute__((address_space(1))) void*)(gp),  \
    (__attribute__((address_space(3))) void*)(lp), 16, 0, 0)

// ---------------------------------------------------------------------------
// LDS-staged bf16 GEMM (m97 structure): C[M][N] = A[M][K] @ B[N][K]^T + bias.
// 256 thr = 4 waves, block tile 128x128, wave tile 64x64 (4x4 frags of
// 16x16x32 MFMA), BK=32 double-buffered in LDS via global_load_lds dwordx4.
//
// LDS swizzle (T2, rule 21: both-sides-or-neither): row stride is 64B so only
// row&1 reaches the bank bits -> plain layout is an 8-way conflict on
// ds_read_b128 (R4 measured 8.19M conflicts). Fix: 16B slot within the row is
// chunk ^ ((row>>1)&3). global_load_lds writes LDS linearly, so the data
// permutation is applied on the GLOBAL source address in stage(); reads use
// the same XOR -> per-quarter-wave banks become exactly 2-way (the b128
// hardware floor, free per m136).
// EPI_SUM/EPI_PROB: 1D grid + bn-major XCD-chunk swizzle (B-panel stays in
// one XCD's L2 across all 16 bm tiles).
// ---------------------------------------------------------------------------
template<int EPI>
__global__ __launch_bounds__(256) void gemm_lds(
    const bf16_t* __restrict__ A, const bf16_t* __restrict__ B,
    const float* __restrict__ bias, void* __restrict__ out,
    float* __restrict__ partial, const float* __restrict__ rowsum,
    int M, int N, int K, int NB)
{
  __shared__ bf16_t As[2][128 * 32];
  __shared__ bf16_t Bs[2][128 * 32];
  __shared__ float psum[128][2];

  const int lane = threadIdx.x & 63;
  const int wv   = threadIdx.x >> 6;
  const int wm = wv >> 1, wn = wv & 1;
  int bn, bm;
  if constexpr (EPI == EPI_SUM || EPI == EPI_PROB) {
    const int lin = blockIdx.x;
    const int nwg = NB * 16;
    const int cpx = nwg >> 3;           // nwg % 8 == 0 (4000/8=500)
    const int wg  = (lin & 7) * cpx + (lin >> 3);
    bn = wg >> 4; bm = wg & 15;
  } else {
    bn = blockIdx.x; bm = blockIdx.y;
  }
  const int la = lane & 15, lg = lane >> 4;
  const int tid = threadIdx.x;

  // stage: thread covers (row, slot c); loads global chunk c ^ ((row>>1)&3)
  auto stage = [&](int buf, int k0) {
#pragma unroll
    for (int q = 0; q < 2; ++q) {
      const int idx = q * 256 + tid;
      const int row = idx >> 2, c = idx & 3;
      const int gch = c ^ ((row >> 1) & 3);
      GLOAD16(A + (size_t)(bm * 128 + row) * K + k0 + gch * 8, &As[buf][idx * 8]);
      GLOAD16(B + (size_t)(bn * 128 + row) * K + k0 + gch * 8, &Bs[buf][idx * 8]);
    }
  };

  // fragment read: data chunk lg lives at LDS slot lg ^ ((row>>1)&3);
  // for row = {wm*64|wn*64} + i*16 + la this reduces to lg ^ ((la>>1)&3).
  const int rdch = (lg ^ ((la >> 1) & 3)) * 8;

  f32x4 acc[4][4] = {};
  const int NT = K >> 5;
  stage(0, 0);
  for (int kt = 0; kt < NT; ++kt) {
    __syncthreads();                    // drains vmcnt -> buf[kt&1] ready
    if (kt + 1 < NT) stage((kt + 1) & 1, (kt + 1) * 32);
    const bf16_t* Ab = As[kt & 1];
    const bf16_t* Bb = Bs[kt & 1];
    bf16x8 a[4], b[4];
#pragma unroll
    for (int i = 0; i < 4; ++i)
      a[i] = *(const bf16x8*)(Ab + (wm * 64 + i * 16 + la) * 32 + rdch);
#pragma unroll
    for (int j = 0; j < 4; ++j)
      b[j] = *(const bf16x8*)(Bb + (wn * 64 + j * 16 + la) * 32 + rdch);
#pragma unroll
    for (int i = 0; i < 4; ++i)
#pragma unroll
      for (int j = 0; j < 4; ++j)
        acc[i][j] = __builtin_amdgcn_mfma_f32_16x16x32_bf16(a[i], b[j], acc[i][j], 0, 0, 0);
  }

  const int m0 = bm * 128 + wm * 64;
  const int n0 = bn * 128 + wn * 64;
#pragma unroll
  for (int i = 0; i < 4; ++i) {
#pragma unroll
    for (int r = 0; r < 4; ++r) {
      const int row = m0 + i * 16 + lg * 4 + r;
      float vsum = 0.f;
      float inv;
      if constexpr (EPI == EPI_PROB) inv = 1.0f / rowsum[row];
#pragma unroll
      for (int j = 0; j < 4; ++j) {
        const int col = n0 + j * 16 + la;
        float v = acc[i][j][r] + bias[col];
        if constexpr (EPI == EPI_F32) {
          ((float*)out)[(size_t)row * N + col] = v;
        } else if constexpr (EPI == EPI_BF16) {
          ((bf16_t*)out)[(size_t)row * N + col] = (bf16_t)v;
        } else if constexpr (EPI == EPI_TANH) {
          ((bf16_t*)out)[(size_t)row * N + col] = (bf16_t)tanhf(v);
        } else if constexpr (EPI == EPI_SUM) {
          vsum += expf(v);
        } else {  // EPI_PROB
          ((float*)out)[(size_t)row * N + col] = expf(v) * inv;
        }
      }
      if constexpr (EPI == EPI_SUM) {
        vsum += __shfl_xor(vsum, 1);
        vsum += __shfl_xor(vsum, 2);
        vsum += __shfl_xor(vsum, 4);
        vsum += __shfl_xor(vsum, 8);
        if (la == 0) psum[wm * 64 + i * 16 + lg * 4 + r][wn] = vsum;
      }
    }
  }
  if constexpr (EPI == EPI_SUM) {
    __syncthreads();
    if (tid < 128) {
      const int rb = bm * 128 + tid;
      partial[(size_t)rb * NB + bn] = psum[tid][0] + psum[tid][1];
    }
  }
  (void)partial; (void)rowsum; (void)NB;
}

// ---------------------------------------------------------------------------
// Phase A: sequential GRU recurrence. 32 blocks; block g owns h1 cols
// [16g,16g+16). Contention-free cross-block exchange:
//  - h layout [parity][blk][row][8 u32]: block-exclusive cachelines.
//  - flags one 64B line per (blk,wave).
//  - flag raised after h stores drain (vmcnt0); Xall stores after the flag.
// ---------------------------------------------------------------------------
__global__ __launch_bounds__(256) void phaseA_k(
    const bf16_t* __restrict__ Wg, const float* __restrict__ bhh,
    const float* __restrict__ gi, const float* __restrict__ ct,
    unsigned int* __restrict__ hbuf /* u32[2][32][64][8] */,
    bf16_t* __restrict__ Xall, int* __restrict__ flags /* [(blk*4+wv)*16] */)
{
  __shared__ bf16_t Wl[48 * 520];
  __shared__ float bl[48];
  const int tid = threadIdx.x, blk = blockIdx.x;

  for (int i = tid; i < 48 * 64; i += 256) {
    const int rw = i >> 6, ch = (i & 63) << 3;
    *(bf16x8*)(Wl + rw * 520 + ch) = *(const bf16x8*)(Wg + (size_t)(blk * 48 + rw) * 512 + ch);
  }
  if (tid < 48) bl[tid] = bhh[blk * 48 + tid];
  __syncthreads();

  const int lane = tid & 63, wv = tid >> 6;
  const int la = lane & 15, lg = lane >> 4;
  const int jcol = blk * 16 + la;
  const int rowA = wv * 16 + la;          // A-fragment row this lane loads

  const float blr = bl[la], blz = bl[16 + la], bln = bl[32 + la];
  float hprev[4], ctv[4];
#pragma unroll
  for (int r = 0; r < 4; ++r) {
    hprev[r] = 0.f;
    ctv[r] = ct[(size_t)(wv * 16 + lg * 4 + r) * HID + jcol];
  }

  for (int t = 0; t < T_STEPS; ++t) {
    // ---- gi prefetch (overlaps the poll)
    const float* girow = gi + (size_t)t * BATCH * G3 + (size_t)blk * 48;
    float gv[12];
#pragma unroll
    for (int r = 0; r < 4; ++r) {
      const float* gp = girow + (size_t)(wv * 16 + lg * 4 + r) * G3;
      gv[r * 3 + 0] = gp[la];
      gv[r * 3 + 1] = gp[16 + la];
      gv[r * 3 + 2] = gp[32 + la];
    }
    // ---- wait: wave w needs flag[blk=lane][w] >= t (each flag own line)
    if (t > 0) {
      if (lane < 32) {
        while (__hip_atomic_load(&flags[(lane * 4 + wv) * 16], __ATOMIC_RELAXED,
                                 __HIP_MEMORY_SCOPE_AGENT) < t)
          __builtin_amdgcn_s_sleep(1);
      }
      asm volatile("" ::: "memory");
    }
    // ---- load A fragments: af[q] = 8 bf16 at (rowA, cols 32q+8lg..+8)
    const unsigned long long* hb =
        (const unsigned long long*)(hbuf + (size_t)(t & 1) * 16384);
    bf16x8 af[16];
#pragma unroll
    for (int q = 0; q < 16; ++q) {
      union { unsigned long long u[2]; bf16x8 v; } c;
      const size_t bidx = (size_t)(2 * q + (lg >> 1)) * 256 + rowA * 4 + (lg & 1) * 2;
      c.u[0] = __hip_atomic_load(hb + bidx,     __ATOMIC_RELAXED, __HIP_MEMORY_SCOPE_AGENT);
      c.u[1] = __hip_atomic_load(hb + bidx + 1, __ATOMIC_RELAXED, __HIP_MEMORY_SCOPE_AGENT);
      af[q] = c.v;
    }
    // ---- MFMA: gh = h @ Whh_slice^T (48 cols = r,z,n x 16)
    f32x4 acc0 = {}, acc1 = {}, acc2 = {};
#pragma unroll
    for (int q = 0; q < 16; ++q) {
      const bf16_t* wp = Wl + q * 32 + lg * 8;
      bf16x8 b0 = *(const bf16x8*)(wp + (0 * 16 + la) * 520);
      bf16x8 b1 = *(const bf16x8*)(wp + (1 * 16 + la) * 520);
      bf16x8 b2 = *(const bf16x8*)(wp + (2 * 16 + la) * 520);
      acc0 = __builtin_amdgcn_mfma_f32_16x16x32_bf16(af[q], b0, acc0, 0, 0, 0);
      acc1 = __builtin_amdgcn_mfma_f32_16x16x32_bf16(af[q], b1, acc1, 0, 0, 0);
      acc2 = __builtin_amdgcn_mfma_f32_16x16x32_bf16(af[q], b2, acc2, 0, 0, 0);
    }
    // ---- gates + h1 (registers first)
    float h1v[4];
#pragma unroll
    for (int r = 0; r < 4; ++r) {
      const float ghr = acc0[r] + blr;
      const float ghz = acc1[r] + blz;
      const float ghn = acc2[r] + bln;
      const float rr = 1.f / (1.f + expf(-(gv[r * 3 + 0] + ghr)));
      const float zz = 1.f / (1.f + expf(-(gv[r * 3 + 1] + ghz)));
      const float nn = tanhf(gv[r * 3 + 2] + rr * ghn);
      h1v[r] = (1.f - zz) * nn + zz * hprev[r];
      hprev[r] = h1v[r];
    }
    // ---- h stores (block-exclusive lines), then flag, then Xall
    unsigned int* hn = hbuf + (size_t)((t + 1) & 1) * 16384 + blk * 512;
#pragma unroll
    for (int r = 0; r < 4; ++r) {
      const int row = wv * 16 + lg * 4 + r;
      const unsigned int mine =
          (unsigned int)__builtin_bit_cast(unsigned short, (bf16_t)h1v[r]);
      const unsigned int other = (unsigned int)__shfl_xor((int)mine, 1);
      if ((la & 1) == 0) {
        __hip_atomic_store(hn + row * 8 + (la >> 1), mine | (other << 16),
                           __ATOMIC_RELAXED, __HIP_MEMORY_SCOPE_AGENT);
      }
    }
    asm volatile("s_waitcnt vmcnt(0)" ::: "memory");
    if (lane == 0) {
      __hip_atomic_store(&flags[(blk * 4 + wv) * 16], t + 1, __ATOMIC_RELAXED,
                         __HIP_MEMORY_SCOPE_AGENT);
    }
#pragma unroll
    for (int r = 0; r < 4; ++r) {
      const int row = wv * 16 + lg * 4 + r;
      Xall[((size_t)t * BATCH + row) * HID + jcol] = (bf16_t)(h1v[r] * ctv[r]);
    }
  }
}

// ---------------------------------------------------------------------------
// Per-(t,b) 8-head self-attention on a single vector.
// ---------------------------------------------------------------------------
__global__ __launch_bounds__(256) void attn_k(const bf16_t* __restrict__ QKV,
                                              bf16_t* __restrict__ attO)
{
  __shared__ float sq[4][512], sk[4][512], sv[4][512], sw[4][64];
  const int tid = threadIdx.x;
  const int wv = tid >> 6, lane = tid & 63;
  const int row = blockIdx.x * 4 + wv;
  const bf16_t* base = QKV + (size_t)row * G3;
  bf16x8 vq = *(const bf16x8*)(base + lane * 8);
  bf16x8 vk = *(const bf16x8*)(base + 512 + lane * 8);
  bf16x8 vv = *(const bf16x8*)(base + 1024 + lane * 8);
#pragma unroll
  for (int e = 0; e < 8; ++e) {
    sq[wv][lane * 8 + e] = (float)vq[e];
    sk[wv][lane * 8 + e] = (float)vk[e];
    sv[wv][lane * 8 + e] = (float)vv[e];
  }
  __syncthreads();
  const int h = lane >> 3, g = lane & 7;
  float s = 0.f;
#pragma unroll 16
  for (int d = 0; d < 64; ++d) s += sq[wv][h * 64 + d] * sk[wv][g * 64 + d];
  s *= (1.f / 64.f);  // reference divides by head_dim (not sqrt)
  float m = s;
  m = fmaxf(m, __shfl_xor(m, 1));
  m = fmaxf(m, __shfl_xor(m, 2));
  m = fmaxf(m, __shfl_xor(m, 4));
  const float e = expf(s - m);
  float sum = e;
  sum += __shfl_xor(sum, 1);
  sum += __shfl_xor(sum, 2);
  sum += __shfl_xor(sum, 4);
  sw[wv][lane] = e / sum;
  __syncthreads();
#pragma unroll
  for (int rep = 0; rep < 8; ++rep) {
    const int idx = rep * 64 + lane;
    const int hh = idx >> 6, d = idx & 63;
    float o = 0.f;
#pragma unroll
    for (int gg = 0; gg < 8; ++gg) o += sw[wv][hh * 8 + gg] * sv[wv][gg * 64 + d];
    attO[(size_t)row * HID + idx] = (bf16_t)o;
  }
}

// --------------------------- small prep kernels ----------------------------
__global__ __launch_bounds__(256) void cast_k(const float* __restrict__ src,
                                              bf16_t* __restrict__ dst, int n4)
{
  const int i = blockIdx.x * 256 + threadIdx.x;
  if (i >= n4) return;
  float4 v = ((const float4*)src)[i];
  bf16x4 o = {(bf16_t)v.x, (bf16_t)v.y, (bf16_t)v.z, (bf16_t)v.w};
  *(bf16x4*)(dst + (size_t)i * 4) = o;
}

__global__ __launch_bounds__(256) void perm_cast_k(const float* __restrict__ src,
                                                   bf16_t* __restrict__ dst)
{
  const int i = blockIdx.x * 256 + threadIdx.x;  // 1536*128
  const int pg = i >> 7, kq = (i & 127) << 2;
  const int g = pg / 48, rem = pg - g * 48, sec = rem >> 4, jj = rem & 15;
  const int srow = sec * 512 + g * 16 + jj;
  float4 v = *(const float4*)(src + (size_t)srow * DIN + kq);
  bf16x4 o = {(bf16_t)v.x, (bf16_t)v.y, (bf16_t)v.z, (bf16_t)v.w};
  *(bf16x4*)(dst + (size_t)pg * DIN + kq) = o;
}

__global__ void perm_bias_k(const float* __restrict__ bih, const float* __restrict__ bhh,
                            float* __restrict__ bihp, float* __restrict__ bhhp)
{
  const int pg = blockIdx.x * 256 + threadIdx.x;
  if (pg >= G3) return;
  const int g = pg / 48, rem = pg - g * 48, sec = rem >> 4, jj = rem & 15;
  const int srow = sec * 512 + g * 16 + jj;
  bihp[pg] = bih[srow];
  bhhp[pg] = bhh[srow];
}

__global__ void bcat_k(const float* __restrict__ a, const float* __restrict__ b,
                       const float* __restrict__ c, float* __restrict__ d)
{
  const int i = blockIdx.x * 256 + threadIdx.x;
  if (i >= G3) return;
  d[i] = i < 512 ? a[i] : (i < 1024 ? b[i - 512] : c[i - 1024]);
}

__global__ __launch_bounds__(256) void yemb_k(const int* __restrict__ y,
                                              const float* __restrict__ embW,
                                              bf16_t* __restrict__ out)
{
  const int idx = blockIdx.x * 256 + threadIdx.x;  // 2048*64
  const int rb = idx >> 6, c = (idx & 63) << 3;
  const int tok = y[rb];
  const float4* s = (const float4*)(embW + (size_t)tok * DIN + c);
  float4 v0 = s[0], v1 = s[1];
  bf16x8 o = {(bf16_t)v0.x, (bf16_t)v0.y, (bf16_t)v0.z, (bf16_t)v0.w,
              (bf16_t)v1.x, (bf16_t)v1.y, (bf16_t)v1.z, (bf16_t)v1.w};
  *(bf16x8*)(out + (size_t)rb * DIN + c) = o;
}

__global__ __launch_bounds__(256) void ct_k(const float* __restrict__ ctx,
                                            const float* __restrict__ Watt,
                                            const float* __restrict__ batt,
                                            float* __restrict__ ct)
{
  const int idx = blockIdx.x * 256 + threadIdx.x;  // 64*512
  const int b = idx >> 9, j = idx & 511;
  const float4* c4 = (const float4*)(ctx + (size_t)b * FFEAT);
  const float4* w4 = (const float4*)(Watt + (size_t)j * FFEAT);
  float s = batt[j];
  for (int q = 0; q < FFEAT / 4; ++q) {
    float4 cc = c4[q], ww = w4[q];
    s += cc.x * ww.x + cc.y * ww.y + cc.z * ww.z + cc.w * ww.w;
  }
  ct[idx] = tanhf(s);
}

__global__ __launch_bounds__(256) void reduce_rows(const float* __restrict__ partial,
                                                   float* __restrict__ rowsum, int NB)
{
  const int wv = threadIdx.x >> 6, lane = threadIdx.x & 63;
  const int row = blockIdx.x * 4 + wv;
  float s = 0.f;
  for (int c = lane; c < NB; c += 64) s += partial[(size_t)row * NB + c];
  for (int m = 1; m < 64; m <<= 1) s += __shfl_xor(s, m);
  if (lane == 0) rowsum[row] = s;
}

// ---------------------------------------------------------------------------
extern "C" void kernel_launch(void* const* d_in, const int* in_sizes, int n_in,
                              void* d_out, int out_size, void* d_ws, size_t ws_size,
                              hipStream_t stream)
{
  const int*   y     = (const int*)  d_in[0];
  const float* ctx   = (const float*)d_in[1];
  const float* embW  = (const float*)d_in[2];
  const float* W_ih  = (const float*)d_in[3];
  const float* b_ih  = (const float*)d_in[4];
  const float* W_hh  = (const float*)d_in[5];
  const float* b_hh  = (const float*)d_in[6];
  const float* W_att = (const float*)d_in[7];
  const float* b_att = (const float*)d_in[8];
  const float* Wq    = (const float*)d_in[9];
  const float* bq    = (const float*)d_in[10];
  const float* Wk    = (const float*)d_in[11];
  const float* bk    = (const float*)d_in[12];
  const float* Wv    = (const float*)d_in[13];
  const float* bv    = (const float*)d_in[14];
  const float* Wfc   = (const float*)d_in[15];
  const float* bfc   = (const float*)d_in[16];
  const float* Wh2o  = (const float*)d_in[17];
  const float* bh2o  = (const float*)d_in[18];
  const float* W_out = (const float*)d_in[19];
  const float* b_out = (const float*)d_in[20];

  char* p = (char*)d_ws;
  auto alloc = [&](size_t bytes) {
    char* r = p;
    p += (bytes + 255) & ~(size_t)255;
    return r;
  };
  bf16_t* WoutB   = (bf16_t*)alloc((size_t)VOCAB * DIN * 2);
  bf16_t* WgIh    = (bf16_t*)alloc((size_t)G3 * DIN * 2);
  bf16_t* WgHh    = (bf16_t*)alloc((size_t)G3 * DIN * 2);
  bf16_t* Wqkv    = (bf16_t*)alloc((size_t)G3 * DIN * 2);
  bf16_t* WfcB    = (bf16_t*)alloc((size_t)HID * HID * 2);
  bf16_t* Wh2oB   = (bf16_t*)alloc((size_t)HID * HID * 2);
  float*  bIhP    = (float*)alloc(G3 * 4);
  float*  bHhP    = (float*)alloc(G3 * 4);
  float*  bQkv    = (float*)alloc(G3 * 4);
  bf16_t* Yemb    = (bf16_t*)alloc((size_t)ROWS * DIN * 2);
  float*  giP     = (float*)alloc((size_t)ROWS * G3 * 4);
  float*  ctB     = (float*)alloc((size_t)BATCH * HID * 4);
  unsigned int* hbuf = (unsigned int*)alloc((size_t)2 * 16384 * 4);
  bf16_t* Xall    = (bf16_t*)alloc((size_t)ROWS * DIN * 2);
  bf16_t* QKV     = (bf16_t*)alloc((size_t)ROWS * G3 * 2);
  bf16_t* attO    = (bf16_t*)alloc((size_t)ROWS * HID * 2);
  bf16_t* h2B     = (bf16_t*)alloc((size_t)ROWS * HID * 2);
  bf16_t* logit   = (bf16_t*)alloc((size_t)ROWS * DIN * 2);
  float*  partial = (float*)alloc((size_t)ROWS * 250 * 4);
  float*  rowsum  = (float*)alloc((size_t)ROWS * 4);
  int*    flags   = (int*)alloc(32 * 4 * 64);

  hipMemsetAsync(hbuf, 0, (size_t)2 * 16384 * 4, stream);  // h0 = 0
  hipMemsetAsync(flags, 0, 32 * 4 * 64, stream);

  // weight prep
  cast_k<<<(VOCAB * DIN / 4 + 255) / 256, 256, 0, stream>>>(W_out, WoutB, VOCAB * DIN / 4);
  cast_k<<<256, 256, 0, stream>>>(Wq, Wqkv, HID * HID / 4);
  cast_k<<<256, 256, 0, stream>>>(Wk, Wqkv + (size_t)HID * DIN, HID * HID / 4);
  cast_k<<<256, 256, 0, stream>>>(Wv, Wqkv + (size_t)2 * HID * DIN, HID * HID / 4);
  cast_k<<<256, 256, 0, stream>>>(Wfc, WfcB, HID * HID / 4);
  cast_k<<<256, 256, 0, stream>>>(Wh2o, Wh2oB, HID * HID / 4);
  perm_cast_k<<<768, 256, 0, stream>>>(W_ih, WgIh);
  perm_cast_k<<<768, 256, 0, stream>>>(W_hh, WgHh);
  perm_bias_k<<<6, 256, 0, stream>>>(b_ih, b_hh, bIhP, bHhP);
  bcat_k<<<6, 256, 0, stream>>>(bq, bk, bv, bQkv);
  yemb_k<<<512, 256, 0, stream>>>(y, embW, Yemb);
  ct_k<<<128, 256, 0, stream>>>(ctx, W_att, b_att, ctB);

  // gi for all steps: [2048,512] @ [1536,512]^T -> fp32 (bias = b_ih)
  gemm_lds<EPI_F32><<<dim3(12, 16), 256, 0, stream>>>(
      Yemb, WgIh, bIhP, giP, nullptr, nullptr, ROWS, G3, DIN, 12);

  // sequential GRU recurrence -> Xall = h1 * ct (bf16)
  phaseA_k<<<NBLK_A, 256, 0, stream>>>(WgHh, bHhP, giP, ctB, hbuf, Xall, flags);

  // QKV = X @ [Wq;Wk;Wv]^T + b
  gemm_lds<EPI_BF16><<<dim3(12, 16), 256, 0, stream>>>(
      Xall, Wqkv, bQkv, QKV, nullptr, nullptr, ROWS, G3, DIN, 12);

  attn_k<<<512, 256, 0, stream>>>(QKV, attO);

  // h2 = att @ Wfc^T + bfc
  gemm_lds<EPI_BF16><<<dim3(4, 16), 256, 0, stream>>>(
      attO, WfcB, bfc, h2B, nullptr, nullptr, ROWS, HID, HID, 4);

  // logit = tanh(h2 @ Wh2o^T + b)
  gemm_lds<EPI_TANH><<<dim3(4, 16), 256, 0, stream>>>(
      h2B, Wh2oB, bh2o, logit, nullptr, nullptr, ROWS, DIN, HID, 4);

  // pass 1: rowsums of exp(logit @ W_out^T + b) -- no 262MB store
  gemm_lds<EPI_SUM><<<dim3(250 * 16), 256, 0, stream>>>(
      logit, WoutB, b_out, nullptr, partial, nullptr, ROWS, VOCAB, DIN, 250);
  reduce_rows<<<512, 256, 0, stream>>>(partial, rowsum, 250);
  // pass 2: recompute, write normalized f32 probs directly
  gemm_lds<EPI_PROB><<<dim3(250 * 16), 256, 0, stream>>>(
      logit, WoutB, b_out, d_out, nullptr, rowsum, ROWS, VOCAB, DIN, 250);
}

// Round 6
// 504.449 us; speedup vs baseline: 1.5542x; 1.0182x over previous
//
#include <hip/hip_runtime.h>
#include <hip/hip_bf16.h>
#include <math.h>

typedef __bf16 bf16_t;
typedef __bf16 bf16x8 __attribute__((ext_vector_type(8)));
typedef __bf16 bf16x4 __attribute__((ext_vector_type(4)));
typedef float  f32x4  __attribute__((ext_vector_type(4)));

#define T_STEPS 32
#define BATCH   64
#define DIN     512
#define HID     512
#define VOCAB   32000
#define FFEAT   768
#define ROWS    2048   /* T*B */
#define G3      1536   /* 3*H */
#define NBLK_A  32

#define EPI_F32  0
#define EPI_BF16 1
#define EPI_TANH 2
#define EPI_SUM  3   /* exp + partial row sums only, no store */
#define EPI_PROB 4   /* exp * 1/rowsum -> f32 store (final probs) */

// async global->LDS, 16B per lane (guide §5: width=16 is the proven fast path)
#define GLOAD16(gp, lp) __builtin_amdgcn_global_load_lds( \
    (const __attribute__((address_space(1))) void*)(gp),  \
    (__attribute__((address_space(3))) void*)(lp), 16, 0, 0)

// ---------------------------------------------------------------------------
// LDS-staged bf16 GEMM: C[M][N] = A[M][K] @ B[N][K]^T + bias.
// 256 thr = 4 waves, block tile 128x128, wave tile 64x64 (4x4 frags of
// 16x16x32 MFMA), BK=32.
//
// Pipeline (T3/T4-lite, R6): depth-2 prefetch over THREE LDS buffers with
// counted vmcnt + RAW s_barrier (no __syncthreads vmcnt(0) drain in the main
// loop). Per thread each stage() = 4 global_load_lds. Prologue: tiles 0,1
// in flight (vmcnt=8). Loop top: wait vmcnt(4) -> tile kt complete (kt+1
// still in flight), barrier, stage kt+2, compute kt. Last iter waits
// vmcnt(0). WAR: buf[(kt+2)%3] was last read in iter kt-1; those ds_reads
// complete before each wave reaches the iter-kt barrier.
//
// LDS swizzle (T2): 16B slot within a 64B row = chunk ^ ((row>>1)&3), applied
// on the global source addr (gload_lds writes linearly) and on the read.
// Gives exactly 2-way bank access per quarter-wave (the b128 volume floor).
// T2 becomes timing-visible only now that the stage/barrier stall is off the
// critical path (m252 regime gate).
// EPI_SUM/EPI_PROB: 1D grid + bn-major XCD-chunk swizzle (B-panel stays in
// one XCD's L2 across all 16 bm tiles).
// ---------------------------------------------------------------------------
template<int EPI>
__global__ __launch_bounds__(256) void gemm_lds(
    const bf16_t* __restrict__ A, const bf16_t* __restrict__ B,
    const float* __restrict__ bias, void* __restrict__ out,
    float* __restrict__ partial, const float* __restrict__ rowsum,
    int M, int N, int K, int NB)
{
  __shared__ bf16_t As[3][128 * 32];
  __shared__ bf16_t Bs[3][128 * 32];
  __shared__ float psum[128][2];

  const int lane = threadIdx.x & 63;
  const int wv   = threadIdx.x >> 6;
  const int wm = wv >> 1, wn = wv & 1;
  int bn, bm;
  if constexpr (EPI == EPI_SUM || EPI == EPI_PROB) {
    const int lin = blockIdx.x;
    const int nwg = NB * 16;
    const int cpx = nwg >> 3;           // nwg % 8 == 0 (4000/8=500)
    const int wg  = (lin & 7) * cpx + (lin >> 3);
    bn = wg >> 4; bm = wg & 15;
  } else {
    bn = blockIdx.x; bm = blockIdx.y;
  }
  const int la = lane & 15, lg = lane >> 4;
  const int tid = threadIdx.x;

  // stage: thread covers (row, slot c); loads global chunk c ^ ((row>>1)&3)
  auto stage = [&](int buf, int k0) {
#pragma unroll
    for (int q = 0; q < 2; ++q) {
      const int idx = q * 256 + tid;
      const int row = idx >> 2, c = idx & 3;
      const int gch = c ^ ((row >> 1) & 3);
      GLOAD16(A + (size_t)(bm * 128 + row) * K + k0 + gch * 8, &As[buf][idx * 8]);
      GLOAD16(B + (size_t)(bn * 128 + row) * K + k0 + gch * 8, &Bs[buf][idx * 8]);
    }
  };

  // fragment read: data chunk lg lives at LDS slot lg ^ ((row>>1)&3);
  // for row = {wm*64|wn*64} + i*16 + la this reduces to lg ^ ((la>>1)&3).
  const int rdch = (lg ^ ((la >> 1) & 3)) * 8;

  f32x4 acc[4][4] = {};
  const int NT = K >> 5;                // >= 3 for all our shapes
  stage(0, 0);
  stage(1, 32);
  for (int kt = 0; kt < NT; ++kt) {
    if (kt + 1 < NT) {
      asm volatile("s_waitcnt vmcnt(4)" ::: "memory");  // tile kt landed
    } else {
      asm volatile("s_waitcnt vmcnt(0)" ::: "memory");  // final tile
    }
    __builtin_amdgcn_s_barrier();
    __builtin_amdgcn_sched_barrier(0);  // keep ds_reads below the barrier
    if (kt + 2 < NT) {
      int b2 = kt + 2; b2 -= (b2 >= 3) ? 3 : 0; b2 -= (b2 >= 3) ? 3 : 0;
      // (kt+2)%3 without sdiv: kt%3 cycles 0,1,2 -> compute directly
      stage((kt + 2) % 3, (kt + 2) * 32);
      (void)b2;
    }
    const bf16_t* Ab = As[kt % 3];
    const bf16_t* Bb = Bs[kt % 3];
    bf16x8 a[4], b[4];
#pragma unroll
    for (int i = 0; i < 4; ++i)
      a[i] = *(const bf16x8*)(Ab + (wm * 64 + i * 16 + la) * 32 + rdch);
#pragma unroll
    for (int j = 0; j < 4; ++j)
      b[j] = *(const bf16x8*)(Bb + (wn * 64 + j * 16 + la) * 32 + rdch);
    __builtin_amdgcn_s_setprio(1);
#pragma unroll
    for (int i = 0; i < 4; ++i)
#pragma unroll
      for (int j = 0; j < 4; ++j)
        acc[i][j] = __builtin_amdgcn_mfma_f32_16x16x32_bf16(a[i], b[j], acc[i][j], 0, 0, 0);
    __builtin_amdgcn_s_setprio(0);
  }

  const int m0 = bm * 128 + wm * 64;
  const int n0 = bn * 128 + wn * 64;
  float bv4[4];
#pragma unroll
  for (int j = 0; j < 4; ++j) bv4[j] = bias[n0 + j * 16 + la];
#pragma unroll
  for (int i = 0; i < 4; ++i) {
#pragma unroll
    for (int r = 0; r < 4; ++r) {
      const int row = m0 + i * 16 + lg * 4 + r;
      float vsum = 0.f;
      float inv;
      if constexpr (EPI == EPI_PROB) inv = 1.0f / rowsum[row];
#pragma unroll
      for (int j = 0; j < 4; ++j) {
        const int col = n0 + j * 16 + la;
        float v = acc[i][j][r] + bv4[j];
        if constexpr (EPI == EPI_F32) {
          ((float*)out)[(size_t)row * N + col] = v;
        } else if constexpr (EPI == EPI_BF16) {
          ((bf16_t*)out)[(size_t)row * N + col] = (bf16_t)v;
        } else if constexpr (EPI == EPI_TANH) {
          ((bf16_t*)out)[(size_t)row * N + col] = (bf16_t)tanhf(v);
        } else if constexpr (EPI == EPI_SUM) {
          vsum += expf(v);
        } else {  // EPI_PROB
          ((float*)out)[(size_t)row * N + col] = expf(v) * inv;
        }
      }
      if constexpr (EPI == EPI_SUM) {
        vsum += __shfl_xor(vsum, 1);
        vsum += __shfl_xor(vsum, 2);
        vsum += __shfl_xor(vsum, 4);
        vsum += __shfl_xor(vsum, 8);
        if (la == 0) psum[wm * 64 + i * 16 + lg * 4 + r][wn] = vsum;
      }
    }
  }
  if constexpr (EPI == EPI_SUM) {
    __syncthreads();
    if (tid < 128) {
      const int rb = bm * 128 + tid;
      partial[(size_t)rb * NB + bn] = psum[tid][0] + psum[tid][1];
    }
  }
  (void)partial; (void)rowsum; (void)NB;
}

// ---------------------------------------------------------------------------
// Phase A: sequential GRU recurrence. 32 blocks; block g owns h1 cols
// [16g,16g+16). Contention-free cross-block exchange:
//  - h layout [parity][blk][row][8 u32]: block-exclusive cachelines.
//  - flags one 64B line per (blk,wave).
//  - flag raised after h stores drain (vmcnt0); Xall stores after the flag.
// ---------------------------------------------------------------------------
__global__ __launch_bounds__(256) void phaseA_k(
    const bf16_t* __restrict__ Wg, const float* __restrict__ bhh,
    const float* __restrict__ gi, const float* __restrict__ ct,
    unsigned int* __restrict__ hbuf /* u32[2][32][64][8] */,
    bf16_t* __restrict__ Xall, int* __restrict__ flags /* [(blk*4+wv)*16] */)
{
  __shared__ bf16_t Wl[48 * 520];
  __shared__ float bl[48];
  const int tid = threadIdx.x, blk = blockIdx.x;

  for (int i = tid; i < 48 * 64; i += 256) {
    const int rw = i >> 6, ch = (i & 63) << 3;
    *(bf16x8*)(Wl + rw * 520 + ch) = *(const bf16x8*)(Wg + (size_t)(blk * 48 + rw) * 512 + ch);
  }
  if (tid < 48) bl[tid] = bhh[blk * 48 + tid];
  __syncthreads();

  const int lane = tid & 63, wv = tid >> 6;
  const int la = lane & 15, lg = lane >> 4;
  const int jcol = blk * 16 + la;
  const int rowA = wv * 16 + la;          // A-fragment row this lane loads

  const float blr = bl[la], blz = bl[16 + la], bln = bl[32 + la];
  float hprev[4], ctv[4];
#pragma unroll
  for (int r = 0; r < 4; ++r) {
    hprev[r] = 0.f;
    ctv[r] = ct[(size_t)(wv * 16 + lg * 4 + r) * HID + jcol];
  }

  for (int t = 0; t < T_STEPS; ++t) {
    // ---- gi prefetch (overlaps the poll)
    const float* girow = gi + (size_t)t * BATCH * G3 + (size_t)blk * 48;
    float gv[12];
#pragma unroll
    for (int r = 0; r < 4; ++r) {
      const float* gp = girow + (size_t)(wv * 16 + lg * 4 + r) * G3;
      gv[r * 3 + 0] = gp[la];
      gv[r * 3 + 1] = gp[16 + la];
      gv[r * 3 + 2] = gp[32 + la];
    }
    // ---- wait: wave w needs flag[blk=lane][w] >= t (each flag own line)
    if (t > 0) {
      if (lane < 32) {
        while (__hip_atomic_load(&flags[(lane * 4 + wv) * 16], __ATOMIC_RELAXED,
                                 __HIP_MEMORY_SCOPE_AGENT) < t)
          __builtin_amdgcn_s_sleep(1);
      }
      asm volatile("" ::: "memory");
    }
    // ---- load A fragments: af[q] = 8 bf16 at (rowA, cols 32q+8lg..+8)
    const unsigned long long* hb =
        (const unsigned long long*)(hbuf + (size_t)(t & 1) * 16384);
    bf16x8 af[16];
#pragma unroll
    for (int q = 0; q < 16; ++q) {
      union { unsigned long long u[2]; bf16x8 v; } c;
      const size_t bidx = (size_t)(2 * q + (lg >> 1)) * 256 + rowA * 4 + (lg & 1) * 2;
      c.u[0] = __hip_atomic_load(hb + bidx,     __ATOMIC_RELAXED, __HIP_MEMORY_SCOPE_AGENT);
      c.u[1] = __hip_atomic_load(hb + bidx + 1, __ATOMIC_RELAXED, __HIP_MEMORY_SCOPE_AGENT);
      af[q] = c.v;
    }
    // ---- MFMA: gh = h @ Whh_slice^T (48 cols = r,z,n x 16)
    f32x4 acc0 = {}, acc1 = {}, acc2 = {};
#pragma unroll
    for (int q = 0; q < 16; ++q) {
      const bf16_t* wp = Wl + q * 32 + lg * 8;
      bf16x8 b0 = *(const bf16x8*)(wp + (0 * 16 + la) * 520);
      bf16x8 b1 = *(const bf16x8*)(wp + (1 * 16 + la) * 520);
      bf16x8 b2 = *(const bf16x8*)(wp + (2 * 16 + la) * 520);
      acc0 = __builtin_amdgcn_mfma_f32_16x16x32_bf16(af[q], b0, acc0, 0, 0, 0);
      acc1 = __builtin_amdgcn_mfma_f32_16x16x32_bf16(af[q], b1, acc1, 0, 0, 0);
      acc2 = __builtin_amdgcn_mfma_f32_16x16x32_bf16(af[q], b2, acc2, 0, 0, 0);
    }
    // ---- gates + h1 (registers first)
    float h1v[4];
#pragma unroll
    for (int r = 0; r < 4; ++r) {
      const float ghr = acc0[r] + blr;
      const float ghz = acc1[r] + blz;
      const float ghn = acc2[r] + bln;
      const float rr = 1.f / (1.f + expf(-(gv[r * 3 + 0] + ghr)));
      const float zz = 1.f / (1.f + expf(-(gv[r * 3 + 1] + ghz)));
      const float nn = tanhf(gv[r * 3 + 2] + rr * ghn);
      h1v[r] = (1.f - zz) * nn + zz * hprev[r];
      hprev[r] = h1v[r];
    }
    // ---- h stores (block-exclusive lines), then flag, then Xall
    unsigned int* hn = hbuf + (size_t)((t + 1) & 1) * 16384 + blk * 512;
#pragma unroll
    for (int r = 0; r < 4; ++r) {
      const int row = wv * 16 + lg * 4 + r;
      const unsigned int mine =
          (unsigned int)__builtin_bit_cast(unsigned short, (bf16_t)h1v[r]);
      const unsigned int other = (unsigned int)__shfl_xor((int)mine, 1);
      if ((la & 1) == 0) {
        __hip_atomic_store(hn + row * 8 + (la >> 1), mine | (other << 16),
                           __ATOMIC_RELAXED, __HIP_MEMORY_SCOPE_AGENT);
      }
    }
    asm volatile("s_waitcnt vmcnt(0)" ::: "memory");
    if (lane == 0) {
      __hip_atomic_store(&flags[(blk * 4 + wv) * 16], t + 1, __ATOMIC_RELAXED,
                         __HIP_MEMORY_SCOPE_AGENT);
    }
#pragma unroll
    for (int r = 0; r < 4; ++r) {
      const int row = wv * 16 + lg * 4 + r;
      Xall[((size_t)t * BATCH + row) * HID + jcol] = (bf16_t)(h1v[r] * ctv[r]);
    }
  }
}

// ---------------------------------------------------------------------------
// Per-(t,b) 8-head self-attention on a single vector.
// ---------------------------------------------------------------------------
__global__ __launch_bounds__(256) void attn_k(const bf16_t* __restrict__ QKV,
                                              bf16_t* __restrict__ attO)
{
  __shared__ float sq[4][512], sk[4][512], sv[4][512], sw[4][64];
  const int tid = threadIdx.x;
  const int wv = tid >> 6, lane = tid & 63;
  const int row = blockIdx.x * 4 + wv;
  const bf16_t* base = QKV + (size_t)row * G3;
  bf16x8 vq = *(const bf16x8*)(base + lane * 8);
  bf16x8 vk = *(const bf16x8*)(base + 512 + lane * 8);
  bf16x8 vv = *(const bf16x8*)(base + 1024 + lane * 8);
#pragma unroll
  for (int e = 0; e < 8; ++e) {
    sq[wv][lane * 8 + e] = (float)vq[e];
    sk[wv][lane * 8 + e] = (float)vk[e];
    sv[wv][lane * 8 + e] = (float)vv[e];
  }
  __syncthreads();
  const int h = lane >> 3, g = lane & 7;
  float s = 0.f;
#pragma unroll 16
  for (int d = 0; d < 64; ++d) s += sq[wv][h * 64 + d] * sk[wv][g * 64 + d];
  s *= (1.f / 64.f);  // reference divides by head_dim (not sqrt)
  float m = s;
  m = fmaxf(m, __shfl_xor(m, 1));
  m = fmaxf(m, __shfl_xor(m, 2));
  m = fmaxf(m, __shfl_xor(m, 4));
  const float e = expf(s - m);
  float sum = e;
  sum += __shfl_xor(sum, 1);
  sum += __shfl_xor(sum, 2);
  sum += __shfl_xor(sum, 4);
  sw[wv][lane] = e / sum;
  __syncthreads();
#pragma unroll
  for (int rep = 0; rep < 8; ++rep) {
    const int idx = rep * 64 + lane;
    const int hh = idx >> 6, d = idx & 63;
    float o = 0.f;
#pragma unroll
    for (int gg = 0; gg < 8; ++gg) o += sw[wv][hh * 8 + gg] * sv[wv][gg * 64 + d];
    attO[(size_t)row * HID + idx] = (bf16_t)o;
  }
}

// --------------------------- small prep kernels ----------------------------
__global__ __launch_bounds__(256) void cast_k(const float* __restrict__ src,
                                              bf16_t* __restrict__ dst, int n4)
{
  const int i = blockIdx.x * 256 + threadIdx.x;
  if (i >= n4) return;
  float4 v = ((const float4*)src)[i];
  bf16x4 o = {(bf16_t)v.x, (bf16_t)v.y, (bf16_t)v.z, (bf16_t)v.w};
  *(bf16x4*)(dst + (size_t)i * 4) = o;
}

__global__ __launch_bounds__(256) void perm_cast_k(const float* __restrict__ src,
                                                   bf16_t* __restrict__ dst)
{
  const int i = blockIdx.x * 256 + threadIdx.x;  // 1536*128
  const int pg = i >> 7, kq = (i & 127) << 2;
  const int g = pg / 48, rem = pg - g * 48, sec = rem >> 4, jj = rem & 15;
  const int srow = sec * 512 + g * 16 + jj;
  float4 v = *(const float4*)(src + (size_t)srow * DIN + kq);
  bf16x4 o = {(bf16_t)v.x, (bf16_t)v.y, (bf16_t)v.z, (bf16_t)v.w};
  *(bf16x4*)(dst + (size_t)pg * DIN + kq) = o;
}

__global__ void perm_bias_k(const float* __restrict__ bih, const float* __restrict__ bhh,
                            float* __restrict__ bihp, float* __restrict__ bhhp)
{
  const int pg = blockIdx.x * 256 + threadIdx.x;
  if (pg >= G3) return;
  const int g = pg / 48, rem = pg - g * 48, sec = rem >> 4, jj = rem & 15;
  const int srow = sec * 512 + g * 16 + jj;
  bihp[pg] = bih[srow];
  bhhp[pg] = bhh[srow];
}

__global__ void bcat_k(const float* __restrict__ a, const float* __restrict__ b,
                       const float* __restrict__ c, float* __restrict__ d)
{
  const int i = blockIdx.x * 256 + threadIdx.x;
  if (i >= G3) return;
  d[i] = i < 512 ? a[i] : (i < 1024 ? b[i - 512] : c[i - 1024]);
}

__global__ __launch_bounds__(256) void yemb_k(const int* __restrict__ y,
                                              const float* __restrict__ embW,
                                              bf16_t* __restrict__ out)
{
  const int idx = blockIdx.x * 256 + threadIdx.x;  // 2048*64
  const int rb = idx >> 6, c = (idx & 63) << 3;
  const int tok = y[rb];
  const float4* s = (const float4*)(embW + (size_t)tok * DIN + c);
  float4 v0 = s[0], v1 = s[1];
  bf16x8 o = {(bf16_t)v0.x, (bf16_t)v0.y, (bf16_t)v0.z, (bf16_t)v0.w,
              (bf16_t)v1.x, (bf16_t)v1.y, (bf16_t)v1.z, (bf16_t)v1.w};
  *(bf16x8*)(out + (size_t)rb * DIN + c) = o;
}

__global__ __launch_bounds__(256) void ct_k(const float* __restrict__ ctx,
                                            const float* __restrict__ Watt,
                                            const float* __restrict__ batt,
                                            float* __restrict__ ct)
{
  const int idx = blockIdx.x * 256 + threadIdx.x;  // 64*512
  const int b = idx >> 9, j = idx & 511;
  const float4* c4 = (const float4*)(ctx + (size_t)b * FFEAT);
  const float4* w4 = (const float4*)(Watt + (size_t)j * FFEAT);
  float s = batt[j];
  for (int q = 0; q < FFEAT / 4; ++q) {
    float4 cc = c4[q], ww = w4[q];
    s += cc.x * ww.x + cc.y * ww.y + cc.z * ww.z + cc.w * ww.w;
  }
  ct[idx] = tanhf(s);
}

__global__ __launch_bounds__(256) void reduce_rows(const float* __restrict__ partial,
                                                   float* __restrict__ rowsum, int NB)
{
  const int wv = threadIdx.x >> 6, lane = threadIdx.x & 63;
  const int row = blockIdx.x * 4 + wv;
  float s = 0.f;
  for (int c = lane; c < NB; c += 64) s += partial[(size_t)row * NB + c];
  for (int m = 1; m < 64; m <<= 1) s += __shfl_xor(s, m);
  if (lane == 0) rowsum[row] = s;
}

// ---------------------------------------------------------------------------
extern "C" void kernel_launch(void* const* d_in, const int* in_sizes, int n_in,
                              void* d_out, int out_size, void* d_ws, size_t ws_size,
                              hipStream_t stream)
{
  const int*   y     = (const int*)  d_in[0];
  const float* ctx   = (const float*)d_in[1];
  const float* embW  = (const float*)d_in[2];
  const float* W_ih  = (const float*)d_in[3];
  const float* b_ih  = (const float*)d_in[4];
  const float* W_hh  = (const float*)d_in[5];
  const float* b_hh  = (const float*)d_in[6];
  const float* W_att = (const float*)d_in[7];
  const float* b_att = (const float*)d_in[8];
  const float* Wq    = (const float*)d_in[9];
  const float* bq    = (const float*)d_in[10];
  const float* Wk    = (const float*)d_in[11];
  const float* bk    = (const float*)d_in[12];
  const float* Wv    = (const float*)d_in[13];
  const float* bv    = (const float*)d_in[14];
  const float* Wfc   = (const float*)d_in[15];
  const float* bfc   = (const float*)d_in[16];
  const float* Wh2o  = (const float*)d_in[17];
  const float* bh2o  = (const float*)d_in[18];
  const float* W_out = (const float*)d_in[19];
  const float* b_out = (const float*)d_in[20];

  char* p = (char*)d_ws;
  auto alloc = [&](size_t bytes) {
    char* r = p;
    p += (bytes + 255) & ~(size_t)255;
    return r;
  };
  bf16_t* WoutB   = (bf16_t*)alloc((size_t)VOCAB * DIN * 2);
  bf16_t* WgIh    = (bf16_t*)alloc((size_t)G3 * DIN * 2);
  bf16_t* WgHh    = (bf16_t*)alloc((size_t)G3 * DIN * 2);
  bf16_t* Wqkv    = (bf16_t*)alloc((size_t)G3 * DIN * 2);
  bf16_t* WfcB    = (bf16_t*)alloc((size_t)HID * HID * 2);
  bf16_t* Wh2oB   = (bf16_t*)alloc((size_t)HID * HID * 2);
  float*  bIhP    = (float*)alloc(G3 * 4);
  float*  bHhP    = (float*)alloc(G3 * 4);
  float*  bQkv    = (float*)alloc(G3 * 4);
  bf16_t* Yemb    = (bf16_t*)alloc((size_t)ROWS * DIN * 2);
  float*  giP     = (float*)alloc((size_t)ROWS * G3 * 4);
  float*  ctB     = (float*)alloc((size_t)BATCH * HID * 4);
  unsigned int* hbuf = (unsigned int*)alloc((size_t)2 * 16384 * 4);
  bf16_t* Xall    = (bf16_t*)alloc((size_t)ROWS * DIN * 2);
  bf16_t* QKV     = (bf16_t*)alloc((size_t)ROWS * G3 * 2);
  bf16_t* attO    = (bf16_t*)alloc((size_t)ROWS * HID * 2);
  bf16_t* h2B     = (bf16_t*)alloc((size_t)ROWS * HID * 2);
  bf16_t* logit   = (bf16_t*)alloc((size_t)ROWS * DIN * 2);
  float*  partial = (float*)alloc((size_t)ROWS * 250 * 4);
  float*  rowsum  = (float*)alloc((size_t)ROWS * 4);
  int*    flags   = (int*)alloc(32 * 4 * 64);

  hipMemsetAsync(hbuf, 0, (size_t)2 * 16384 * 4, stream);  // h0 = 0
  hipMemsetAsync(flags, 0, 32 * 4 * 64, stream);

  // weight prep
  cast_k<<<(VOCAB * DIN / 4 + 255) / 256, 256, 0, stream>>>(W_out, WoutB, VOCAB * DIN / 4);
  cast_k<<<256, 256, 0, stream>>>(Wq, Wqkv, HID * HID / 4);
  cast_k<<<256, 256, 0, stream>>>(Wk, Wqkv + (size_t)HID * DIN, HID * HID / 4);
  cast_k<<<256, 256, 0, stream>>>(Wv, Wqkv + (size_t)2 * HID * DIN, HID * HID / 4);
  cast_k<<<256, 256, 0, stream>>>(Wfc, WfcB, HID * HID / 4);
  cast_k<<<256, 256, 0, stream>>>(Wh2o, Wh2oB, HID * HID / 4);
  perm_cast_k<<<768, 256, 0, stream>>>(W_ih, WgIh);
  perm_cast_k<<<768, 256, 0, stream>>>(W_hh, WgHh);
  perm_bias_k<<<6, 256, 0, stream>>>(b_ih, b_hh, bIhP, bHhP);
  bcat_k<<<6, 256, 0, stream>>>(bq, bk, bv, bQkv);
  yemb_k<<<512, 256, 0, stream>>>(y, embW, Yemb);
  ct_k<<<128, 256, 0, stream>>>(ctx, W_att, b_att, ctB);

  // gi for all steps: [2048,512] @ [1536,512]^T -> fp32 (bias = b_ih)
  gemm_lds<EPI_F32><<<dim3(12, 16), 256, 0, stream>>>(
      Yemb, WgIh, bIhP, giP, nullptr, nullptr, ROWS, G3, DIN, 12);

  // sequential GRU recurrence -> Xall = h1 * ct (bf16)
  phaseA_k<<<NBLK_A, 256, 0, stream>>>(WgHh, bHhP, giP, ctB, hbuf, Xall, flags);

  // QKV = X @ [Wq;Wk;Wv]^T + b
  gemm_lds<EPI_BF16><<<dim3(12, 16), 256, 0, stream>>>(
      Xall, Wqkv, bQkv, QKV, nullptr, nullptr, ROWS, G3, DIN, 12);

  attn_k<<<512, 256, 0, stream>>>(QKV, attO);

  // h2 = att @ Wfc^T + bfc
  gemm_lds<EPI_BF16><<<dim3(4, 16), 256, 0, stream>>>(
      attO, WfcB, bfc, h2B, nullptr, nullptr, ROWS, HID, HID, 4);

  // logit = tanh(h2 @ Wh2o^T + b)
  gemm_lds<EPI_TANH><<<dim3(4, 16), 256, 0, stream>>>(
      h2B, Wh2oB, bh2o, logit, nullptr, nullptr, ROWS, DIN, HID, 4);

  // pass 1: rowsums of exp(logit @ W_out^T + b) -- no 262MB store
  gemm_lds<EPI_SUM><<<dim3(250 * 16), 256, 0, stream>>>(
      logit, WoutB, b_out, nullptr, partial, nullptr, ROWS, VOCAB, DIN, 250);
  reduce_rows<<<512, 256, 0, stream>>>(partial, rowsum, 250);
  // pass 2: recompute, write normalized f32 probs directly
  gemm_lds<EPI_PROB><<<dim3(250 * 16), 256, 0, stream>>>(
      logit, WoutB, b_out, d_out, nullptr, rowsum, ROWS, VOCAB, DIN, 250);
}

// Round 7
// 492.076 us; speedup vs baseline: 1.5933x; 1.0251x over previous
//
#include <hip/hip_runtime.h>
#include <hip/hip_bf16.h>
#include <math.h>

typedef __bf16 bf16_t;
typedef __bf16 bf16x8 __attribute__((ext_vector_type(8)));
typedef __bf16 bf16x4 __attribute__((ext_vector_type(4)));
typedef float  f32x4  __attribute__((ext_vector_type(4)));

#define T_STEPS 32
#define BATCH   64
#define DIN     512
#define HID     512
#define VOCAB   32000
#define FFEAT   768
#define ROWS    2048   /* T*B */
#define G3      1536   /* 3*H */
#define NBLK_A  32

#define EPI_F32  0
#define EPI_BF16 1
#define EPI_TANH 2
#define EPI_SUM  3   /* exp + partial row sums only, no store */
#define EPI_PROB 4   /* exp * 1/rowsum -> f32 store (final probs) */

#define GLOAD16(gp, lp) __builtin_amdgcn_global_load_lds( \
    (const __attribute__((address_space(1))) void*)(gp),  \
    (__attribute__((address_space(3))) void*)(lp), 16, 0, 0)

// ===========================================================================
// gemm_v: 256x256 8-phase GEMM (guide §5 template) for the VOCAB passes.
// C[M][N] = A[M][K]@B[N][K]^T + bias, EPI_SUM / EPI_PROB only.
// 512 thr = 8 waves (2M x 4N). Wave rows: {wm*64..+63} U {128+wm*64..+63};
// wave cols: {wn*32..+31} U {128+wn*32..+31} (interleaved so each 128-row
// half-tile frees after 2 phases -> continuous stage stream).
// K-tile BK=64; LDS = 2 bufs x 4 halves (Ah0,Ah1,Bh0,Bh1) x [128][64] bf16
// = 128 KB. Iteration = 8 phases consuming K-tiles T(2i) [ph1-4, buf0] and
// T(2i+1) [ph5-8, buf1]; each phase: 12 ds_read_b128 + stage 1 half-tile
// (2 gload_lds/thread) + barrier + 16 MFMA (setprio) + barrier.
// Stage schedule (stage at free+1 phase):
//   ph1:T(2i+1).Ah1  ph2:T(2i+1).Bh1  ph3:T(2i+2).Ah0  ph4:T(2i+2).Bh0
//   ph5:T(2i+2).Ah1  ph6:T(2i+2).Bh1  ph7:T(2i+3).Ah0  ph8:T(2i+3).Bh0
// Gates: vmcnt(4) inside ph4 and ph8 only (keeps 2 half-tiles in flight);
// final iteration drains vmcnt(0) at ph4. Deadlines verified per half.
// Swizzle (T2, rule 21): LDS 16B slot s holds data chunk c = s ^ (row&7);
// inverse applied on the GLOBAL source addr (gload_lds dest stays linear),
// same XOR on ds_read -> quarter-wave banks = 8 slots x 2 rows = 2-way (free).
// ===========================================================================
#define PHASEV(BUF, MH, NH, STAGE_STMT, GATE_STMT)                            \
  {                                                                           \
    bf16x8 af_[8], bf_[4];                                                    \
    _Pragma("unroll")                                                         \
    for (int m2 = 0; m2 < 4; ++m2) {                                          \
      const int row = wm * 64 + m2 * 16 + la;                                 \
      _Pragma("unroll")                                                       \
      for (int ks = 0; ks < 2; ++ks) {                                        \
        const int sl = (ks * 4 + lg) ^ (row & 7);                             \
        af_[m2 * 2 + ks] =                                                    \
            *(const bf16x8*)&lds[((BUF)*4 + (MH)) * 8192 + row * 64 + sl * 8];\
      }                                                                       \
    }                                                                         \
    _Pragma("unroll")                                                         \
    for (int n2 = 0; n2 < 2; ++n2) {                                          \
      const int row = wn * 32 + n2 * 16 + la;                                 \
      _Pragma("unroll")                                                       \
      for (int ks = 0; ks < 2; ++ks) {                                        \
        const int sl = (ks * 4 + lg) ^ (row & 7);                             \
        bf_[n2 * 2 + ks] =                                                    \
            *(const bf16x8*)&lds[((BUF)*4 + 2 + (NH)) * 8192 + row * 64 + sl * 8];\
      }                                                                       \
    }                                                                         \
    STAGE_STMT;                                                               \
    GATE_STMT;                                                                \
    __builtin_amdgcn_s_barrier();                                             \
    __builtin_amdgcn_s_setprio(1);                                            \
    _Pragma("unroll")                                                         \
    for (int m2 = 0; m2 < 4; ++m2)                                            \
      _Pragma("unroll")                                                       \
      for (int n2 = 0; n2 < 2; ++n2)                                          \
        _Pragma("unroll")                                                     \
        for (int ks = 0; ks < 2; ++ks)                                        \
          acc[(MH)*4 + m2][(NH)*2 + n2] =                                     \
              __builtin_amdgcn_mfma_f32_16x16x32_bf16(                        \
                  af_[m2*2+ks], bf_[n2*2+ks],                                 \
                  acc[(MH)*4 + m2][(NH)*2 + n2], 0, 0, 0);                    \
    __builtin_amdgcn_s_setprio(0);                                            \
    __builtin_amdgcn_s_barrier();                                             \
  }

template<int EPI>
__global__ __launch_bounds__(512, 2) void gemm_v(
    const bf16_t* __restrict__ A, const bf16_t* __restrict__ B,
    const float* __restrict__ bias, float* __restrict__ out,
    float* __restrict__ partial, const float* __restrict__ rowsum,
    int M, int N, int K, int NB)
{
  __shared__ bf16_t lds[2 * 4 * 8192];   // 128 KB
  __shared__ float psum[256][4];
  const int tid = threadIdx.x;
  const int lane = tid & 63, wv = tid >> 6;
  const int wm = wv >> 2, wn = wv & 3;
  const int la = lane & 15, lg = lane >> 4;

  // bn-major XCD-chunk swizzle (nwg = NB * M/256, multiple of 8)
  const int lin = blockIdx.x;
  const int mt = M >> 8;                       // 8
  const int cpx = (NB * mt) >> 3;
  const int wg = (lin & 7) * cpx + (lin >> 3);
  const int bn = wg / mt, bm = wg - bn * mt;   // mt=8 -> cheap

  // stage one 128x64 half-tile (2 x gload16/thread, src pre-unswizzled)
  auto stageA = [&](int buf, int h, int kt) {
    const size_t base = (size_t)(bm * 256 + h * 128) * K + (size_t)kt * 64;
#pragma unroll
    for (int q = 0; q < 2; ++q) {
      const int L = q * 512 + tid;
      const int row = L >> 3, sl = L & 7;
      const int c = sl ^ (row & 7);
      GLOAD16(A + base + (size_t)row * K + c * 8,
              &lds[(buf * 4 + h) * 8192 + L * 8]);
    }
  };
  auto stageB = [&](int buf, int h, int kt) {
    const size_t base = (size_t)(bn * 256 + h * 128) * K + (size_t)kt * 64;
#pragma unroll
    for (int q = 0; q < 2; ++q) {
      const int L = q * 512 + tid;
      const int row = L >> 3, sl = L & 7;
      const int c = sl ^ (row & 7);
      GLOAD16(B + base + (size_t)row * K + c * 8,
              &lds[(buf * 4 + 2 + h) * 8192 + L * 8]);
    }
  };

  f32x4 acc[8][4] = {};
  const int NITER = K >> 7;                    // K/128 (=4 for K=512)

  // prologue: T0 all 4 halves + T1.{Ah0,Bh0}; T0 landed (4 ops in flight)
  stageA(0, 0, 0); stageB(0, 0, 0); stageA(0, 1, 0); stageB(0, 1, 0);
  stageA(1, 0, 1); stageB(1, 0, 1);
  asm volatile("s_waitcnt vmcnt(4)" ::: "memory");
  __builtin_amdgcn_s_barrier();

  for (int it = 0; it < NITER; ++it) {
    const int t0 = 2 * it;
    const bool lastI = (it == NITER - 1);
    PHASEV(0, 0, 0, { stageA(1, 1, t0 + 1); }, ;)
    PHASEV(0, 0, 1, { stageB(1, 1, t0 + 1); }, ;)
    PHASEV(0, 1, 0, { if (!lastI) stageA(0, 0, t0 + 2); }, ;)
    PHASEV(0, 1, 1, { if (!lastI) stageB(0, 0, t0 + 2); },
           { if (lastI) { asm volatile("s_waitcnt vmcnt(0)" ::: "memory"); }
             else       { asm volatile("s_waitcnt vmcnt(4)" ::: "memory"); } })
    PHASEV(1, 0, 0, { if (!lastI) stageA(0, 1, t0 + 2); }, ;)
    PHASEV(1, 0, 1, { if (!lastI) stageB(0, 1, t0 + 2); }, ;)
    PHASEV(1, 1, 0, { if (!lastI) stageA(1, 0, t0 + 3); }, ;)
    PHASEV(1, 1, 1, { if (!lastI) stageB(1, 0, t0 + 3); },
           { if (!lastI) { asm volatile("s_waitcnt vmcnt(4)" ::: "memory"); } })
  }

  // epilogue --------------------------------------------------------------
  float bv[4];
#pragma unroll
  for (int nj = 0; nj < 4; ++nj) {
    const int col = bn * 256 + (nj >> 1) * 128 + wn * 32 + (nj & 1) * 16 + la;
    bv[nj] = bias[col];
  }
#pragma unroll
  for (int mi = 0; mi < 8; ++mi) {
#pragma unroll
    for (int rr = 0; rr < 4; ++rr) {
      const int rowl = (mi >> 2) * 128 + wm * 64 + (mi & 3) * 16 + lg * 4 + rr;
      const int row = bm * 256 + rowl;
      float vsum = 0.f, inv;
      if constexpr (EPI == EPI_PROB) inv = 1.0f / rowsum[row];
#pragma unroll
      for (int nj = 0; nj < 4; ++nj) {
        const float v = acc[mi][nj][rr] + bv[nj];
        if constexpr (EPI == EPI_SUM) {
          vsum += expf(v);
        } else {
          const int col = bn * 256 + (nj >> 1) * 128 + wn * 32 + (nj & 1) * 16 + la;
          out[(size_t)row * N + col] = expf(v) * inv;
        }
      }
      if constexpr (EPI == EPI_SUM) {
        vsum += __shfl_xor(vsum, 1);
        vsum += __shfl_xor(vsum, 2);
        vsum += __shfl_xor(vsum, 4);
        vsum += __shfl_xor(vsum, 8);
        if (la == 0) psum[rowl][wn] = vsum;
      }
    }
  }
  if constexpr (EPI == EPI_SUM) {
    __syncthreads();
    if (tid < 256) {
      partial[(size_t)(bm * 256 + tid) * NB + bn] =
          psum[tid][0] + psum[tid][1] + psum[tid][2] + psum[tid][3];
    }
  }
  (void)out; (void)partial; (void)rowsum;
}

// ---------------------------------------------------------------------------
// 128x128 LDS GEMM (R6 pipeline) for the small GEMMs (gi, QKV, fc, h2o).
// ---------------------------------------------------------------------------
template<int EPI>
__global__ __launch_bounds__(256) void gemm_lds(
    const bf16_t* __restrict__ A, const bf16_t* __restrict__ B,
    const float* __restrict__ bias, void* __restrict__ out,
    int M, int N, int K)
{
  __shared__ bf16_t As[3][128 * 32];
  __shared__ bf16_t Bs[3][128 * 32];

  const int lane = threadIdx.x & 63;
  const int wv   = threadIdx.x >> 6;
  const int wm = wv >> 1, wn = wv & 1;
  const int bn = blockIdx.x, bm = blockIdx.y;
  const int la = lane & 15, lg = lane >> 4;
  const int tid = threadIdx.x;

  auto stage = [&](int buf, int k0) {
#pragma unroll
    for (int q = 0; q < 2; ++q) {
      const int idx = q * 256 + tid;
      const int row = idx >> 2, c = idx & 3;
      const int gch = c ^ ((row >> 1) & 3);
      GLOAD16(A + (size_t)(bm * 128 + row) * K + k0 + gch * 8, &As[buf][idx * 8]);
      GLOAD16(B + (size_t)(bn * 128 + row) * K + k0 + gch * 8, &Bs[buf][idx * 8]);
    }
  };
  const int rdch = (lg ^ ((la >> 1) & 3)) * 8;

  f32x4 acc[4][4] = {};
  const int NT = K >> 5;
  stage(0, 0);
  stage(1, 32);
  for (int kt = 0; kt < NT; ++kt) {
    if (kt + 1 < NT) {
      asm volatile("s_waitcnt vmcnt(4)" ::: "memory");
    } else {
      asm volatile("s_waitcnt vmcnt(0)" ::: "memory");
    }
    __builtin_amdgcn_s_barrier();
    __builtin_amdgcn_sched_barrier(0);
    if (kt + 2 < NT) stage((kt + 2) % 3, (kt + 2) * 32);
    const bf16_t* Ab = As[kt % 3];
    const bf16_t* Bb = Bs[kt % 3];
    bf16x8 a[4], b[4];
#pragma unroll
    for (int i = 0; i < 4; ++i)
      a[i] = *(const bf16x8*)(Ab + (wm * 64 + i * 16 + la) * 32 + rdch);
#pragma unroll
    for (int j = 0; j < 4; ++j)
      b[j] = *(const bf16x8*)(Bb + (wn * 64 + j * 16 + la) * 32 + rdch);
    __builtin_amdgcn_s_setprio(1);
#pragma unroll
    for (int i = 0; i < 4; ++i)
#pragma unroll
      for (int j = 0; j < 4; ++j)
        acc[i][j] = __builtin_amdgcn_mfma_f32_16x16x32_bf16(a[i], b[j], acc[i][j], 0, 0, 0);
    __builtin_amdgcn_s_setprio(0);
  }

  const int m0 = bm * 128 + wm * 64;
  const int n0 = bn * 128 + wn * 64;
  float bv4[4];
#pragma unroll
  for (int j = 0; j < 4; ++j) bv4[j] = bias[n0 + j * 16 + la];
#pragma unroll
  for (int i = 0; i < 4; ++i) {
#pragma unroll
    for (int r = 0; r < 4; ++r) {
      const int row = m0 + i * 16 + lg * 4 + r;
#pragma unroll
      for (int j = 0; j < 4; ++j) {
        const int col = n0 + j * 16 + la;
        float v = acc[i][j][r] + bv4[j];
        if constexpr (EPI == EPI_F32) {
          ((float*)out)[(size_t)row * N + col] = v;
        } else if constexpr (EPI == EPI_BF16) {
          ((bf16_t*)out)[(size_t)row * N + col] = (bf16_t)v;
        } else {
          ((bf16_t*)out)[(size_t)row * N + col] = (bf16_t)tanhf(v);
        }
      }
    }
  }
}

// ---------------------------------------------------------------------------
// Phase A: sequential GRU recurrence (blocks 0..31) + fused W_out cast on
// otherwise-idle CUs (blocks 32..223; all 224 co-resident so spin-flags safe).
// ---------------------------------------------------------------------------
__global__ __launch_bounds__(256) void phaseA_k(
    const bf16_t* __restrict__ Wg, const float* __restrict__ bhh,
    const float* __restrict__ gi, const float* __restrict__ ct,
    unsigned int* __restrict__ hbuf, bf16_t* __restrict__ Xall,
    int* __restrict__ flags, const float* __restrict__ Wout_f32,
    bf16_t* __restrict__ WoutB)
{
  __shared__ bf16_t Wl[48 * 520];
  __shared__ float bl[48];
  const int tid = threadIdx.x, blk = blockIdx.x;

  if (blk >= NBLK_A) {                          // cast crew
    const int NCB = gridDim.x - NBLK_A;
    const int n4 = VOCAB * DIN / 4;
    for (int i = (blk - NBLK_A) * 256 + tid; i < n4; i += NCB * 256) {
      float4 v = ((const float4*)Wout_f32)[i];
      bf16x4 o = {(bf16_t)v.x, (bf16_t)v.y, (bf16_t)v.z, (bf16_t)v.w};
      *(bf16x4*)(WoutB + (size_t)i * 4) = o;
    }
    return;
  }

  for (int i = tid; i < 48 * 64; i += 256) {
    const int rw = i >> 6, ch = (i & 63) << 3;
    *(bf16x8*)(Wl + rw * 520 + ch) = *(const bf16x8*)(Wg + (size_t)(blk * 48 + rw) * 512 + ch);
  }
  if (tid < 48) bl[tid] = bhh[blk * 48 + tid];
  __syncthreads();

  const int lane = tid & 63, wv = tid >> 6;
  const int la = lane & 15, lg = lane >> 4;
  const int jcol = blk * 16 + la;
  const int rowA = wv * 16 + la;

  const float blr = bl[la], blz = bl[16 + la], bln = bl[32 + la];
  float hprev[4], ctv[4];
#pragma unroll
  for (int r = 0; r < 4; ++r) {
    hprev[r] = 0.f;
    ctv[r] = ct[(size_t)(wv * 16 + lg * 4 + r) * HID + jcol];
  }

  for (int t = 0; t < T_STEPS; ++t) {
    const float* girow = gi + (size_t)t * BATCH * G3 + (size_t)blk * 48;
    float gv[12];
#pragma unroll
    for (int r = 0; r < 4; ++r) {
      const float* gp = girow + (size_t)(wv * 16 + lg * 4 + r) * G3;
      gv[r * 3 + 0] = gp[la];
      gv[r * 3 + 1] = gp[16 + la];
      gv[r * 3 + 2] = gp[32 + la];
    }
    if (t > 0) {
      if (lane < 32) {
        while (__hip_atomic_load(&flags[(lane * 4 + wv) * 16], __ATOMIC_RELAXED,
                                 __HIP_MEMORY_SCOPE_AGENT) < t)
          __builtin_amdgcn_s_sleep(1);
      }
      asm volatile("" ::: "memory");
    }
    const unsigned long long* hb =
        (const unsigned long long*)(hbuf + (size_t)(t & 1) * 16384);
    bf16x8 af[16];
#pragma unroll
    for (int q = 0; q < 16; ++q) {
      union { unsigned long long u[2]; bf16x8 v; } c;
      const size_t bidx = (size_t)(2 * q + (lg >> 1)) * 256 + rowA * 4 + (lg & 1) * 2;
      c.u[0] = __hip_atomic_load(hb + bidx,     __ATOMIC_RELAXED, __HIP_MEMORY_SCOPE_AGENT);
      c.u[1] = __hip_atomic_load(hb + bidx + 1, __ATOMIC_RELAXED, __HIP_MEMORY_SCOPE_AGENT);
      af[q] = c.v;
    }
    f32x4 acc0 = {}, acc1 = {}, acc2 = {};
#pragma unroll
    for (int q = 0; q < 16; ++q) {
      const bf16_t* wp = Wl + q * 32 + lg * 8;
      bf16x8 b0 = *(const bf16x8*)(wp + (0 * 16 + la) * 520);
      bf16x8 b1 = *(const bf16x8*)(wp + (1 * 16 + la) * 520);
      bf16x8 b2 = *(const bf16x8*)(wp + (2 * 16 + la) * 520);
      acc0 = __builtin_amdgcn_mfma_f32_16x16x32_bf16(af[q], b0, acc0, 0, 0, 0);
      acc1 = __builtin_amdgcn_mfma_f32_16x16x32_bf16(af[q], b1, acc1, 0, 0, 0);
      acc2 = __builtin_amdgcn_mfma_f32_16x16x32_bf16(af[q], b2, acc2, 0, 0, 0);
    }
    float h1v[4];
#pragma unroll
    for (int r = 0; r < 4; ++r) {
      const float ghr = acc0[r] + blr;
      const float ghz = acc1[r] + blz;
      const float ghn = acc2[r] + bln;
      const float rr = 1.f / (1.f + expf(-(gv[r * 3 + 0] + ghr)));
      const float zz = 1.f / (1.f + expf(-(gv[r * 3 + 1] + ghz)));
      const float nn = tanhf(gv[r * 3 + 2] + rr * ghn);
      h1v[r] = (1.f - zz) * nn + zz * hprev[r];
      hprev[r] = h1v[r];
    }
    unsigned int* hn = hbuf + (size_t)((t + 1) & 1) * 16384 + blk * 512;
#pragma unroll
    for (int r = 0; r < 4; ++r) {
      const int row = wv * 16 + lg * 4 + r;
      const unsigned int mine =
          (unsigned int)__builtin_bit_cast(unsigned short, (bf16_t)h1v[r]);
      const unsigned int other = (unsigned int)__shfl_xor((int)mine, 1);
      if ((la & 1) == 0) {
        __hip_atomic_store(hn + row * 8 + (la >> 1), mine | (other << 16),
                           __ATOMIC_RELAXED, __HIP_MEMORY_SCOPE_AGENT);
      }
    }
    asm volatile("s_waitcnt vmcnt(0)" ::: "memory");
    if (lane == 0) {
      __hip_atomic_store(&flags[(blk * 4 + wv) * 16], t + 1, __ATOMIC_RELAXED,
                         __HIP_MEMORY_SCOPE_AGENT);
    }
#pragma unroll
    for (int r = 0; r < 4; ++r) {
      const int row = wv * 16 + lg * 4 + r;
      Xall[((size_t)t * BATCH + row) * HID + jcol] = (bf16_t)(h1v[r] * ctv[r]);
    }
  }
}

// ---------------------------------------------------------------------------
__global__ __launch_bounds__(256) void attn_k(const bf16_t* __restrict__ QKV,
                                              bf16_t* __restrict__ attO)
{
  __shared__ float sq[4][512], sk[4][512], sv[4][512], sw[4][64];
  const int tid = threadIdx.x;
  const int wv = tid >> 6, lane = tid & 63;
  const int row = blockIdx.x * 4 + wv;
  const bf16_t* base = QKV + (size_t)row * G3;
  bf16x8 vq = *(const bf16x8*)(base + lane * 8);
  bf16x8 vk = *(const bf16x8*)(base + 512 + lane * 8);
  bf16x8 vv = *(const bf16x8*)(base + 1024 + lane * 8);
#pragma unroll
  for (int e = 0; e < 8; ++e) {
    sq[wv][lane * 8 + e] = (float)vq[e];
    sk[wv][lane * 8 + e] = (float)vk[e];
    sv[wv][lane * 8 + e] = (float)vv[e];
  }
  __syncthreads();
  const int h = lane >> 3, g = lane & 7;
  float s = 0.f;
#pragma unroll 16
  for (int d = 0; d < 64; ++d) s += sq[wv][h * 64 + d] * sk[wv][g * 64 + d];
  s *= (1.f / 64.f);
  float m = s;
  m = fmaxf(m, __shfl_xor(m, 1));
  m = fmaxf(m, __shfl_xor(m, 2));
  m = fmaxf(m, __shfl_xor(m, 4));
  const float e = expf(s - m);
  float sum = e;
  sum += __shfl_xor(sum, 1);
  sum += __shfl_xor(sum, 2);
  sum += __shfl_xor(sum, 4);
  sw[wv][lane] = e / sum;
  __syncthreads();
#pragma unroll
  for (int rep = 0; rep < 8; ++rep) {
    const int idx = rep * 64 + lane;
    const int hh = idx >> 6, d = idx & 63;
    float o = 0.f;
#pragma unroll
    for (int gg = 0; gg < 8; ++gg) o += sw[wv][hh * 8 + gg] * sv[wv][gg * 64 + d];
    attO[(size_t)row * HID + idx] = (bf16_t)o;
  }
}

// --------------------------- small prep kernels ----------------------------
__global__ __launch_bounds__(256) void cast_k(const float* __restrict__ src,
                                              bf16_t* __restrict__ dst, int n4)
{
  const int i = blockIdx.x * 256 + threadIdx.x;
  if (i >= n4) return;
  float4 v = ((const float4*)src)[i];
  bf16x4 o = {(bf16_t)v.x, (bf16_t)v.y, (bf16_t)v.z, (bf16_t)v.w};
  *(bf16x4*)(dst + (size_t)i * 4) = o;
}

__global__ __launch_bounds__(256) void perm_cast_k(const float* __restrict__ src,
                                                   bf16_t* __restrict__ dst)
{
  const int i = blockIdx.x * 256 + threadIdx.x;
  const int pg = i >> 7, kq = (i & 127) << 2;
  const int g = pg / 48, rem = pg - g * 48, sec = rem >> 4, jj = rem & 15;
  const int srow = sec * 512 + g * 16 + jj;
  float4 v = *(const float4*)(src + (size_t)srow * DIN + kq);
  bf16x4 o = {(bf16_t)v.x, (bf16_t)v.y, (bf16_t)v.z, (bf16_t)v.w};
  *(bf16x4*)(dst + (size_t)pg * DIN + kq) = o;
}

__global__ void perm_bias_k(const float* __restrict__ bih, const float* __restrict__ bhh,
                            float* __restrict__ bihp, float* __restrict__ bhhp)
{
  const int pg = blockIdx.x * 256 + threadIdx.x;
  if (pg >= G3) return;
  const int g = pg / 48, rem = pg - g * 48, sec = rem >> 4, jj = rem & 15;
  const int srow = sec * 512 + g * 16 + jj;
  bihp[pg] = bih[srow];
  bhhp[pg] = bhh[srow];
}

__global__ void bcat_k(const float* __restrict__ a, const float* __restrict__ b,
                       const float* __restrict__ c, float* __restrict__ d)
{
  const int i = blockIdx.x * 256 + threadIdx.x;
  if (i >= G3) return;
  d[i] = i < 512 ? a[i] : (i < 1024 ? b[i - 512] : c[i - 1024]);
}

__global__ __launch_bounds__(256) void yemb_k(const int* __restrict__ y,
                                              const float* __restrict__ embW,
                                              bf16_t* __restrict__ out)
{
  const int idx = blockIdx.x * 256 + threadIdx.x;
  const int rb = idx >> 6, c = (idx & 63) << 3;
  const int tok = y[rb];
  const float4* s = (const float4*)(embW + (size_t)tok * DIN + c);
  float4 v0 = s[0], v1 = s[1];
  bf16x8 o = {(bf16_t)v0.x, (bf16_t)v0.y, (bf16_t)v0.z, (bf16_t)v0.w,
              (bf16_t)v1.x, (bf16_t)v1.y, (bf16_t)v1.z, (bf16_t)v1.w};
  *(bf16x8*)(out + (size_t)rb * DIN + c) = o;
}

__global__ __launch_bounds__(256) void ct_k(const float* __restrict__ ctx,
                                            const float* __restrict__ Watt,
                                            const float* __restrict__ batt,
                                            float* __restrict__ ct)
{
  const int idx = blockIdx.x * 256 + threadIdx.x;
  const int b = idx >> 9, j = idx & 511;
  const float4* c4 = (const float4*)(ctx + (size_t)b * FFEAT);
  const float4* w4 = (const float4*)(Watt + (size_t)j * FFEAT);
  float s = batt[j];
  for (int q = 0; q < FFEAT / 4; ++q) {
    float4 cc = c4[q], ww = w4[q];
    s += cc.x * ww.x + cc.y * ww.y + cc.z * ww.z + cc.w * ww.w;
  }
  ct[idx] = tanhf(s);
}

__global__ __launch_bounds__(256) void reduce_rows(const float* __restrict__ partial,
                                                   float* __restrict__ rowsum, int NB)
{
  const int wv = threadIdx.x >> 6, lane = threadIdx.x & 63;
  const int row = blockIdx.x * 4 + wv;
  float s = 0.f;
  for (int c = lane; c < NB; c += 64) s += partial[(size_t)row * NB + c];
  for (int m = 1; m < 64; m <<= 1) s += __shfl_xor(s, m);
  if (lane == 0) rowsum[row] = s;
}

// ---------------------------------------------------------------------------
extern "C" void kernel_launch(void* const* d_in, const int* in_sizes, int n_in,
                              void* d_out, int out_size, void* d_ws, size_t ws_size,
                              hipStream_t stream)
{
  const int*   y     = (const int*)  d_in[0];
  const float* ctx   = (const float*)d_in[1];
  const float* embW  = (const float*)d_in[2];
  const float* W_ih  = (const float*)d_in[3];
  const float* b_ih  = (const float*)d_in[4];
  const float* W_hh  = (const float*)d_in[5];
  const float* b_hh  = (const float*)d_in[6];
  const float* W_att = (const float*)d_in[7];
  const float* b_att = (const float*)d_in[8];
  const float* Wq    = (const float*)d_in[9];
  const float* bq    = (const float*)d_in[10];
  const float* Wk    = (const float*)d_in[11];
  const float* bk    = (const float*)d_in[12];
  const float* Wv    = (const float*)d_in[13];
  const float* bv    = (const float*)d_in[14];
  const float* Wfc   = (const float*)d_in[15];
  const float* bfc   = (const float*)d_in[16];
  const float* Wh2o  = (const float*)d_in[17];
  const float* bh2o  = (const float*)d_in[18];
  const float* W_out = (const float*)d_in[19];
  const float* b_out = (const float*)d_in[20];

  char* p = (char*)d_ws;
  auto alloc = [&](size_t bytes) {
    char* r = p;
    p += (bytes + 255) & ~(size_t)255;
    return r;
  };
  bf16_t* WoutB   = (bf16_t*)alloc((size_t)VOCAB * DIN * 2);
  bf16_t* WgIh    = (bf16_t*)alloc((size_t)G3 * DIN * 2);
  bf16_t* WgHh    = (bf16_t*)alloc((size_t)G3 * DIN * 2);
  bf16_t* Wqkv    = (bf16_t*)alloc((size_t)G3 * DIN * 2);
  bf16_t* WfcB    = (bf16_t*)alloc((size_t)HID * HID * 2);
  bf16_t* Wh2oB   = (bf16_t*)alloc((size_t)HID * HID * 2);
  float*  bIhP    = (float*)alloc(G3 * 4);
  float*  bHhP    = (float*)alloc(G3 * 4);
  float*  bQkv    = (float*)alloc(G3 * 4);
  bf16_t* Yemb    = (bf16_t*)alloc((size_t)ROWS * DIN * 2);
  float*  giP     = (float*)alloc((size_t)ROWS * G3 * 4);
  float*  ctB     = (float*)alloc((size_t)BATCH * HID * 4);
  unsigned int* hbuf = (unsigned int*)alloc((size_t)2 * 16384 * 4);
  bf16_t* Xall    = (bf16_t*)alloc((size_t)ROWS * DIN * 2);
  bf16_t* QKV     = (bf16_t*)alloc((size_t)ROWS * G3 * 2);
  bf16_t* attO    = (bf16_t*)alloc((size_t)ROWS * HID * 2);
  bf16_t* h2B     = (bf16_t*)alloc((size_t)ROWS * HID * 2);
  bf16_t* logit   = (bf16_t*)alloc((size_t)ROWS * DIN * 2);
  float*  partial = (float*)alloc((size_t)ROWS * 250 * 4);
  float*  rowsum  = (float*)alloc((size_t)ROWS * 4);
  int*    flags   = (int*)alloc(32 * 4 * 64);

  hipMemsetAsync(hbuf, 0, (size_t)2 * 16384 * 4, stream);
  hipMemsetAsync(flags, 0, 32 * 4 * 64, stream);

  // weight prep (W_out cast fused into phaseA launch below)
  cast_k<<<256, 256, 0, stream>>>(Wq, Wqkv, HID * HID / 4);
  cast_k<<<256, 256, 0, stream>>>(Wk, Wqkv + (size_t)HID * DIN, HID * HID / 4);
  cast_k<<<256, 256, 0, stream>>>(Wv, Wqkv + (size_t)2 * HID * DIN, HID * HID / 4);
  cast_k<<<256, 256, 0, stream>>>(Wfc, WfcB, HID * HID / 4);
  cast_k<<<256, 256, 0, stream>>>(Wh2o, Wh2oB, HID * HID / 4);
  perm_cast_k<<<768, 256, 0, stream>>>(W_ih, WgIh);
  perm_cast_k<<<768, 256, 0, stream>>>(W_hh, WgHh);
  perm_bias_k<<<6, 256, 0, stream>>>(b_ih, b_hh, bIhP, bHhP);
  bcat_k<<<6, 256, 0, stream>>>(bq, bk, bv, bQkv);
  yemb_k<<<512, 256, 0, stream>>>(y, embW, Yemb);
  ct_k<<<128, 256, 0, stream>>>(ctx, W_att, b_att, ctB);

  // gi = Yemb @ WgIh^T + bIhP  (fp32)
  gemm_lds<EPI_F32><<<dim3(12, 16), 256, 0, stream>>>(
      Yemb, WgIh, bIhP, giP, ROWS, G3, DIN);

  // GRU recurrence (blocks 0-31) + W_out cast (blocks 32-223)
  phaseA_k<<<224, 256, 0, stream>>>(WgHh, bHhP, giP, ctB, hbuf, Xall, flags,
                                    W_out, WoutB);

  // QKV = X @ [Wq;Wk;Wv]^T + b
  gemm_lds<EPI_BF16><<<dim3(12, 16), 256, 0, stream>>>(
      Xall, Wqkv, bQkv, QKV, ROWS, G3, DIN);

  attn_k<<<512, 256, 0, stream>>>(QKV, attO);

  gemm_lds<EPI_BF16><<<dim3(4, 16), 256, 0, stream>>>(
      attO, WfcB, bfc, h2B, ROWS, HID, HID);

  gemm_lds<EPI_TANH><<<dim3(4, 16), 256, 0, stream>>>(
      h2B, Wh2oB, bh2o, logit, ROWS, DIN, HID);

  // vocab pass 1: rowsums of exp (8-phase 256^2), NB = 125
  gemm_v<EPI_SUM><<<1000, 512, 0, stream>>>(
      logit, WoutB, b_out, nullptr, partial, nullptr, ROWS, VOCAB, DIN, 125);
  reduce_rows<<<512, 256, 0, stream>>>(partial, rowsum, 125);
  // vocab pass 2: normalized probs -> d_out
  gemm_v<EPI_PROB><<<1000, 512, 0, stream>>>(
      logit, WoutB, b_out, (float*)d_out, nullptr, rowsum, ROWS, VOCAB, DIN, 125);
}

// Round 8
// 442.174 us; speedup vs baseline: 1.7731x; 1.1129x over previous
//
#include <hip/hip_runtime.h>
#include <hip/hip_bf16.h>
#include <math.h>

typedef __bf16 bf16_t;
typedef __bf16 bf16x8 __attribute__((ext_vector_type(8)));
typedef __bf16 bf16x4 __attribute__((ext_vector_type(4)));
typedef float  f32x4  __attribute__((ext_vector_type(4)));

#define T_STEPS 32
#define BATCH   64
#define DIN     512
#define HID     512
#define VOCAB   32000
#define FFEAT   768
#define ROWS    2048   /* T*B */
#define G3      1536   /* 3*H */
#define NBLK_A  32

#define EPI_F32  0
#define EPI_BF16 1
#define EPI_TANH 2

#define GLOAD16(gp, lp) __builtin_amdgcn_global_load_lds( \
    (const __attribute__((address_space(1))) void*)(gp),  \
    (__attribute__((address_space(3))) void*)(lp), 16, 0, 0)

// ===========================================================================
// gemm_v: 256x256 8-phase GEMM (guide §5 template) -- VOCAB pass 1 only.
// Computes e = exp(A@B^T + bias); stores e as bf16 to ecache (131 MB) and
// per-(row, bn) partial sums to `partial`. The old PROB pass (a full 67 GF
// recompute) is replaced by a streaming normalize over ecache.
// Schedule identical to R7 (verified deadlines); K now a template constant.
// ===========================================================================
#define PHASEV(BUF, MH, NH, STAGE_STMT, GATE_STMT)                            \
  {                                                                           \
    bf16x8 af_[8], bf_[4];                                                    \
    _Pragma("unroll")                                                         \
    for (int m2 = 0; m2 < 4; ++m2) {                                          \
      const int row = wm * 64 + m2 * 16 + la;                                 \
      _Pragma("unroll")                                                       \
      for (int ks = 0; ks < 2; ++ks) {                                        \
        const int sl = (ks * 4 + lg) ^ (row & 7);                             \
        af_[m2 * 2 + ks] =                                                    \
            *(const bf16x8*)&lds[((BUF)*4 + (MH)) * 8192 + row * 64 + sl * 8];\
      }                                                                       \
    }                                                                         \
    _Pragma("unroll")                                                         \
    for (int n2 = 0; n2 < 2; ++n2) {                                          \
      const int row = wn * 32 + n2 * 16 + la;                                 \
      _Pragma("unroll")                                                       \
      for (int ks = 0; ks < 2; ++ks) {                                        \
        const int sl = (ks * 4 + lg) ^ (row & 7);                             \
        bf_[n2 * 2 + ks] =                                                    \
            *(const bf16x8*)&lds[((BUF)*4 + 2 + (NH)) * 8192 + row * 64 + sl * 8];\
      }                                                                       \
    }                                                                         \
    STAGE_STMT;                                                               \
    GATE_STMT;                                                                \
    __builtin_amdgcn_s_barrier();                                             \
    __builtin_amdgcn_s_setprio(1);                                            \
    _Pragma("unroll")                                                         \
    for (int m2 = 0; m2 < 4; ++m2)                                            \
      _Pragma("unroll")                                                       \
      for (int n2 = 0; n2 < 2; ++n2)                                          \
        _Pragma("unroll")                                                     \
        for (int ks = 0; ks < 2; ++ks)                                        \
          acc[(MH)*4 + m2][(NH)*2 + n2] =                                     \
              __builtin_amdgcn_mfma_f32_16x16x32_bf16(                        \
                  af_[m2*2+ks], bf_[n2*2+ks],                                 \
                  acc[(MH)*4 + m2][(NH)*2 + n2], 0, 0, 0);                    \
    __builtin_amdgcn_s_setprio(0);                                            \
    __builtin_amdgcn_s_barrier();                                             \
  }

template<int KD>
__global__ __launch_bounds__(512, 2) void gemm_v(
    const bf16_t* __restrict__ A, const bf16_t* __restrict__ B,
    const float* __restrict__ bias, bf16_t* __restrict__ ecache,
    float* __restrict__ partial, int M, int N, int NB)
{
  __shared__ bf16_t lds[2 * 4 * 8192];   // 128 KB
  __shared__ float psum[256][4];
  const int tid = threadIdx.x;
  const int lane = tid & 63, wv = tid >> 6;
  const int wm = wv >> 2, wn = wv & 3;
  const int la = lane & 15, lg = lane >> 4;

  // bn-major XCD-chunk swizzle (nwg = NB * M/256, multiple of 8)
  const int lin = blockIdx.x;
  const int mt = M >> 8;                       // 8
  const int cpx = (NB * mt) >> 3;
  const int wg = (lin & 7) * cpx + (lin >> 3);
  const int bn = wg / mt, bm = wg - bn * mt;

  auto stageA = [&](int buf, int h, int kt) {
    const size_t base = (size_t)(bm * 256 + h * 128) * KD + (size_t)kt * 64;
#pragma unroll
    for (int q = 0; q < 2; ++q) {
      const int L = q * 512 + tid;
      const int row = L >> 3, sl = L & 7;
      const int c = sl ^ (row & 7);
      GLOAD16(A + base + (size_t)row * KD + c * 8,
              &lds[(buf * 4 + h) * 8192 + L * 8]);
    }
  };
  auto stageB = [&](int buf, int h, int kt) {
    const size_t base = (size_t)(bn * 256 + h * 128) * KD + (size_t)kt * 64;
#pragma unroll
    for (int q = 0; q < 2; ++q) {
      const int L = q * 512 + tid;
      const int row = L >> 3, sl = L & 7;
      const int c = sl ^ (row & 7);
      GLOAD16(B + base + (size_t)row * KD + c * 8,
              &lds[(buf * 4 + 2 + h) * 8192 + L * 8]);
    }
  };

  f32x4 acc[8][4] = {};
  constexpr int NITER = KD >> 7;               // 4 for K=512

  stageA(0, 0, 0); stageB(0, 0, 0); stageA(0, 1, 0); stageB(0, 1, 0);
  stageA(1, 0, 1); stageB(1, 0, 1);
  asm volatile("s_waitcnt vmcnt(4)" ::: "memory");
  __builtin_amdgcn_s_barrier();

#pragma unroll
  for (int it = 0; it < NITER; ++it) {
    const int t0 = 2 * it;
    const bool lastI = (it == NITER - 1);
    PHASEV(0, 0, 0, { stageA(1, 1, t0 + 1); }, ;)
    PHASEV(0, 0, 1, { stageB(1, 1, t0 + 1); }, ;)
    PHASEV(0, 1, 0, { if (!lastI) stageA(0, 0, t0 + 2); }, ;)
    PHASEV(0, 1, 1, { if (!lastI) stageB(0, 0, t0 + 2); },
           { if (lastI) { asm volatile("s_waitcnt vmcnt(0)" ::: "memory"); }
             else       { asm volatile("s_waitcnt vmcnt(4)" ::: "memory"); } })
    PHASEV(1, 0, 0, { if (!lastI) stageA(0, 1, t0 + 2); }, ;)
    PHASEV(1, 0, 1, { if (!lastI) stageB(0, 1, t0 + 2); }, ;)
    PHASEV(1, 1, 0, { if (!lastI) stageA(1, 0, t0 + 3); }, ;)
    PHASEV(1, 1, 1, { if (!lastI) stageB(1, 0, t0 + 3); },
           { if (!lastI) { asm volatile("s_waitcnt vmcnt(4)" ::: "memory"); } })
  }

  // epilogue: e = exp(acc + bias) -> bf16 ecache + fp32 partial row sums
  float bv[4];
#pragma unroll
  for (int nj = 0; nj < 4; ++nj) {
    const int col = bn * 256 + (nj >> 1) * 128 + wn * 32 + (nj & 1) * 16 + la;
    bv[nj] = bias[col];
  }
#pragma unroll
  for (int mi = 0; mi < 8; ++mi) {
#pragma unroll
    for (int rr = 0; rr < 4; ++rr) {
      const int rowl = (mi >> 2) * 128 + wm * 64 + (mi & 3) * 16 + lg * 4 + rr;
      const int row = bm * 256 + rowl;
      float vsum = 0.f;
#pragma unroll
      for (int nj = 0; nj < 4; ++nj) {
        const float e = expf(acc[mi][nj][rr] + bv[nj]);
        const int col = bn * 256 + (nj >> 1) * 128 + wn * 32 + (nj & 1) * 16 + la;
        ecache[(size_t)row * N + col] = (bf16_t)e;
        vsum += e;
      }
      vsum += __shfl_xor(vsum, 1);
      vsum += __shfl_xor(vsum, 2);
      vsum += __shfl_xor(vsum, 4);
      vsum += __shfl_xor(vsum, 8);
      if (la == 0) psum[rowl][wn] = vsum;
    }
  }
  __syncthreads();
  if (tid < 256) {
    partial[(size_t)(bm * 256 + tid) * NB + bn] =
        psum[tid][0] + psum[tid][1] + psum[tid][2] + psum[tid][3];
  }
}

// ---------------------------------------------------------------------------
// 128x128 LDS GEMM (R6 pipeline, K templated) for gi/QKV/fc/h2o.
// ---------------------------------------------------------------------------
template<int EPI, int KD>
__global__ __launch_bounds__(256) void gemm_lds(
    const bf16_t* __restrict__ A, const bf16_t* __restrict__ B,
    const float* __restrict__ bias, void* __restrict__ out, int M, int N)
{
  __shared__ bf16_t As[3][128 * 32];
  __shared__ bf16_t Bs[3][128 * 32];

  const int lane = threadIdx.x & 63;
  const int wv   = threadIdx.x >> 6;
  const int wm = wv >> 1, wn = wv & 1;
  const int bn = blockIdx.x, bm = blockIdx.y;
  const int la = lane & 15, lg = lane >> 4;
  const int tid = threadIdx.x;

  auto stage = [&](int buf, int k0) {
#pragma unroll
    for (int q = 0; q < 2; ++q) {
      const int idx = q * 256 + tid;
      const int row = idx >> 2, c = idx & 3;
      const int gch = c ^ ((row >> 1) & 3);
      GLOAD16(A + (size_t)(bm * 128 + row) * KD + k0 + gch * 8, &As[buf][idx * 8]);
      GLOAD16(B + (size_t)(bn * 128 + row) * KD + k0 + gch * 8, &Bs[buf][idx * 8]);
    }
  };
  const int rdch = (lg ^ ((la >> 1) & 3)) * 8;

  f32x4 acc[4][4] = {};
  constexpr int NT = KD >> 5;
  stage(0, 0);
  stage(1, 32);
  for (int kt = 0; kt < NT; ++kt) {
    if (kt + 1 < NT) {
      asm volatile("s_waitcnt vmcnt(4)" ::: "memory");
    } else {
      asm volatile("s_waitcnt vmcnt(0)" ::: "memory");
    }
    __builtin_amdgcn_s_barrier();
    __builtin_amdgcn_sched_barrier(0);
    if (kt + 2 < NT) stage((kt + 2) % 3, (kt + 2) * 32);
    const bf16_t* Ab = As[kt % 3];
    const bf16_t* Bb = Bs[kt % 3];
    bf16x8 a[4], b[4];
#pragma unroll
    for (int i = 0; i < 4; ++i)
      a[i] = *(const bf16x8*)(Ab + (wm * 64 + i * 16 + la) * 32 + rdch);
#pragma unroll
    for (int j = 0; j < 4; ++j)
      b[j] = *(const bf16x8*)(Bb + (wn * 64 + j * 16 + la) * 32 + rdch);
    __builtin_amdgcn_s_setprio(1);
#pragma unroll
    for (int i = 0; i < 4; ++i)
#pragma unroll
      for (int j = 0; j < 4; ++j)
        acc[i][j] = __builtin_amdgcn_mfma_f32_16x16x32_bf16(a[i], b[j], acc[i][j], 0, 0, 0);
    __builtin_amdgcn_s_setprio(0);
  }

  const int m0 = bm * 128 + wm * 64;
  const int n0 = bn * 128 + wn * 64;
  float bv4[4];
#pragma unroll
  for (int j = 0; j < 4; ++j) bv4[j] = bias[n0 + j * 16 + la];
#pragma unroll
  for (int i = 0; i < 4; ++i) {
#pragma unroll
    for (int r = 0; r < 4; ++r) {
      const int row = m0 + i * 16 + lg * 4 + r;
#pragma unroll
      for (int j = 0; j < 4; ++j) {
        const int col = n0 + j * 16 + la;
        float v = acc[i][j][r] + bv4[j];
        if constexpr (EPI == EPI_F32) {
          ((float*)out)[(size_t)row * N + col] = v;
        } else if constexpr (EPI == EPI_BF16) {
          ((bf16_t*)out)[(size_t)row * N + col] = (bf16_t)v;
        } else {
          ((bf16_t*)out)[(size_t)row * N + col] = (bf16_t)tanhf(v);
        }
      }
    }
  }
}

// ---------------------------------------------------------------------------
// Phase A: GRU recurrence (blocks 0..31) + fused W_out cast (blocks 32..223).
// Busy-poll (no s_sleep): detection quantum is now one L3 load RT.
// ---------------------------------------------------------------------------
__global__ __launch_bounds__(256) void phaseA_k(
    const bf16_t* __restrict__ Wg, const float* __restrict__ bhh,
    const float* __restrict__ gi, const float* __restrict__ ct,
    unsigned int* __restrict__ hbuf, bf16_t* __restrict__ Xall,
    int* __restrict__ flags, const float* __restrict__ Wout_f32,
    bf16_t* __restrict__ WoutB)
{
  __shared__ bf16_t Wl[48 * 520];
  __shared__ float bl[48];
  const int tid = threadIdx.x, blk = blockIdx.x;

  if (blk >= NBLK_A) {                          // cast crew
    const int NCB = gridDim.x - NBLK_A;
    const int n4 = VOCAB * DIN / 4;
    for (int i = (blk - NBLK_A) * 256 + tid; i < n4; i += NCB * 256) {
      float4 v = ((const float4*)Wout_f32)[i];
      bf16x4 o = {(bf16_t)v.x, (bf16_t)v.y, (bf16_t)v.z, (bf16_t)v.w};
      *(bf16x4*)(WoutB + (size_t)i * 4) = o;
    }
    return;
  }

  for (int i = tid; i < 48 * 64; i += 256) {
    const int rw = i >> 6, ch = (i & 63) << 3;
    *(bf16x8*)(Wl + rw * 520 + ch) = *(const bf16x8*)(Wg + (size_t)(blk * 48 + rw) * 512 + ch);
  }
  if (tid < 48) bl[tid] = bhh[blk * 48 + tid];
  __syncthreads();

  const int lane = tid & 63, wv = tid >> 6;
  const int la = lane & 15, lg = lane >> 4;
  const int jcol = blk * 16 + la;
  const int rowA = wv * 16 + la;

  const float blr = bl[la], blz = bl[16 + la], bln = bl[32 + la];
  float hprev[4], ctv[4];
#pragma unroll
  for (int r = 0; r < 4; ++r) {
    hprev[r] = 0.f;
    ctv[r] = ct[(size_t)(wv * 16 + lg * 4 + r) * HID + jcol];
  }

  for (int t = 0; t < T_STEPS; ++t) {
    const float* girow = gi + (size_t)t * BATCH * G3 + (size_t)blk * 48;
    float gv[12];
#pragma unroll
    for (int r = 0; r < 4; ++r) {
      const float* gp = girow + (size_t)(wv * 16 + lg * 4 + r) * G3;
      gv[r * 3 + 0] = gp[la];
      gv[r * 3 + 1] = gp[16 + la];
      gv[r * 3 + 2] = gp[32 + la];
    }
    if (t > 0) {
      if (lane < 32) {
        while (__hip_atomic_load(&flags[(lane * 4 + wv) * 16], __ATOMIC_RELAXED,
                                 __HIP_MEMORY_SCOPE_AGENT) < t) { }
      }
      asm volatile("" ::: "memory");
    }
    const unsigned long long* hb =
        (const unsigned long long*)(hbuf + (size_t)(t & 1) * 16384);
    bf16x8 af[16];
#pragma unroll
    for (int q = 0; q < 16; ++q) {
      union { unsigned long long u[2]; bf16x8 v; } c;
      const size_t bidx = (size_t)(2 * q + (lg >> 1)) * 256 + rowA * 4 + (lg & 1) * 2;
      c.u[0] = __hip_atomic_load(hb + bidx,     __ATOMIC_RELAXED, __HIP_MEMORY_SCOPE_AGENT);
      c.u[1] = __hip_atomic_load(hb + bidx + 1, __ATOMIC_RELAXED, __HIP_MEMORY_SCOPE_AGENT);
      af[q] = c.v;
    }
    f32x4 acc0 = {}, acc1 = {}, acc2 = {};
#pragma unroll
    for (int q = 0; q < 16; ++q) {
      const bf16_t* wp = Wl + q * 32 + lg * 8;
      bf16x8 b0 = *(const bf16x8*)(wp + (0 * 16 + la) * 520);
      bf16x8 b1 = *(const bf16x8*)(wp + (1 * 16 + la) * 520);
      bf16x8 b2 = *(const bf16x8*)(wp + (2 * 16 + la) * 520);
      acc0 = __builtin_amdgcn_mfma_f32_16x16x32_bf16(af[q], b0, acc0, 0, 0, 0);
      acc1 = __builtin_amdgcn_mfma_f32_16x16x32_bf16(af[q], b1, acc1, 0, 0, 0);
      acc2 = __builtin_amdgcn_mfma_f32_16x16x32_bf16(af[q], b2, acc2, 0, 0, 0);
    }
    float h1v[4];
#pragma unroll
    for (int r = 0; r < 4; ++r) {
      const float ghr = acc0[r] + blr;
      const float ghz = acc1[r] + blz;
      const float ghn = acc2[r] + bln;
      const float rr = 1.f / (1.f + expf(-(gv[r * 3 + 0] + ghr)));
      const float zz = 1.f / (1.f + expf(-(gv[r * 3 + 1] + ghz)));
      const float nn = tanhf(gv[r * 3 + 2] + rr * ghn);
      h1v[r] = (1.f - zz) * nn + zz * hprev[r];
      hprev[r] = h1v[r];
    }
    unsigned int* hn = hbuf + (size_t)((t + 1) & 1) * 16384 + blk * 512;
#pragma unroll
    for (int r = 0; r < 4; ++r) {
      const int row = wv * 16 + lg * 4 + r;
      const unsigned int mine =
          (unsigned int)__builtin_bit_cast(unsigned short, (bf16_t)h1v[r]);
      const unsigned int other = (unsigned int)__shfl_xor((int)mine, 1);
      if ((la & 1) == 0) {
        __hip_atomic_store(hn + row * 8 + (la >> 1), mine | (other << 16),
                           __ATOMIC_RELAXED, __HIP_MEMORY_SCOPE_AGENT);
      }
    }
    asm volatile("s_waitcnt vmcnt(0)" ::: "memory");
    if (lane == 0) {
      __hip_atomic_store(&flags[(blk * 4 + wv) * 16], t + 1, __ATOMIC_RELAXED,
                         __HIP_MEMORY_SCOPE_AGENT);
    }
#pragma unroll
    for (int r = 0; r < 4; ++r) {
      const int row = wv * 16 + lg * 4 + r;
      Xall[((size_t)t * BATCH + row) * HID + jcol] = (bf16_t)(h1v[r] * ctv[r]);
    }
  }
}

// ---------------------------------------------------------------------------
__global__ __launch_bounds__(256) void attn_k(const bf16_t* __restrict__ QKV,
                                              bf16_t* __restrict__ attO)
{
  __shared__ float sq[4][512], sk[4][512], sv[4][512], sw[4][64];
  const int tid = threadIdx.x;
  const int wv = tid >> 6, lane = tid & 63;
  const int row = blockIdx.x * 4 + wv;
  const bf16_t* base = QKV + (size_t)row * G3;
  bf16x8 vq = *(const bf16x8*)(base + lane * 8);
  bf16x8 vk = *(const bf16x8*)(base + 512 + lane * 8);
  bf16x8 vv = *(const bf16x8*)(base + 1024 + lane * 8);
#pragma unroll
  for (int e = 0; e < 8; ++e) {
    sq[wv][lane * 8 + e] = (float)vq[e];
    sk[wv][lane * 8 + e] = (float)vk[e];
    sv[wv][lane * 8 + e] = (float)vv[e];
  }
  __syncthreads();
  const int h = lane >> 3, g = lane & 7;
  float s = 0.f;
#pragma unroll 16
  for (int d = 0; d < 64; ++d) s += sq[wv][h * 64 + d] * sk[wv][g * 64 + d];
  s *= (1.f / 64.f);
  float m = s;
  m = fmaxf(m, __shfl_xor(m, 1));
  m = fmaxf(m, __shfl_xor(m, 2));
  m = fmaxf(m, __shfl_xor(m, 4));
  const float e = expf(s - m);
  float sum = e;
  sum += __shfl_xor(sum, 1);
  sum += __shfl_xor(sum, 2);
  sum += __shfl_xor(sum, 4);
  sw[wv][lane] = e / sum;
  __syncthreads();
#pragma unroll
  for (int rep = 0; rep < 8; ++rep) {
    const int idx = rep * 64 + lane;
    const int hh = idx >> 6, d = idx & 63;
    float o = 0.f;
#pragma unroll
    for (int gg = 0; gg < 8; ++gg) o += sw[wv][hh * 8 + gg] * sv[wv][gg * 64 + d];
    attO[(size_t)row * HID + idx] = (bf16_t)o;
  }
}

// --------------------------- small prep kernels ----------------------------
// one launch for all five HIDxHID weight casts (Wq,Wk,Wv -> Wqkv; Wfc; Wh2o)
__global__ __launch_bounds__(256) void cast5_k(
    const float* __restrict__ s0, const float* __restrict__ s1,
    const float* __restrict__ s2, const float* __restrict__ s3,
    const float* __restrict__ s4, bf16_t* __restrict__ Wqkv,
    bf16_t* __restrict__ WfcB, bf16_t* __restrict__ Wh2oB)
{
  const int seg = blockIdx.x >> 8;               // 256 blocks per segment
  const int i = (blockIdx.x & 255) * 256 + threadIdx.x;  // < 65536
  const float* src = seg == 0 ? s0 : seg == 1 ? s1 : seg == 2 ? s2
                   : seg == 3 ? s3 : s4;
  bf16_t* dst = seg <= 2 ? Wqkv + (size_t)seg * HID * DIN
              : seg == 3 ? WfcB : Wh2oB;
  float4 v = ((const float4*)src)[i];
  bf16x4 o = {(bf16_t)v.x, (bf16_t)v.y, (bf16_t)v.z, (bf16_t)v.w};
  *(bf16x4*)(dst + (size_t)i * 4) = o;
}

__global__ __launch_bounds__(256) void perm_cast_k(const float* __restrict__ src,
                                                   bf16_t* __restrict__ dst)
{
  const int i = blockIdx.x * 256 + threadIdx.x;
  const int pg = i >> 7, kq = (i & 127) << 2;
  const int g = pg / 48, rem = pg - g * 48, sec = rem >> 4, jj = rem & 15;
  const int srow = sec * 512 + g * 16 + jj;
  float4 v = *(const float4*)(src + (size_t)srow * DIN + kq);
  bf16x4 o = {(bf16_t)v.x, (bf16_t)v.y, (bf16_t)v.z, (bf16_t)v.w};
  *(bf16x4*)(dst + (size_t)pg * DIN + kq) = o;
}

__global__ void perm_bias_k(const float* __restrict__ bih, const float* __restrict__ bhh,
                            float* __restrict__ bihp, float* __restrict__ bhhp)
{
  const int pg = blockIdx.x * 256 + threadIdx.x;
  if (pg >= G3) return;
  const int g = pg / 48, rem = pg - g * 48, sec = rem >> 4, jj = rem & 15;
  const int srow = sec * 512 + g * 16 + jj;
  bihp[pg] = bih[srow];
  bhhp[pg] = bhh[srow];
}

__global__ void bcat_k(const float* __restrict__ a, const float* __restrict__ b,
                       const float* __restrict__ c, float* __restrict__ d)
{
  const int i = blockIdx.x * 256 + threadIdx.x;
  if (i >= G3) return;
  d[i] = i < 512 ? a[i] : (i < 1024 ? b[i - 512] : c[i - 1024]);
}

__global__ __launch_bounds__(256) void yemb_k(const int* __restrict__ y,
                                              const float* __restrict__ embW,
                                              bf16_t* __restrict__ out)
{
  const int idx = blockIdx.x * 256 + threadIdx.x;
  const int rb = idx >> 6, c = (idx & 63) << 3;
  const int tok = y[rb];
  const float4* s = (const float4*)(embW + (size_t)tok * DIN + c);
  float4 v0 = s[0], v1 = s[1];
  bf16x8 o = {(bf16_t)v0.x, (bf16_t)v0.y, (bf16_t)v0.z, (bf16_t)v0.w,
              (bf16_t)v1.x, (bf16_t)v1.y, (bf16_t)v1.z, (bf16_t)v1.w};
  *(bf16x8*)(out + (size_t)rb * DIN + c) = o;
}

__global__ __launch_bounds__(256) void ct_k(const float* __restrict__ ctx,
                                            const float* __restrict__ Watt,
                                            const float* __restrict__ batt,
                                            float* __restrict__ ct)
{
  const int idx = blockIdx.x * 256 + threadIdx.x;
  const int b = idx >> 9, j = idx & 511;
  const float4* c4 = (const float4*)(ctx + (size_t)b * FFEAT);
  const float4* w4 = (const float4*)(Watt + (size_t)j * FFEAT);
  float s = batt[j];
  for (int q = 0; q < FFEAT / 4; ++q) {
    float4 cc = c4[q], ww = w4[q];
    s += cc.x * ww.x + cc.y * ww.y + cc.z * ww.z + cc.w * ww.w;
  }
  ct[idx] = tanhf(s);
}

__global__ __launch_bounds__(256) void reduce_rows(const float* __restrict__ partial,
                                                   float* __restrict__ rowsum, int NB)
{
  const int wv = threadIdx.x >> 6, lane = threadIdx.x & 63;
  const int row = blockIdx.x * 4 + wv;
  float s = 0.f;
  for (int c = lane; c < NB; c += 64) s += partial[(size_t)row * NB + c];
  for (int m = 1; m < 64; m <<= 1) s += __shfl_xor(s, m);
  if (lane == 0) rowsum[row] = s;
}

// normalize: prob = e_bf16 * (1/rowsum) -> f32 d_out. 393 MB streaming.
__global__ __launch_bounds__(256) void normalize_k(const bf16_t* __restrict__ e,
                                                   const float* __restrict__ rowsum,
                                                   float* __restrict__ out)
{
  const int row = blockIdx.y;
  const int c8 = blockIdx.x * 256 + threadIdx.x;   // 8 cols per thread
  if (c8 >= VOCAB / 8) return;
  const float inv = 1.0f / rowsum[row];
  const size_t base = (size_t)row * VOCAB + (size_t)c8 * 8;
  bf16x8 v = *(const bf16x8*)(e + base);
  float4 o0 = {(float)v[0] * inv, (float)v[1] * inv, (float)v[2] * inv, (float)v[3] * inv};
  float4 o1 = {(float)v[4] * inv, (float)v[5] * inv, (float)v[6] * inv, (float)v[7] * inv};
  *(float4*)(out + base) = o0;
  *(float4*)(out + base + 4) = o1;
}

// ---------------------------------------------------------------------------
extern "C" void kernel_launch(void* const* d_in, const int* in_sizes, int n_in,
                              void* d_out, int out_size, void* d_ws, size_t ws_size,
                              hipStream_t stream)
{
  const int*   y     = (const int*)  d_in[0];
  const float* ctx   = (const float*)d_in[1];
  const float* embW  = (const float*)d_in[2];
  const float* W_ih  = (const float*)d_in[3];
  const float* b_ih  = (const float*)d_in[4];
  const float* W_hh  = (const float*)d_in[5];
  const float* b_hh  = (const float*)d_in[6];
  const float* W_att = (const float*)d_in[7];
  const float* b_att = (const float*)d_in[8];
  const float* Wq    = (const float*)d_in[9];
  const float* bq    = (const float*)d_in[10];
  const float* Wk    = (const float*)d_in[11];
  const float* bk    = (const float*)d_in[12];
  const float* Wv    = (const float*)d_in[13];
  const float* bv    = (const float*)d_in[14];
  const float* Wfc   = (const float*)d_in[15];
  const float* bfc   = (const float*)d_in[16];
  const float* Wh2o  = (const float*)d_in[17];
  const float* bh2o  = (const float*)d_in[18];
  const float* W_out = (const float*)d_in[19];
  const float* b_out = (const float*)d_in[20];

  char* p = (char*)d_ws;
  auto alloc = [&](size_t bytes) {
    char* r = p;
    p += (bytes + 255) & ~(size_t)255;
    return r;
  };
  bf16_t* WoutB   = (bf16_t*)alloc((size_t)VOCAB * DIN * 2);
  bf16_t* WgIh    = (bf16_t*)alloc((size_t)G3 * DIN * 2);
  bf16_t* WgHh    = (bf16_t*)alloc((size_t)G3 * DIN * 2);
  bf16_t* Wqkv    = (bf16_t*)alloc((size_t)G3 * DIN * 2);
  bf16_t* WfcB    = (bf16_t*)alloc((size_t)HID * HID * 2);
  bf16_t* Wh2oB   = (bf16_t*)alloc((size_t)HID * HID * 2);
  float*  bIhP    = (float*)alloc(G3 * 4);
  float*  bHhP    = (float*)alloc(G3 * 4);
  float*  bQkv    = (float*)alloc(G3 * 4);
  bf16_t* Yemb    = (bf16_t*)alloc((size_t)ROWS * DIN * 2);
  float*  giP     = (float*)alloc((size_t)ROWS * G3 * 4);
  float*  ctB     = (float*)alloc((size_t)BATCH * HID * 4);
  unsigned int* hbuf = (unsigned int*)alloc((size_t)2 * 16384 * 4);
  bf16_t* Xall    = (bf16_t*)alloc((size_t)ROWS * DIN * 2);
  bf16_t* QKV     = (bf16_t*)alloc((size_t)ROWS * G3 * 2);
  bf16_t* attO    = (bf16_t*)alloc((size_t)ROWS * HID * 2);
  bf16_t* h2B     = (bf16_t*)alloc((size_t)ROWS * HID * 2);
  bf16_t* logit   = (bf16_t*)alloc((size_t)ROWS * DIN * 2);
  float*  partial = (float*)alloc((size_t)ROWS * 125 * 4);
  float*  rowsum  = (float*)alloc((size_t)ROWS * 4);
  int*    flags   = (int*)alloc(32 * 4 * 64);
  bf16_t* eCache  = (bf16_t*)alloc((size_t)ROWS * VOCAB * 2);   // 131 MB

  hipMemsetAsync(hbuf, 0, (size_t)2 * 16384 * 4, stream);
  hipMemsetAsync(flags, 0, 32 * 4 * 64, stream);

  // weight prep (W_out cast fused into phaseA launch below)
  cast5_k<<<1280, 256, 0, stream>>>(Wq, Wk, Wv, Wfc, Wh2o, Wqkv, WfcB, Wh2oB);
  perm_cast_k<<<768, 256, 0, stream>>>(W_ih, WgIh);
  perm_cast_k<<<768, 256, 0, stream>>>(W_hh, WgHh);
  perm_bias_k<<<6, 256, 0, stream>>>(b_ih, b_hh, bIhP, bHhP);
  bcat_k<<<6, 256, 0, stream>>>(bq, bk, bv, bQkv);
  yemb_k<<<512, 256, 0, stream>>>(y, embW, Yemb);
  ct_k<<<128, 256, 0, stream>>>(ctx, W_att, b_att, ctB);

  // gi = Yemb @ WgIh^T + bIhP  (fp32)
  gemm_lds<EPI_F32, DIN><<<dim3(12, 16), 256, 0, stream>>>(
      Yemb, WgIh, bIhP, giP, ROWS, G3);

  // GRU recurrence (blocks 0-31) + W_out cast (blocks 32-223)
  phaseA_k<<<224, 256, 0, stream>>>(WgHh, bHhP, giP, ctB, hbuf, Xall, flags,
                                    W_out, WoutB);

  // QKV = X @ [Wq;Wk;Wv]^T + b
  gemm_lds<EPI_BF16, DIN><<<dim3(12, 16), 256, 0, stream>>>(
      Xall, Wqkv, bQkv, QKV, ROWS, G3);

  attn_k<<<512, 256, 0, stream>>>(QKV, attO);

  gemm_lds<EPI_BF16, HID><<<dim3(4, 16), 256, 0, stream>>>(
      attO, WfcB, bfc, h2B, ROWS, HID);

  gemm_lds<EPI_TANH, HID><<<dim3(4, 16), 256, 0, stream>>>(
      h2B, Wh2oB, bh2o, logit, ROWS, DIN);

  // vocab: single GEMM -> bf16 exp cache + partial sums (NB = 125)
  gemm_v<DIN><<<1000, 512, 0, stream>>>(
      logit, WoutB, b_out, eCache, partial, ROWS, VOCAB, 125);
  reduce_rows<<<512, 256, 0, stream>>>(partial, rowsum, 125);
  // streaming normalize: prob = e * 1/rowsum -> f32 d_out
  normalize_k<<<dim3(16, ROWS), 256, 0, stream>>>(eCache, rowsum, (float*)d_out);
}